// Round 1
// baseline (1025.738 us; speedup 1.0000x reference)
//
#include <hip/hip_runtime.h>
#include <math.h>

#define ALPHA 0.2f
#define NP 50000
#define NA 25000

__device__ __forceinline__ void atomicMaxF(float* addr, float val) {
    if (val >= 0.f) atomicMax((int*)addr, __float_as_int(val));
    else            atomicMin((unsigned int*)addr, __float_as_uint(val));
}

__global__ void fill_f32(float* __restrict__ p, float v, int n) {
    int i = blockIdx.x * blockDim.x + threadIdx.x;
    if (i < n) p[i] = v;
}

// Z = X @ W + b   (X:[N,64], W:[64,64] row-major, b:[64])
__global__ void xform(const float* __restrict__ X, const float* __restrict__ W,
                      const float* __restrict__ b, float* __restrict__ Z, int N) {
    __shared__ float Ws[64][64];
    __shared__ float Xs[4][64];
    int tid = threadIdx.x;                 // 256 threads
#pragma unroll
    for (int i = 0; i < 16; ++i) {
        int idx = tid + i * 256;           // 0..4095
        Ws[idx >> 6][idx & 63] = W[idx];
    }
    int r = tid >> 6, c = tid & 63;
    int row = blockIdx.x * 4 + r;
    Xs[r][c] = (row < N) ? X[row * 64 + c] : 0.f;
    __syncthreads();
    float acc = b[c];
#pragma unroll
    for (int k = 0; k < 64; ++k) acc = fmaf(Xs[r][k], Ws[k][c], acc);
    if (row < N) Z[row * 64 + c] = acc;
}

// s[n] = dot(Z[n,:], a[0:64]) ; one wave per row
__global__ void rowdot(const float* __restrict__ Z, const float* __restrict__ a,
                       float* __restrict__ s, int N) {
    int lane = threadIdx.x & 63;
    int row = (blockIdx.x * blockDim.x + threadIdx.x) >> 6;
    if (row >= N) return;                  // whole wave exits together
    float v = Z[row * 64 + lane] * a[lane];
#pragma unroll
    for (int off = 32; off > 0; off >>= 1) v += __shfl_down(v, off, 64);
    if (lane == 0) s[row] = v;
}

// pass1: e = leaky_relu(s_src[src] + s_dst[dst]); m[dst] = max(...)
__global__ void edge_pass1(const int* __restrict__ src, const int* __restrict__ dst,
                           const float* __restrict__ s_src, const float* __restrict__ s_dst,
                           float* __restrict__ e, float* __restrict__ m, int E) {
    int k = blockIdx.x * blockDim.x + threadIdx.x;
    if (k >= E) return;
    float v = s_src[src[k]] + s_dst[dst[k]];
    v = v > 0.f ? v : ALPHA * v;
    e[k] = v;
    atomicMaxF(&m[dst[k]], v);
}

// pass2: ex = exp(e - m[dst]); den[dst] += ex; e <- ex
__global__ void edge_pass2(const int* __restrict__ dst, float* __restrict__ e,
                           const float* __restrict__ m, float* __restrict__ den, int E) {
    int k = blockIdx.x * blockDim.x + threadIdx.x;
    if (k >= E) return;
    int d = dst[k];
    float ex = expf(e[k] - m[d]);
    e[k] = ex;
    atomicAdd(&den[d], ex);
}

// pass3: acc[dst,:] += (ex/den[dst]) * Z[src,:]   (one wave per edge)
__global__ void edge_pass3(const int* __restrict__ src, const int* __restrict__ dst,
                           const float* __restrict__ ex, const float* __restrict__ den,
                           const float* __restrict__ Z, float* __restrict__ acc, int E) {
    long long idx = (long long)blockIdx.x * blockDim.x + threadIdx.x;
    int k = (int)(idx >> 6);
    int lane = (int)(idx & 63);
    if (k >= E) return;
    int s = src[k], d = dst[k];
    float w = ex[k] / den[d];
    atomicAdd(&acc[(long long)d * 64 + lane], w * Z[(long long)s * 64 + lane]);
}

// state prep: Wh_in = feat_state @ W_in + b_in (written to outS), plus the two
// dst-half attention dots for p2s/a2s. 64 threads (1 wave).
__global__ void state_prep(const float* __restrict__ fS, const float* __restrict__ W_in,
                           const float* __restrict__ b_in, const float* __restrict__ a_p2s,
                           const float* __restrict__ a_a2s, float* __restrict__ outS,
                           float* __restrict__ sdst2) {
    int c = threadIdx.x;
    float acc = b_in[c];
    for (int k = 0; k < 64; ++k) acc = fmaf(fS[k], W_in[k * 64 + c], acc);
    outS[c] = acc;
    float v0 = acc * a_p2s[64 + c];
    float v1 = acc * a_a2s[64 + c];
#pragma unroll
    for (int off = 32; off > 0; off >>= 1) {
        v0 += __shfl_down(v0, off, 64);
        v1 += __shfl_down(v1, off, 64);
    }
    if (c == 0) { sdst2[0] = v0; sdst2[1] = v1; }
}

// state pass1: e_i = leaky(s_src[src[i]] + sdst); global max via per-wave atomic
__global__ void state_pass1(const int* __restrict__ src, const float* __restrict__ s_src,
                            const float* __restrict__ sdst, float* __restrict__ e,
                            float* __restrict__ m, int N) {
    int i = blockIdx.x * blockDim.x + threadIdx.x;
    float v = -INFINITY;
    if (i < N) {
        v = s_src[src[i]] + *sdst;
        v = v > 0.f ? v : ALPHA * v;
        e[i] = v;
    }
#pragma unroll
    for (int off = 32; off > 0; off >>= 1) v = fmaxf(v, __shfl_down(v, off, 64));
    if ((threadIdx.x & 63) == 0) atomicMaxF(m, v);
}

// state pass2: ex = exp(e - m); den += ex (per-wave partial, then atomic)
__global__ void state_pass2(float* __restrict__ e, const float* __restrict__ m,
                            float* __restrict__ den, int N) {
    int i = blockIdx.x * blockDim.x + threadIdx.x;
    float ex = 0.f;
    if (i < N) {
        ex = expf(e[i] - *m);
        e[i] = ex;
    }
#pragma unroll
    for (int off = 32; off > 0; off >>= 1) ex += __shfl_down(ex, off, 64);
    if ((threadIdx.x & 63) == 0) atomicAdd(den, ex);
}

// state pass3: outS[d] += sum_i (ex_i/den) * Z[src[i], d]
__global__ void state_pass3(const int* __restrict__ src, const float* __restrict__ ex,
                            const float* __restrict__ den, const float* __restrict__ Z,
                            float* __restrict__ outS, int N) {
    __shared__ float red[4][64];
    int lane = threadIdx.x & 63;
    int wv = threadIdx.x >> 6;
    int gw = blockIdx.x * 4 + wv;
    int nw = gridDim.x * 4;
    float dn = *den;
    float acc = 0.f;
    for (int i = gw; i < N; i += nw)
        acc += (ex[i] / dn) * Z[(long long)src[i] * 64 + lane];
    red[wv][lane] = acc;
    __syncthreads();
    if (wv == 0) {
        float t = red[0][lane] + red[1][lane] + red[2][lane] + red[3][lane];
        atomicAdd(&outS[lane], t);
    }
}

__global__ void relu_inplace(float* __restrict__ p, int n) {
    int i = blockIdx.x * blockDim.x + threadIdx.x;
    if (i < n) p[i] = fmaxf(p[i], 0.f);
}

extern "C" void kernel_launch(void* const* d_in, const int* in_sizes, int n_in,
                              void* d_out, int out_size, void* d_ws, size_t ws_size,
                              hipStream_t stream) {
    const float* feat_P = (const float*)d_in[0];
    const float* feat_A = (const float*)d_in[1];
    const float* feat_S = (const float*)d_in[2];
    const float* W_P   = (const float*)d_in[3];  const float* b_P   = (const float*)d_in[4];
    const float* W_A   = (const float*)d_in[5];  const float* b_A   = (const float*)d_in[6];
    const float* W_p2p = (const float*)d_in[7];  const float* b_p2p = (const float*)d_in[8];
    const float* W_p2a = (const float*)d_in[9];  const float* b_p2a = (const float*)d_in[10];
    const float* W_a2p = (const float*)d_in[11]; const float* b_a2p = (const float*)d_in[12];
    const float* W_a2a = (const float*)d_in[13]; const float* b_a2a = (const float*)d_in[14];
    const float* W_p2s = (const float*)d_in[15]; const float* b_p2s = (const float*)d_in[16];
    const float* W_a2s = (const float*)d_in[17]; const float* b_a2s = (const float*)d_in[18];
    const float* W_in  = (const float*)d_in[19]; const float* b_in  = (const float*)d_in[20];
    const float* a_p2p = (const float*)d_in[21];
    const float* a_p2a = (const float*)d_in[22];
    const float* a_a2p = (const float*)d_in[23];
    const float* a_a2a = (const float*)d_in[24];
    const float* a_p2s = (const float*)d_in[25];
    const float* a_a2s = (const float*)d_in[26];
    const int* src_p2p = (const int*)d_in[27]; const int* dst_p2p = (const int*)d_in[28];
    const int* src_p2a = (const int*)d_in[29]; const int* dst_p2a = (const int*)d_in[30];
    const int* src_a2p = (const int*)d_in[31]; const int* dst_a2p = (const int*)d_in[32];
    const int* src_a2a = (const int*)d_in[33]; const int* dst_a2a = (const int*)d_in[34];
    const int* src_p2s = (const int*)d_in[35];
    const int* src_a2s = (const int*)d_in[37];
    int E_p2p = in_sizes[27], E_p2a = in_sizes[29], E_a2p = in_sizes[31], E_a2a = in_sizes[33];
    int E_p2s = in_sizes[35], E_a2s = in_sizes[37];

    float* out = (float*)d_out;
    float* outP = out;                       // [NP,64]
    float* outA = out + (long long)NP * 64;  // [NA,64]
    float* outS = out + (long long)(NP + NA) * 64;  // [64]

    // ---- workspace layout (floats) ----
    float* ws = (float*)d_ws;
    float* z_p2p = ws;                 ws += (long long)NP * 64;
    float* z_p2a = ws;                 ws += (long long)NP * 64;
    float* z_p2s = ws;                 ws += (long long)NP * 64;
    float* z_a2p = ws;                 ws += (long long)NA * 64;
    float* z_a2a = ws;                 ws += (long long)NA * 64;
    float* z_a2s = ws;                 ws += (long long)NA * 64;
    float* ss_p2p = ws; ws += NP;  float* sd_p2p = ws; ws += NP;
    float* ss_p2a = ws; ws += NP;  float* sd_p2a = ws; ws += NA;
    float* ss_a2p = ws; ws += NA;  float* sd_a2p = ws; ws += NP;
    float* ss_a2a = ws; ws += NA;  float* sd_a2a = ws; ws += NA;
    float* ss_p2s = ws; ws += NP;
    float* ss_a2s = ws; ws += NA;
    // m-region (init -inf) then den-region (init 0), contiguous each
    float* m_all = ws;
    float* m_p2p = ws; ws += NP;
    float* m_p2a = ws; ws += NA;
    float* m_a2p = ws; ws += NP;
    float* m_a2a = ws; ws += NA;
    float* m_p2s = ws; ws += 1;
    float* m_a2s = ws; ws += 1;
    int n_m = (int)(ws - m_all);
    float* den_all = ws;
    float* den_p2p = ws; ws += NP;
    float* den_p2a = ws; ws += NA;
    float* den_a2p = ws; ws += NP;
    float* den_a2a = ws; ws += NA;
    float* den_p2s = ws; ws += 1;
    float* den_a2s = ws; ws += 1;
    int n_den = (int)(ws - den_all);
    float* sdst2 = ws; ws += 2;   // [0]=p2s dst dot, [1]=a2s dst dot
    float* e_p2p = ws; ws += E_p2p;
    float* e_p2a = ws; ws += E_p2a;
    float* e_a2p = ws; ws += E_a2p;
    float* e_a2a = ws; ws += E_a2a;
    float* e_p2s = ws; ws += E_p2s;
    float* e_a2s = ws; ws += E_a2s;

    const int T = 256;
    int gP = (NP + 3) / 4, gA = (NA + 3) / 4;

    // init m / den
    fill_f32<<<(n_m + T - 1) / T, T, 0, stream>>>(m_all, -INFINITY, n_m);
    fill_f32<<<(n_den + T - 1) / T, T, 0, stream>>>(den_all, 0.f, n_den);

    // ---- dense transforms ----
    xform<<<gP, T, 0, stream>>>(feat_P, W_P,   b_P,   outP,  NP);   // Wh_P -> out
    xform<<<gA, T, 0, stream>>>(feat_A, W_A,   b_A,   outA,  NA);   // Wh_A -> out
    xform<<<gP, T, 0, stream>>>(feat_P, W_p2p, b_p2p, z_p2p, NP);
    xform<<<gP, T, 0, stream>>>(feat_P, W_p2a, b_p2a, z_p2a, NP);
    xform<<<gP, T, 0, stream>>>(feat_P, W_p2s, b_p2s, z_p2s, NP);
    xform<<<gA, T, 0, stream>>>(feat_A, W_a2p, b_a2p, z_a2p, NA);
    xform<<<gA, T, 0, stream>>>(feat_A, W_a2a, b_a2a, z_a2a, NA);
    xform<<<gA, T, 0, stream>>>(feat_A, W_a2s, b_a2s, z_a2s, NA);
    state_prep<<<1, 64, 0, stream>>>(feat_S, W_in, b_in, a_p2s, a_a2s, outS, sdst2);

    // ---- per-node attention half-dots (wave per row) ----
    int gPd = (NP * 64 + T - 1) / T, gAd = (NA * 64 + T - 1) / T;
    rowdot<<<gPd, T, 0, stream>>>(z_p2p, a_p2p,      ss_p2p, NP);
    rowdot<<<gPd, T, 0, stream>>>(outP,  a_p2p + 64, sd_p2p, NP);
    rowdot<<<gPd, T, 0, stream>>>(z_p2a, a_p2a,      ss_p2a, NP);
    rowdot<<<gAd, T, 0, stream>>>(outA,  a_p2a + 64, sd_p2a, NA);
    rowdot<<<gAd, T, 0, stream>>>(z_a2p, a_a2p,      ss_a2p, NA);
    rowdot<<<gPd, T, 0, stream>>>(outP,  a_a2p + 64, sd_a2p, NP);
    rowdot<<<gAd, T, 0, stream>>>(z_a2a, a_a2a,      ss_a2a, NA);
    rowdot<<<gAd, T, 0, stream>>>(outA,  a_a2a + 64, sd_a2a, NA);
    rowdot<<<gPd, T, 0, stream>>>(z_p2s, a_p2s,      ss_p2s, NP);
    rowdot<<<gAd, T, 0, stream>>>(z_a2s, a_a2s,      ss_a2s, NA);

    // ---- big edge types: 3-pass GAT ----
#define EDGE3(src, dst, ss, sd, e, m, den, Z, acc, E)                                   \
    edge_pass1<<<((E) + T - 1) / T, T, 0, stream>>>(src, dst, ss, sd, e, m, E);         \
    edge_pass2<<<((E) + T - 1) / T, T, 0, stream>>>(dst, e, m, den, E);                 \
    edge_pass3<<<(int)(((long long)(E) * 64 + T - 1) / T), T, 0, stream>>>(src, dst, e, den, Z, acc, E);

    EDGE3(src_p2p, dst_p2p, ss_p2p, sd_p2p, e_p2p, m_p2p, den_p2p, z_p2p, outP, E_p2p)
    EDGE3(src_a2p, dst_a2p, ss_a2p, sd_a2p, e_a2p, m_a2p, den_a2p, z_a2p, outP, E_a2p)
    EDGE3(src_p2a, dst_p2a, ss_p2a, sd_p2a, e_p2a, m_p2a, den_p2a, z_p2a, outA, E_p2a)
    EDGE3(src_a2a, dst_a2a, ss_a2a, sd_a2a, e_a2a, m_a2a, den_a2a, z_a2a, outA, E_a2a)
#undef EDGE3

    // ---- state (single-segment) GATs ----
    int gS1 = (E_p2s + T - 1) / T, gS2 = (E_a2s + T - 1) / T;
    state_pass1<<<gS1, T, 0, stream>>>(src_p2s, ss_p2s, &sdst2[0], e_p2s, m_p2s, E_p2s);
    state_pass2<<<gS1, T, 0, stream>>>(e_p2s, m_p2s, den_p2s, E_p2s);
    state_pass3<<<128, T, 0, stream>>>(src_p2s, e_p2s, den_p2s, z_p2s, outS, E_p2s);
    state_pass1<<<gS2, T, 0, stream>>>(src_a2s, ss_a2s, &sdst2[1], e_a2s, m_a2s, E_a2s);
    state_pass2<<<gS2, T, 0, stream>>>(e_a2s, m_a2s, den_a2s, E_a2s);
    state_pass3<<<128, T, 0, stream>>>(src_a2s, e_a2s, den_a2s, z_a2s, outS, E_a2s);

    // ---- final relu over the whole output ----
    int n_out = out_size;
    relu_inplace<<<(n_out + T - 1) / T, T, 0, stream>>>(out, n_out);
}

// Round 2
// 706.181 us; speedup vs baseline: 1.4525x; 1.4525x over previous
//
#include <hip/hip_runtime.h>
#include <math.h>

#define ALPHA 0.2f
#define NP 50000
#define NA 25000

__device__ __forceinline__ void atomicMaxF(float* addr, float val) {
    if (val >= 0.f) atomicMax((int*)addr, __float_as_int(val));
    else            atomicMin((unsigned int*)addr, __float_as_uint(val));
}

__global__ void fill_f32(float* __restrict__ p, float v, int n) {
    int i = blockIdx.x * blockDim.x + threadIdx.x;
    if (i < n) p[i] = v;
}
__global__ void fill_i32(int* __restrict__ p, int v, int n) {
    int i = blockIdx.x * blockDim.x + threadIdx.x;
    if (i < n) p[i] = v;
}

// Z = X @ W + b, plus optional row-dots s0[row]=dot(Zrow,a0), s1[row]=dot(Zrow,a1)
__global__ void xform_dot(const float* __restrict__ X, const float* __restrict__ W,
                          const float* __restrict__ b, float* __restrict__ Z,
                          const float* __restrict__ a0, float* __restrict__ s0,
                          const float* __restrict__ a1, float* __restrict__ s1, int N) {
    __shared__ float Ws[64][64];
    __shared__ float Xs[4][64];
    int tid = threadIdx.x;                 // 256 threads = 4 waves; wave r owns row r
#pragma unroll
    for (int i = 0; i < 16; ++i) {
        int idx = tid + i * 256;           // 0..4095
        Ws[idx >> 6][idx & 63] = W[idx];
    }
    int r = tid >> 6, c = tid & 63;
    int row = blockIdx.x * 4 + r;
    Xs[r][c] = (row < N) ? X[row * 64 + c] : 0.f;
    __syncthreads();
    float acc = b[c];
#pragma unroll
    for (int k = 0; k < 64; ++k) acc = fmaf(Xs[r][k], Ws[k][c], acc);
    if (row < N) {
        Z[(long long)row * 64 + c] = acc;
        if (s0) {
            float v = acc * a0[c];
#pragma unroll
            for (int o = 32; o > 0; o >>= 1) v += __shfl_down(v, o, 64);
            if (c == 0) s0[row] = v;
        }
        if (s1) {
            float v = acc * a1[c];
#pragma unroll
            for (int o = 32; o > 0; o >>= 1) v += __shfl_down(v, o, 64);
            if (c == 0) s1[row] = v;
        }
    }
}

// ---------------- counting sort by dst (concatenated across 4 edge types) ----------------
__global__ void hist_k(const int* __restrict__ dst, int* __restrict__ cnt, int E) {
    int k = blockIdx.x * blockDim.x + threadIdx.x;
    if (k < E) atomicAdd(&cnt[dst[k]], 1);
}

// per-block exclusive scan of 256 elements, block totals to bsum
__global__ void scan_k1(const int* __restrict__ cnt, int* __restrict__ off,
                        int* __restrict__ bsum, int n) {
    __shared__ int s[256];
    int t = threadIdx.x;
    int i = blockIdx.x * 256 + t;
    int v = (i < n) ? cnt[i] : 0;
    s[t] = v;
    __syncthreads();
    for (int o = 1; o < 256; o <<= 1) {
        int x = (t >= o) ? s[t - o] : 0;
        __syncthreads();
        s[t] += x;
        __syncthreads();
    }
    if (i < n) off[i] = s[t] - v;          // exclusive within block
    if (t == 255) bsum[blockIdx.x] = s[255];
}

// single-block exclusive scan of block sums (nb <= 1024)
__global__ void scan_k2(int* __restrict__ bsum, int nb) {
    __shared__ int s[1024];
    int t = threadIdx.x;
    int v = (t < nb) ? bsum[t] : 0;
    s[t] = v;
    __syncthreads();
    for (int o = 1; o < 1024; o <<= 1) {
        int x = (t >= o) ? s[t - o] : 0;
        __syncthreads();
        s[t] += x;
        __syncthreads();
    }
    if (t < nb) bsum[t] = s[t] - v;
}

__global__ void scan_k3(int* __restrict__ off, int* __restrict__ cursor,
                        const int* __restrict__ bsum, int n, int total) {
    int i = blockIdx.x * 256 + threadIdx.x;
    if (i < n) {
        int v = off[i] + bsum[blockIdx.x];
        off[i] = v;
        cursor[i] = v;
    }
    if (i == 0) off[n] = total;
}

__global__ void scatter_k(const int* __restrict__ src, const int* __restrict__ dst,
                          int* __restrict__ cursor, int* __restrict__ ssrc, int E) {
    int k = blockIdx.x * blockDim.x + threadIdx.x;
    if (k >= E) return;
    int pos = atomicAdd(&cursor[dst[k]], 1);
    ssrc[pos] = src[k];
}

// ---------------- fused per-dst GAT (wave per destination node) ----------------
__device__ __forceinline__ float seg_gat(int d, const int* __restrict__ off,
                                         const int* __restrict__ ssrc,
                                         const float* __restrict__ ss, float sd,
                                         const float* __restrict__ z, int lane) {
    int s0 = off[d], s1 = off[d + 1];
    if (s0 >= s1) return 0.f;
    // phase 1: segment max
    float m = -INFINITY;
    for (int i = s0 + lane; i < s1; i += 64) {
        float e = ss[ssrc[i]] + sd;
        e = e > 0.f ? e : ALPHA * e;
        m = fmaxf(m, e);
    }
#pragma unroll
    for (int o = 32; o > 0; o >>= 1) m = fmaxf(m, __shfl_xor(m, o, 64));
    // phase 2: denominator
    float den = 0.f;
    for (int i = s0 + lane; i < s1; i += 64) {
        float e = ss[ssrc[i]] + sd;
        e = e > 0.f ? e : ALPHA * e;
        den += __expf(e - m);
    }
#pragma unroll
    for (int o = 32; o > 0; o >>= 1) den += __shfl_xor(den, o, 64);
    float inv = 1.f / den;
    // phase 3: weighted gather-accumulate
    float acc = 0.f;
    for (int c = s0; c < s1; c += 64) {
        int i = c + lane;
        float w = 0.f;
        int s = 0;
        if (i < s1) {
            float e = ss[ssrc[i]] + sd;
            e = e > 0.f ? e : ALPHA * e;
            w = __expf(e - m) * inv;
            s = ssrc[i];
        }
        int cnt = min(64, s1 - c);
        for (int t = 0; t < cnt; ++t) {
            float wt = __shfl(w, t, 64);
            int st = __shfl(s, t, 64);
            acc = fmaf(wt, z[(long long)st * 64 + lane], acc);
        }
    }
    return acc;
}

__global__ void gat_dst(const float* __restrict__ Wh, float* __restrict__ out, int N,
                        const int* __restrict__ off, const int* __restrict__ ssrc,
                        int base0, const float* __restrict__ ss0,
                        const float* __restrict__ sd0, const float* __restrict__ z0,
                        int base1, const float* __restrict__ ss1,
                        const float* __restrict__ sd1, const float* __restrict__ z1) {
    int lane = threadIdx.x & 63;
    int d = (blockIdx.x * blockDim.x + threadIdx.x) >> 6;
    if (d >= N) return;                    // whole wave exits
    float acc = Wh[(long long)d * 64 + lane];
    acc += seg_gat(d, off + base0, ssrc, ss0, sd0[d], z0, lane);
    acc += seg_gat(d, off + base1, ssrc, ss1, sd1[d], z1, lane);
    out[(long long)d * 64 + lane] = fmaxf(acc, 0.f);
}

// ---------------- state (single destination) path ----------------
__global__ void state_prep(const float* __restrict__ fS, const float* __restrict__ W_in,
                           const float* __restrict__ b_in, const float* __restrict__ a_p2s,
                           const float* __restrict__ a_a2s, float* __restrict__ outS,
                           float* __restrict__ sdst2) {
    int c = threadIdx.x;
    float acc = b_in[c];
    for (int k = 0; k < 64; ++k) acc = fmaf(fS[k], W_in[k * 64 + c], acc);
    outS[c] = acc;
    float v0 = acc * a_p2s[64 + c];
    float v1 = acc * a_a2s[64 + c];
#pragma unroll
    for (int off = 32; off > 0; off >>= 1) {
        v0 += __shfl_down(v0, off, 64);
        v1 += __shfl_down(v1, off, 64);
    }
    if (c == 0) { sdst2[0] = v0; sdst2[1] = v1; }
}

__global__ void state_pass1(const int* __restrict__ src, const float* __restrict__ s_src,
                            const float* __restrict__ sdst, float* __restrict__ e,
                            float* __restrict__ m, int N) {
    int i = blockIdx.x * blockDim.x + threadIdx.x;
    float v = -INFINITY;
    if (i < N) {
        v = s_src[src[i]] + *sdst;
        v = v > 0.f ? v : ALPHA * v;
        e[i] = v;
    }
#pragma unroll
    for (int off = 32; off > 0; off >>= 1) v = fmaxf(v, __shfl_down(v, off, 64));
    if ((threadIdx.x & 63) == 0) atomicMaxF(m, v);
}

__global__ void state_pass2(float* __restrict__ e, const float* __restrict__ m,
                            float* __restrict__ den, int N) {
    int i = blockIdx.x * blockDim.x + threadIdx.x;
    float ex = 0.f;
    if (i < N) {
        ex = __expf(e[i] - *m);
        e[i] = ex;
    }
#pragma unroll
    for (int off = 32; off > 0; off >>= 1) ex += __shfl_down(ex, off, 64);
    if ((threadIdx.x & 63) == 0) atomicAdd(den, ex);
}

__global__ void state_pass3(const int* __restrict__ src, const float* __restrict__ ex,
                            const float* __restrict__ den, const float* __restrict__ Z,
                            float* __restrict__ outS, int N) {
    __shared__ float red[4][64];
    int lane = threadIdx.x & 63;
    int wv = threadIdx.x >> 6;
    int gw = blockIdx.x * 4 + wv;
    int nw = gridDim.x * 4;
    float dn = *den;
    float acc = 0.f;
    for (int i = gw; i < N; i += nw)
        acc += (ex[i] / dn) * Z[(long long)src[i] * 64 + lane];
    red[wv][lane] = acc;
    __syncthreads();
    if (wv == 0) {
        float t = red[0][lane] + red[1][lane] + red[2][lane] + red[3][lane];
        atomicAdd(&outS[lane], t);
    }
}

__global__ void relu_inplace(float* __restrict__ p, int n) {
    int i = blockIdx.x * blockDim.x + threadIdx.x;
    if (i < n) p[i] = fmaxf(p[i], 0.f);
}

extern "C" void kernel_launch(void* const* d_in, const int* in_sizes, int n_in,
                              void* d_out, int out_size, void* d_ws, size_t ws_size,
                              hipStream_t stream) {
    const float* feat_P = (const float*)d_in[0];
    const float* feat_A = (const float*)d_in[1];
    const float* feat_S = (const float*)d_in[2];
    const float* W_P   = (const float*)d_in[3];  const float* b_P   = (const float*)d_in[4];
    const float* W_A   = (const float*)d_in[5];  const float* b_A   = (const float*)d_in[6];
    const float* W_p2p = (const float*)d_in[7];  const float* b_p2p = (const float*)d_in[8];
    const float* W_p2a = (const float*)d_in[9];  const float* b_p2a = (const float*)d_in[10];
    const float* W_a2p = (const float*)d_in[11]; const float* b_a2p = (const float*)d_in[12];
    const float* W_a2a = (const float*)d_in[13]; const float* b_a2a = (const float*)d_in[14];
    const float* W_p2s = (const float*)d_in[15]; const float* b_p2s = (const float*)d_in[16];
    const float* W_a2s = (const float*)d_in[17]; const float* b_a2s = (const float*)d_in[18];
    const float* W_in  = (const float*)d_in[19]; const float* b_in  = (const float*)d_in[20];
    const float* a_p2p = (const float*)d_in[21];
    const float* a_p2a = (const float*)d_in[22];
    const float* a_a2p = (const float*)d_in[23];
    const float* a_a2a = (const float*)d_in[24];
    const float* a_p2s = (const float*)d_in[25];
    const float* a_a2s = (const float*)d_in[26];
    const int* src_p2p = (const int*)d_in[27]; const int* dst_p2p = (const int*)d_in[28];
    const int* src_p2a = (const int*)d_in[29]; const int* dst_p2a = (const int*)d_in[30];
    const int* src_a2p = (const int*)d_in[31]; const int* dst_a2p = (const int*)d_in[32];
    const int* src_a2a = (const int*)d_in[33]; const int* dst_a2a = (const int*)d_in[34];
    const int* src_p2s = (const int*)d_in[35];
    const int* src_a2s = (const int*)d_in[37];
    int E_p2p = in_sizes[27], E_p2a = in_sizes[29], E_a2p = in_sizes[31], E_a2a = in_sizes[33];
    int E_p2s = in_sizes[35], E_a2s = in_sizes[37];
    int E_tot = E_p2p + E_a2p + E_p2a + E_a2a;

    float* out = (float*)d_out;
    float* outP = out;
    float* outA = out + (long long)NP * 64;
    float* outS = out + (long long)(NP + NA) * 64;

    // ---- workspace layout ----
    float* ws = (float*)d_ws;
    float* WhP   = ws; ws += (long long)NP * 64;
    float* WhA   = ws; ws += (long long)NA * 64;
    float* z_p2p = ws; ws += (long long)NP * 64;
    float* z_p2a = ws; ws += (long long)NP * 64;
    float* z_p2s = ws; ws += (long long)NP * 64;
    float* z_a2p = ws; ws += (long long)NA * 64;
    float* z_a2a = ws; ws += (long long)NA * 64;
    float* z_a2s = ws; ws += (long long)NA * 64;
    float* ss_p2p = ws; ws += NP;  float* sd_p2p = ws; ws += NP;
    float* ss_p2a = ws; ws += NP;  float* sd_p2a = ws; ws += NA;
    float* ss_a2p = ws; ws += NA;  float* sd_a2p = ws; ws += NP;
    float* ss_a2a = ws; ws += NA;  float* sd_a2a = ws; ws += NA;
    float* ss_p2s = ws; ws += NP;
    float* ss_a2s = ws; ws += NA;
    float* sdst2  = ws; ws += 2;
    float* m2     = ws; ws += 2;   // m_p2s, m_a2s
    float* den2   = ws; ws += 2;   // den_p2s, den_a2s
    float* e_p2s  = ws; ws += NP;
    float* e_a2s  = ws; ws += NA;
    // int region
    int* iw = (int*)ws;
    const int NTOT = 2 * NP + 2 * NA;          // 150000 concat dst bins
    int* cnt_all = iw; iw += NTOT;
    int* off_all = iw; iw += NTOT + 1;
    int* cursor  = iw; iw += NTOT;
    int* bsum    = iw; iw += 1024;
    int* ssrc    = iw; iw += E_tot;            // dst-sorted src indices (global positions)

    const int T = 256;
    const int B_p2p = 0, B_a2p = NP, B_p2a = 2 * NP, B_a2a = 2 * NP + NA;

    // ---- init ----
    fill_i32<<<(NTOT + T - 1) / T, T, 0, stream>>>(cnt_all, 0, NTOT);
    fill_f32<<<1, 64, 0, stream>>>(m2, -INFINITY, 2);
    fill_f32<<<1, 64, 0, stream>>>(den2, 0.f, 2);

    // ---- dense transforms with fused attention row-dots ----
    int gP = (NP + 3) / 4, gA = (NA + 3) / 4;
    xform_dot<<<gP, T, 0, stream>>>(feat_P, W_P,   b_P,   WhP,   a_p2p + 64, sd_p2p, a_a2p + 64, sd_a2p, NP);
    xform_dot<<<gA, T, 0, stream>>>(feat_A, W_A,   b_A,   WhA,   a_p2a + 64, sd_p2a, a_a2a + 64, sd_a2a, NA);
    xform_dot<<<gP, T, 0, stream>>>(feat_P, W_p2p, b_p2p, z_p2p, a_p2p,      ss_p2p, nullptr, nullptr, NP);
    xform_dot<<<gP, T, 0, stream>>>(feat_P, W_p2a, b_p2a, z_p2a, a_p2a,      ss_p2a, nullptr, nullptr, NP);
    xform_dot<<<gP, T, 0, stream>>>(feat_P, W_p2s, b_p2s, z_p2s, a_p2s,      ss_p2s, nullptr, nullptr, NP);
    xform_dot<<<gA, T, 0, stream>>>(feat_A, W_a2p, b_a2p, z_a2p, a_a2p,      ss_a2p, nullptr, nullptr, NA);
    xform_dot<<<gA, T, 0, stream>>>(feat_A, W_a2a, b_a2a, z_a2a, a_a2a,      ss_a2a, nullptr, nullptr, NA);
    xform_dot<<<gA, T, 0, stream>>>(feat_A, W_a2s, b_a2s, z_a2s, a_a2s,      ss_a2s, nullptr, nullptr, NA);
    state_prep<<<1, 64, 0, stream>>>(feat_S, W_in, b_in, a_p2s, a_a2s, outS, sdst2);

    // ---- counting sort by destination (all 4 big edge types concatenated) ----
    hist_k<<<(E_p2p + T - 1) / T, T, 0, stream>>>(dst_p2p, cnt_all + B_p2p, E_p2p);
    hist_k<<<(E_a2p + T - 1) / T, T, 0, stream>>>(dst_a2p, cnt_all + B_a2p, E_a2p);
    hist_k<<<(E_p2a + T - 1) / T, T, 0, stream>>>(dst_p2a, cnt_all + B_p2a, E_p2a);
    hist_k<<<(E_a2a + T - 1) / T, T, 0, stream>>>(dst_a2a, cnt_all + B_a2a, E_a2a);

    int nScanB = (NTOT + 255) / 256;           // 586
    scan_k1<<<nScanB, 256, 0, stream>>>(cnt_all, off_all, bsum, NTOT);
    scan_k2<<<1, 1024, 0, stream>>>(bsum, nScanB);
    scan_k3<<<nScanB, 256, 0, stream>>>(off_all, cursor, bsum, NTOT, E_tot);

    scatter_k<<<(E_p2p + T - 1) / T, T, 0, stream>>>(src_p2p, dst_p2p, cursor + B_p2p, ssrc, E_p2p);
    scatter_k<<<(E_a2p + T - 1) / T, T, 0, stream>>>(src_a2p, dst_a2p, cursor + B_a2p, ssrc, E_a2p);
    scatter_k<<<(E_p2a + T - 1) / T, T, 0, stream>>>(src_p2a, dst_p2a, cursor + B_p2a, ssrc, E_p2a);
    scatter_k<<<(E_a2a + T - 1) / T, T, 0, stream>>>(src_a2a, dst_a2a, cursor + B_a2a, ssrc, E_a2a);

    // ---- fused per-destination GAT + self + relu ----
    gat_dst<<<(NP * 64 + T - 1) / T, T, 0, stream>>>(WhP, outP, NP, off_all, ssrc,
            B_p2p, ss_p2p, sd_p2p, z_p2p,
            B_a2p, ss_a2p, sd_a2p, z_a2p);
    gat_dst<<<(NA * 64 + T - 1) / T, T, 0, stream>>>(WhA, outA, NA, off_all, ssrc,
            B_p2a, ss_p2a, sd_p2a, z_p2a,
            B_a2a, ss_a2a, sd_a2a, z_a2a);

    // ---- state GATs (dense src lists, single segment) ----
    int gS1 = (E_p2s + T - 1) / T, gS2 = (E_a2s + T - 1) / T;
    state_pass1<<<gS1, T, 0, stream>>>(src_p2s, ss_p2s, &sdst2[0], e_p2s, &m2[0], E_p2s);
    state_pass2<<<gS1, T, 0, stream>>>(e_p2s, &m2[0], &den2[0], E_p2s);
    state_pass3<<<128, T, 0, stream>>>(src_p2s, e_p2s, &den2[0], z_p2s, outS, E_p2s);
    state_pass1<<<gS2, T, 0, stream>>>(src_a2s, ss_a2s, &sdst2[1], e_a2s, &m2[1], E_a2s);
    state_pass2<<<gS2, T, 0, stream>>>(e_a2s, &m2[1], &den2[1], E_a2s);
    state_pass3<<<128, T, 0, stream>>>(src_a2s, e_a2s, &den2[1], z_a2s, outS, E_a2s);

    relu_inplace<<<1, 64, 0, stream>>>(outS, 64);
}

// Round 3
// 579.640 us; speedup vs baseline: 1.7696x; 1.2183x over previous
//
#include <hip/hip_runtime.h>
#include <math.h>

#define ALPHA 0.2f
#define NP 50000
#define NA 25000

typedef unsigned short u16;

__device__ __forceinline__ float bf2f(u16 u) { return __uint_as_float(((unsigned)u) << 16); }
__device__ __forceinline__ u16 f2bf(float f) {
    unsigned x = __float_as_uint(f);
    return (u16)((x + 0x7fffu + ((x >> 16) & 1u)) >> 16);   // RNE
}

__device__ __forceinline__ void atomicMaxF(float* addr, float val) {
    if (val >= 0.f) atomicMax((int*)addr, __float_as_int(val));
    else            atomicMin((unsigned int*)addr, __float_as_uint(val));
}

// ---------------- fused 4-matrix transform + attention dots ----------------
// Per node type: a0 = X@W0+b0 (f32 -> Wh, two dst-half dots), a1..a3 = X@Wi+bi
// (bf16 -> zi, one src-half dot each). 256 thr, 32 rows/block.
__global__ __launch_bounds__(256) void xform4(
    const float* __restrict__ X, int N,
    const float* __restrict__ W0, const float* __restrict__ b0, float* __restrict__ Wh,
    const float* __restrict__ dA, float* __restrict__ sdA,
    const float* __restrict__ dB, float* __restrict__ sdB,
    const float* __restrict__ W1, const float* __restrict__ b1, u16* __restrict__ z1,
    const float* __restrict__ v1, float* __restrict__ s1,
    const float* __restrict__ W2, const float* __restrict__ b2, u16* __restrict__ z2,
    const float* __restrict__ v2, float* __restrict__ s2,
    const float* __restrict__ W3, const float* __restrict__ b3, u16* __restrict__ z3,
    const float* __restrict__ v3, float* __restrict__ s3)
{
    __shared__ float Ws[4][4096];
    int tid = threadIdx.x;
    for (int i = tid; i < 4096; i += 256) {
        Ws[0][i] = W0[i]; Ws[1][i] = W1[i]; Ws[2][i] = W2[i]; Ws[3][i] = W3[i];
    }
    __syncthreads();
    int wv = tid >> 6, lane = tid & 63;
    float bb0 = b0[lane], bb1 = b1[lane], bb2 = b2[lane], bb3 = b3[lane];
    float da = dA[lane], db = dB[lane], dv1 = v1[lane], dv2 = v2[lane], dv3 = v3[lane];
    for (int it = 0; it < 8; ++it) {
        int row = blockIdx.x * 32 + it * 4 + wv;
        if (row >= N) break;                       // wave-uniform
        float xv = X[(long long)row * 64 + lane];
        float a0 = bb0, a1 = bb1, a2 = bb2, a3 = bb3;
#pragma unroll
        for (int k = 0; k < 64; ++k) {
            float xk = __shfl(xv, k, 64);
            a0 = fmaf(xk, Ws[0][k * 64 + lane], a0);
            a1 = fmaf(xk, Ws[1][k * 64 + lane], a1);
            a2 = fmaf(xk, Ws[2][k * 64 + lane], a2);
            a3 = fmaf(xk, Ws[3][k * 64 + lane], a3);
        }
        long long o = (long long)row * 64 + lane;
        Wh[o] = a0;
        z1[o] = f2bf(a1); z2[o] = f2bf(a2); z3[o] = f2bf(a3);
        float t0 = a0 * da, t1 = a0 * db, t2 = a1 * dv1, t3 = a2 * dv2, t4 = a3 * dv3;
#pragma unroll
        for (int of = 32; of > 0; of >>= 1) {
            t0 += __shfl_xor(t0, of, 64); t1 += __shfl_xor(t1, of, 64);
            t2 += __shfl_xor(t2, of, 64); t3 += __shfl_xor(t3, of, 64);
            t4 += __shfl_xor(t4, of, 64);
        }
        if (lane == 0) { sdA[row] = t0; sdB[row] = t1; s1[row] = t2; s2[row] = t3; s3[row] = t4; }
    }
}

// ---------------- counting sort by dst, all 4 edge types in one pass ----------------
__global__ void hist_all(const int* __restrict__ d0, int E0, const int* __restrict__ d1, int E1,
                         const int* __restrict__ d2, int E2, const int* __restrict__ d3, int E3,
                         int* __restrict__ cnt) {
    int k = blockIdx.x * blockDim.x + threadIdx.x;
    if (k < E0) { atomicAdd(&cnt[d0[k]], 1); return; }
    k -= E0; if (k < E1) { atomicAdd(&cnt[NP + d1[k]], 1); return; }
    k -= E1; if (k < E2) { atomicAdd(&cnt[2 * NP + d2[k]], 1); return; }
    k -= E2; if (k < E3) { atomicAdd(&cnt[2 * NP + NA + d3[k]], 1); return; }
}

__global__ void scan_k1(const int* __restrict__ cnt, int* __restrict__ off,
                        int* __restrict__ bsum, int n) {
    __shared__ int s[256];
    int t = threadIdx.x;
    int i = blockIdx.x * 256 + t;
    int v = (i < n) ? cnt[i] : 0;
    s[t] = v;
    __syncthreads();
    for (int o = 1; o < 256; o <<= 1) {
        int x = (t >= o) ? s[t - o] : 0;
        __syncthreads();
        s[t] += x;
        __syncthreads();
    }
    if (i < n) off[i] = s[t] - v;
    if (t == 255) bsum[blockIdx.x] = s[255];
}

__global__ void scan_k2(int* __restrict__ bsum, int nb) {
    __shared__ int s[1024];
    int t = threadIdx.x;
    int v = (t < nb) ? bsum[t] : 0;
    s[t] = v;
    __syncthreads();
    for (int o = 1; o < 1024; o <<= 1) {
        int x = (t >= o) ? s[t - o] : 0;
        __syncthreads();
        s[t] += x;
        __syncthreads();
    }
    if (t < nb) bsum[t] = s[t] - v;
}

__global__ void scan_k3(int* __restrict__ off, int* __restrict__ cursor,
                        const int* __restrict__ bsum, int n, int total) {
    int i = blockIdx.x * 256 + threadIdx.x;
    if (i < n) {
        int v = off[i] + bsum[blockIdx.x];
        off[i] = v;
        cursor[i] = v;
    }
    if (i == 0) off[n] = total;
}

__global__ void scatter_all(const int* __restrict__ s0, const int* __restrict__ d0, int E0,
                            const int* __restrict__ s1, const int* __restrict__ d1, int E1,
                            const int* __restrict__ s2, const int* __restrict__ d2, int E2,
                            const int* __restrict__ s3, const int* __restrict__ d3, int E3,
                            int* __restrict__ cursor, int* __restrict__ ssrc) {
    int k = blockIdx.x * blockDim.x + threadIdx.x;
    const int* sp; const int* dp; int B;
    if (k < E0) { sp = s0; dp = d0; B = 0; }
    else {
        k -= E0;
        if (k < E1) { sp = s1; dp = d1; B = NP; }
        else {
            k -= E1;
            if (k < E2) { sp = s2; dp = d2; B = 2 * NP; }
            else {
                k -= E2;
                if (k < E3) { sp = s3; dp = d3; B = 2 * NP + NA; }
                else return;
            }
        }
    }
    int pos = atomicAdd(&cursor[B + dp[k]], 1);
    ssrc[pos] = sp[k];
}

// ---------------- fused per-dst GAT (wave per destination node) ----------------
// Layout: lane = egrp(2b) x cgrp(4b); 4 edges in flight, ushort4 bf16 loads.
__device__ __forceinline__ void seg_gat4(int d, const int* __restrict__ off,
                                         const int* __restrict__ ssrc,
                                         const float* __restrict__ ss, float sd,
                                         const u16* __restrict__ z, int lane,
                                         float4& acc) {
    int s0 = off[d], s1 = off[d + 1];
    int cnt = s1 - s0;
    if (cnt <= 0) return;
    int egrp = lane >> 4, cg4 = (lane & 15) * 4;
    if (cnt <= 64) {                    // fast path: whole segment in registers
        int s = 0; float e = -INFINITY;
        if (lane < cnt) {
            s = ssrc[s0 + lane];
            e = ss[s] + sd;
            e = e > 0.f ? e : ALPHA * e;
        }
        float m = e;
#pragma unroll
        for (int o = 32; o > 0; o >>= 1) m = fmaxf(m, __shfl_xor(m, o, 64));
        float w = (lane < cnt) ? __expf(e - m) : 0.f;
        float den = w;
#pragma unroll
        for (int o = 32; o > 0; o >>= 1) den += __shfl_xor(den, o, 64);
        w *= 1.f / den;
        int nit = (cnt + 3) >> 2;
        for (int it = 0; it < nit; ++it) {
            int ei = it * 4 + egrp;
            float wt = __shfl(w, ei, 64);
            int   st = __shfl(s, ei, 64);
            ushort4 q = *(const ushort4*)(z + (long long)st * 64 + cg4);
            acc.x = fmaf(wt, bf2f(q.x), acc.x);
            acc.y = fmaf(wt, bf2f(q.y), acc.y);
            acc.z = fmaf(wt, bf2f(q.z), acc.z);
            acc.w = fmaf(wt, bf2f(q.w), acc.w);
        }
    } else {                            // general path (rare)
        float m = -INFINITY;
        for (int i = s0 + lane; i < s1; i += 64) {
            float e = ss[ssrc[i]] + sd; e = e > 0.f ? e : ALPHA * e; m = fmaxf(m, e);
        }
#pragma unroll
        for (int o = 32; o > 0; o >>= 1) m = fmaxf(m, __shfl_xor(m, o, 64));
        float den = 0.f;
        for (int i = s0 + lane; i < s1; i += 64) {
            float e = ss[ssrc[i]] + sd; e = e > 0.f ? e : ALPHA * e; den += __expf(e - m);
        }
#pragma unroll
        for (int o = 32; o > 0; o >>= 1) den += __shfl_xor(den, o, 64);
        float inv = 1.f / den;
        for (int c = s0; c < s1; c += 64) {
            int i = c + lane; int s = 0; float w = 0.f;
            if (i < s1) {
                s = ssrc[i];
                float e = ss[s] + sd; e = e > 0.f ? e : ALPHA * e;
                w = __expf(e - m) * inv;
            }
            int cc = min(64, s1 - c);
            int nit = (cc + 3) >> 2;
            for (int it = 0; it < nit; ++it) {
                int ei = it * 4 + egrp;
                float wt = __shfl(w, ei, 64);
                int   st = __shfl(s, ei, 64);
                ushort4 q = *(const ushort4*)(z + (long long)st * 64 + cg4);
                acc.x = fmaf(wt, bf2f(q.x), acc.x);
                acc.y = fmaf(wt, bf2f(q.y), acc.y);
                acc.z = fmaf(wt, bf2f(q.z), acc.z);
                acc.w = fmaf(wt, bf2f(q.w), acc.w);
            }
        }
    }
}

__global__ __launch_bounds__(256) void gat_dst(
        const float* __restrict__ Wh, float* __restrict__ out, int N,
        const int* __restrict__ off, const int* __restrict__ ssrc,
        int base0, const float* __restrict__ ss0, const float* __restrict__ sd0,
        const u16* __restrict__ z0,
        int base1, const float* __restrict__ ss1, const float* __restrict__ sd1,
        const u16* __restrict__ z1) {
    int lane = threadIdx.x & 63;
    int d = (blockIdx.x * blockDim.x + threadIdx.x) >> 6;
    if (d >= N) return;                 // wave-uniform
    float4 acc = {0.f, 0.f, 0.f, 0.f};
    seg_gat4(d, off + base0, ssrc, ss0, sd0[d], z0, lane, acc);
    seg_gat4(d, off + base1, ssrc, ss1, sd1[d], z1, lane, acc);
#pragma unroll
    for (int o = 16; o <= 32; o <<= 1) {
        acc.x += __shfl_xor(acc.x, o, 64);
        acc.y += __shfl_xor(acc.y, o, 64);
        acc.z += __shfl_xor(acc.z, o, 64);
        acc.w += __shfl_xor(acc.w, o, 64);
    }
    if (lane < 16) {
        float4 self = *(const float4*)&Wh[(long long)d * 64 + lane * 4];
        float4 r;
        r.x = fmaxf(self.x + acc.x, 0.f);
        r.y = fmaxf(self.y + acc.y, 0.f);
        r.z = fmaxf(self.z + acc.z, 0.f);
        r.w = fmaxf(self.w + acc.w, 0.f);
        *(float4*)&out[(long long)d * 64 + lane * 4] = r;
    }
}

// ---------------- state (single destination) path ----------------
__global__ void state_prep(const float* __restrict__ fS, const float* __restrict__ W_in,
                           const float* __restrict__ b_in, const float* __restrict__ a_p2s,
                           const float* __restrict__ a_a2s, float* __restrict__ outS,
                           float* __restrict__ sdst2, float* __restrict__ m2,
                           float* __restrict__ den2) {
    int c = threadIdx.x;
    if (c < 2) { m2[c] = -INFINITY; den2[c] = 0.f; }
    float acc = b_in[c];
    for (int k = 0; k < 64; ++k) acc = fmaf(fS[k], W_in[k * 64 + c], acc);
    outS[c] = acc;
    float v0 = acc * a_p2s[64 + c];
    float v1 = acc * a_a2s[64 + c];
#pragma unroll
    for (int off = 32; off > 0; off >>= 1) {
        v0 += __shfl_down(v0, off, 64);
        v1 += __shfl_down(v1, off, 64);
    }
    if (c == 0) { sdst2[0] = v0; sdst2[1] = v1; }
}

__global__ void state_e(const int* __restrict__ srcP, const float* __restrict__ ssP,
                        const int* __restrict__ srcA, const float* __restrict__ ssA,
                        const float* __restrict__ sdst2, float* __restrict__ eP,
                        float* __restrict__ eA, float* __restrict__ m2,
                        int EP, int EA, int nbP) {
    bool isP = (int)blockIdx.x < nbP;
    int bid = isP ? blockIdx.x : blockIdx.x - nbP;
    int i = bid * 256 + threadIdx.x;
    int E = isP ? EP : EA;
    float v = -INFINITY;
    if (i < E) {
        const int* src = isP ? srcP : srcA;
        const float* ss = isP ? ssP : ssA;
        float e = ss[src[i]] + sdst2[isP ? 0 : 1];
        e = e > 0.f ? e : ALPHA * e;
        (isP ? eP : eA)[i] = e;
        v = e;
    }
#pragma unroll
    for (int o = 32; o > 0; o >>= 1) v = fmaxf(v, __shfl_xor(v, o, 64));
    if ((threadIdx.x & 63) == 0) atomicMaxF(&m2[isP ? 0 : 1], v);
}

__global__ void state_den(float* __restrict__ eP, float* __restrict__ eA,
                          const float* __restrict__ m2, float* __restrict__ den2,
                          int EP, int EA, int nbP) {
    bool isP = (int)blockIdx.x < nbP;
    int bid = isP ? blockIdx.x : blockIdx.x - nbP;
    int i = bid * 256 + threadIdx.x;
    int E = isP ? EP : EA;
    float ex = 0.f;
    if (i < E) {
        float* e = isP ? eP : eA;
        ex = __expf(e[i] - m2[isP ? 0 : 1]);
        e[i] = ex;
    }
#pragma unroll
    for (int o = 32; o > 0; o >>= 1) ex += __shfl_xor(ex, o, 64);
    if ((threadIdx.x & 63) == 0) atomicAdd(&den2[isP ? 0 : 1], ex);
}

__global__ void state_acc(const int* __restrict__ srcP, const float* __restrict__ eP,
                          const u16* __restrict__ zP, int EP,
                          const int* __restrict__ srcA, const float* __restrict__ eA,
                          const u16* __restrict__ zA, int EA,
                          const float* __restrict__ den2, float* __restrict__ outS, int nbP) {
    __shared__ float red[4][64];
    bool isP = (int)blockIdx.x < nbP;
    const int* src = isP ? srcP : srcA;
    const float* e = isP ? eP : eA;
    const u16* z = isP ? zP : zA;
    int E = isP ? EP : EA;
    float inv = 1.f / den2[isP ? 0 : 1];
    int bid = isP ? blockIdx.x : blockIdx.x - nbP;
    int nb = isP ? nbP : ((int)gridDim.x - nbP);
    int lane = threadIdx.x & 63, wv = threadIdx.x >> 6;
    int egrp = lane >> 4, cg4 = (lane & 15) * 4;
    int gw = bid * 4 + wv;
    int waves = nb * 4;
    float4 acc = {0.f, 0.f, 0.f, 0.f};
    for (int base = gw * 4; base < E; base += waves * 4) {
        int i = base + egrp;
        float w = (i < E) ? e[i] * inv : 0.f;
        int ri = (i < E) ? src[i] : 0;
        ushort4 q = *(const ushort4*)(z + (long long)ri * 64 + cg4);
        acc.x = fmaf(w, bf2f(q.x), acc.x);
        acc.y = fmaf(w, bf2f(q.y), acc.y);
        acc.z = fmaf(w, bf2f(q.z), acc.z);
        acc.w = fmaf(w, bf2f(q.w), acc.w);
    }
#pragma unroll
    for (int o = 16; o <= 32; o <<= 1) {
        acc.x += __shfl_xor(acc.x, o, 64);
        acc.y += __shfl_xor(acc.y, o, 64);
        acc.z += __shfl_xor(acc.z, o, 64);
        acc.w += __shfl_xor(acc.w, o, 64);
    }
    if (lane < 16) ((float4*)red[wv])[lane] = acc;
    __syncthreads();
    if (wv == 0) {
        float t = red[0][lane] + red[1][lane] + red[2][lane] + red[3][lane];
        atomicAdd(&outS[lane], t);
    }
}

__global__ void relu_small(float* __restrict__ p, int n) {
    int i = threadIdx.x;
    if (i < n) p[i] = fmaxf(p[i], 0.f);
}

extern "C" void kernel_launch(void* const* d_in, const int* in_sizes, int n_in,
                              void* d_out, int out_size, void* d_ws, size_t ws_size,
                              hipStream_t stream) {
    const float* feat_P = (const float*)d_in[0];
    const float* feat_A = (const float*)d_in[1];
    const float* feat_S = (const float*)d_in[2];
    const float* W_P   = (const float*)d_in[3];  const float* b_P   = (const float*)d_in[4];
    const float* W_A   = (const float*)d_in[5];  const float* b_A   = (const float*)d_in[6];
    const float* W_p2p = (const float*)d_in[7];  const float* b_p2p = (const float*)d_in[8];
    const float* W_p2a = (const float*)d_in[9];  const float* b_p2a = (const float*)d_in[10];
    const float* W_a2p = (const float*)d_in[11]; const float* b_a2p = (const float*)d_in[12];
    const float* W_a2a = (const float*)d_in[13]; const float* b_a2a = (const float*)d_in[14];
    const float* W_p2s = (const float*)d_in[15]; const float* b_p2s = (const float*)d_in[16];
    const float* W_a2s = (const float*)d_in[17]; const float* b_a2s = (const float*)d_in[18];
    const float* W_in  = (const float*)d_in[19]; const float* b_in  = (const float*)d_in[20];
    const float* a_p2p = (const float*)d_in[21];
    const float* a_p2a = (const float*)d_in[22];
    const float* a_a2p = (const float*)d_in[23];
    const float* a_a2a = (const float*)d_in[24];
    const float* a_p2s = (const float*)d_in[25];
    const float* a_a2s = (const float*)d_in[26];
    const int* src_p2p = (const int*)d_in[27]; const int* dst_p2p = (const int*)d_in[28];
    const int* src_p2a = (const int*)d_in[29]; const int* dst_p2a = (const int*)d_in[30];
    const int* src_a2p = (const int*)d_in[31]; const int* dst_a2p = (const int*)d_in[32];
    const int* src_a2a = (const int*)d_in[33]; const int* dst_a2a = (const int*)d_in[34];
    const int* src_p2s = (const int*)d_in[35];
    const int* src_a2s = (const int*)d_in[37];
    int E_p2p = in_sizes[27], E_p2a = in_sizes[29], E_a2p = in_sizes[31], E_a2a = in_sizes[33];
    int E_p2s = in_sizes[35], E_a2s = in_sizes[37];
    int E_tot = E_p2p + E_a2p + E_p2a + E_a2a;

    float* out = (float*)d_out;
    float* outP = out;
    float* outA = out + (long long)NP * 64;
    float* outS = out + (long long)(NP + NA) * 64;

    // ---- workspace layout ----
    float* ws = (float*)d_ws;
    float* WhP = ws; ws += (long long)NP * 64;
    float* WhA = ws; ws += (long long)NA * 64;
    u16* z_p2p = (u16*)ws; ws += (long long)NP * 32;
    u16* z_p2a = (u16*)ws; ws += (long long)NP * 32;
    u16* z_p2s = (u16*)ws; ws += (long long)NP * 32;
    u16* z_a2p = (u16*)ws; ws += (long long)NA * 32;
    u16* z_a2a = (u16*)ws; ws += (long long)NA * 32;
    u16* z_a2s = (u16*)ws; ws += (long long)NA * 32;
    float* ss_p2p = ws; ws += NP;  float* sd_p2p = ws; ws += NP;
    float* ss_p2a = ws; ws += NP;  float* sd_p2a = ws; ws += NA;
    float* ss_a2p = ws; ws += NA;  float* sd_a2p = ws; ws += NP;
    float* ss_a2a = ws; ws += NA;  float* sd_a2a = ws; ws += NA;
    float* ss_p2s = ws; ws += NP;
    float* ss_a2s = ws; ws += NA;
    float* sdst2  = ws; ws += 2;
    float* m2     = ws; ws += 2;
    float* den2   = ws; ws += 2;
    float* e_p2s  = ws; ws += NP;
    float* e_a2s  = ws; ws += NA;
    int* iw = (int*)ws;
    const int NTOT = 2 * NP + 2 * NA;          // 150000 concatenated dst bins
    int* cnt_all = iw; iw += NTOT;
    int* off_all = iw; iw += NTOT + 1;
    int* cursor  = iw; iw += NTOT;
    int* bsum    = iw; iw += 1024;
    int* ssrc    = iw; iw += E_tot;

    const int T = 256;
    const int B_p2p = 0, B_a2p = NP, B_p2a = 2 * NP, B_a2a = 2 * NP + NA;

    hipMemsetAsync(cnt_all, 0, (size_t)NTOT * 4, stream);

    // ---- fused transforms + dots ----
    int gP4 = (NP + 31) / 32, gA4 = (NA + 31) / 32;
    xform4<<<gP4, T, 0, stream>>>(feat_P, NP,
        W_P, b_P, WhP, a_p2p + 64, sd_p2p, a_a2p + 64, sd_a2p,
        W_p2p, b_p2p, z_p2p, a_p2p, ss_p2p,
        W_p2a, b_p2a, z_p2a, a_p2a, ss_p2a,
        W_p2s, b_p2s, z_p2s, a_p2s, ss_p2s);
    xform4<<<gA4, T, 0, stream>>>(feat_A, NA,
        W_A, b_A, WhA, a_p2a + 64, sd_p2a, a_a2a + 64, sd_a2a,
        W_a2p, b_a2p, z_a2p, a_a2p, ss_a2p,
        W_a2a, b_a2a, z_a2a, a_a2a, ss_a2a,
        W_a2s, b_a2s, z_a2s, a_a2s, ss_a2s);
    state_prep<<<1, 64, 0, stream>>>(feat_S, W_in, b_in, a_p2s, a_a2s, outS, sdst2, m2, den2);

    // ---- counting sort by destination ----
    hist_all<<<(E_tot + T - 1) / T, T, 0, stream>>>(dst_p2p, E_p2p, dst_a2p, E_a2p,
                                                    dst_p2a, E_p2a, dst_a2a, E_a2a, cnt_all);
    int nScanB = (NTOT + 255) / 256;
    scan_k1<<<nScanB, 256, 0, stream>>>(cnt_all, off_all, bsum, NTOT);
    scan_k2<<<1, 1024, 0, stream>>>(bsum, nScanB);
    scan_k3<<<nScanB, 256, 0, stream>>>(off_all, cursor, bsum, NTOT, E_tot);
    scatter_all<<<(E_tot + T - 1) / T, T, 0, stream>>>(
        src_p2p, dst_p2p, E_p2p, src_a2p, dst_a2p, E_a2p,
        src_p2a, dst_p2a, E_p2a, src_a2a, dst_a2a, E_a2a, cursor, ssrc);

    // ---- fused per-destination GAT + self + relu ----
    gat_dst<<<(NP + 3) / 4, T, 0, stream>>>(WhP, outP, NP, off_all, ssrc,
            B_p2p, ss_p2p, sd_p2p, z_p2p,
            B_a2p, ss_a2p, sd_a2p, z_a2p);
    gat_dst<<<(NA + 3) / 4, T, 0, stream>>>(WhA, outA, NA, off_all, ssrc,
            B_p2a, ss_p2a, sd_p2a, z_p2a,
            B_a2a, ss_a2a, sd_a2a, z_a2a);

    // ---- state GATs ----
    int nbP = (E_p2s + 255) / 256, nbA = (E_a2s + 255) / 256;
    state_e<<<nbP + nbA, T, 0, stream>>>(src_p2s, ss_p2s, src_a2s, ss_a2s, sdst2,
                                         e_p2s, e_a2s, m2, E_p2s, E_a2s, nbP);
    state_den<<<nbP + nbA, T, 0, stream>>>(e_p2s, e_a2s, m2, den2, E_p2s, E_a2s, nbP);
    state_acc<<<192, T, 0, stream>>>(src_p2s, e_p2s, z_p2s, E_p2s,
                                     src_a2s, e_a2s, z_a2s, E_a2s, den2, outS, 128);
    relu_small<<<1, 64, 0, stream>>>(outS, 64);
}

// Round 4
// 509.179 us; speedup vs baseline: 2.0145x; 1.1384x over previous
//
#include <hip/hip_runtime.h>
#include <math.h>

#define ALPHA 0.2f
#define NP 50000
#define NA 25000
#define NBINS 150000          // P: 2*NP interleaved bins, then A: 2*NA
#define ABASE 100000          // bin base for A nodes
#define NBUCK 586             // ceil(NBINS/256)
#define CH 16384              // edges per passA block
#define CAP 8192              // max edges per bucket held in LDS (mean ~4k)

typedef unsigned short u16;

__device__ __forceinline__ float bf2f(u16 u) { return __uint_as_float(((unsigned)u) << 16); }
__device__ __forceinline__ u16 f2bf(float f) {
    unsigned x = __float_as_uint(f);
    return (u16)((x + 0x7fffu + ((x >> 16) & 1u)) >> 16);   // RNE
}

__device__ __forceinline__ void atomicMaxF(float* addr, float val) {
    if (val >= 0.f) atomicMax((int*)addr, __float_as_int(val));
    else            atomicMin((unsigned int*)addr, __float_as_uint(val));
}

// ---------------- fused 4-matrix transform + attention dots ----------------
__global__ __launch_bounds__(256) void xform4(
    const float* __restrict__ X, int N,
    const float* __restrict__ W0, const float* __restrict__ b0, float* __restrict__ Wh,
    const float* __restrict__ dA, float* __restrict__ sdA,
    const float* __restrict__ dB, float* __restrict__ sdB,
    const float* __restrict__ W1, const float* __restrict__ b1, u16* __restrict__ z1,
    const float* __restrict__ v1, float* __restrict__ s1,
    const float* __restrict__ W2, const float* __restrict__ b2, u16* __restrict__ z2,
    const float* __restrict__ v2, float* __restrict__ s2,
    const float* __restrict__ W3, const float* __restrict__ b3, u16* __restrict__ z3,
    const float* __restrict__ v3, float* __restrict__ s3)
{
    __shared__ float Ws[4][4096];
    int tid = threadIdx.x;
    for (int i = tid; i < 4096; i += 256) {
        Ws[0][i] = W0[i]; Ws[1][i] = W1[i]; Ws[2][i] = W2[i]; Ws[3][i] = W3[i];
    }
    __syncthreads();
    int wv = tid >> 6, lane = tid & 63;
    float bb0 = b0[lane], bb1 = b1[lane], bb2 = b2[lane], bb3 = b3[lane];
    float da = dA[lane], db = dB[lane], dv1 = v1[lane], dv2 = v2[lane], dv3 = v3[lane];
    for (int it = 0; it < 8; ++it) {
        int row = blockIdx.x * 32 + it * 4 + wv;
        if (row >= N) break;                       // wave-uniform
        float xv = X[(long long)row * 64 + lane];
        float a0 = bb0, a1 = bb1, a2 = bb2, a3 = bb3;
#pragma unroll
        for (int k = 0; k < 64; ++k) {
            float xk = __shfl(xv, k, 64);
            a0 = fmaf(xk, Ws[0][k * 64 + lane], a0);
            a1 = fmaf(xk, Ws[1][k * 64 + lane], a1);
            a2 = fmaf(xk, Ws[2][k * 64 + lane], a2);
            a3 = fmaf(xk, Ws[3][k * 64 + lane], a3);
        }
        long long o = (long long)row * 64 + lane;
        Wh[o] = a0;
        z1[o] = f2bf(a1); z2[o] = f2bf(a2); z3[o] = f2bf(a3);
        float t0 = a0 * da, t1 = a0 * db, t2 = a1 * dv1, t3 = a2 * dv2, t4 = a3 * dv3;
#pragma unroll
        for (int of = 32; of > 0; of >>= 1) {
            t0 += __shfl_xor(t0, of, 64); t1 += __shfl_xor(t1, of, 64);
            t2 += __shfl_xor(t2, of, 64); t3 += __shfl_xor(t3, of, 64);
            t4 += __shfl_xor(t4, of, 64);
        }
        if (lane == 0) { sdA[row] = t0; sdB[row] = t1; s1[row] = t2; s2[row] = t3; s3[row] = t4; }
    }
}

// ---------------- pass A: coarse bucket sort (256-bin buckets) ----------------
__device__ __forceinline__ int edge_bin(int k,
    const int* __restrict__ d0, int E0, const int* __restrict__ d1, int E1,
    const int* __restrict__ d2, int E2, const int* __restrict__ d3) {
    if (k < E0) return 2 * d0[k];
    k -= E0; if (k < E1) return 2 * d1[k] + 1;
    k -= E1; if (k < E2) return ABASE + 2 * d2[k];
    k -= E2; return ABASE + 2 * d3[k] + 1;
}
__device__ __forceinline__ void edge_decode(int k,
    const int* __restrict__ s0, const int* __restrict__ d0, int E0,
    const int* __restrict__ s1, const int* __restrict__ d1, int E1,
    const int* __restrict__ s2, const int* __restrict__ d2, int E2,
    const int* __restrict__ s3, const int* __restrict__ d3,
    int& src, int& bin) {
    if (k < E0) { src = s0[k]; bin = 2 * d0[k]; return; }
    k -= E0; if (k < E1) { src = s1[k]; bin = 2 * d1[k] + 1; return; }
    k -= E1; if (k < E2) { src = s2[k]; bin = ABASE + 2 * d2[k]; return; }
    k -= E2; src = s3[k]; bin = ABASE + 2 * d3[k] + 1;
}

// per-block coarse histogram -> cnt[bucket * nblk + blk]
__global__ __launch_bounds__(256) void passA_hist(
    const int* __restrict__ d0, int E0, const int* __restrict__ d1, int E1,
    const int* __restrict__ d2, int E2, const int* __restrict__ d3, int E3,
    int* __restrict__ cnt, int nblk, int Etot) {
    __shared__ int h[NBUCK];
    int tid = threadIdx.x;
    for (int i = tid; i < NBUCK; i += 256) h[i] = 0;
    __syncthreads();
    int base = blockIdx.x * CH;
    int end = min(base + CH, Etot);
    for (int i = base + tid; i < end; i += 256) {
        int bin = edge_bin(i, d0, E0, d1, E1, d2, E2, d3);
        atomicAdd(&h[bin >> 8], 1);
    }
    __syncthreads();
    for (int i = tid; i < NBUCK; i += 256) cnt[i * nblk + blockIdx.x] = h[i];
}

__global__ void scan_k1(const int* __restrict__ cnt, int* __restrict__ off,
                        int* __restrict__ bsum, int n) {
    __shared__ int s[256];
    int t = threadIdx.x;
    int i = blockIdx.x * 256 + t;
    int v = (i < n) ? cnt[i] : 0;
    s[t] = v;
    __syncthreads();
    for (int o = 1; o < 256; o <<= 1) {
        int x = (t >= o) ? s[t - o] : 0;
        __syncthreads();
        s[t] += x;
        __syncthreads();
    }
    if (i < n) off[i] = s[t] - v;
    if (t == 255) bsum[blockIdx.x] = s[255];
}
__global__ void scan_k2(int* __restrict__ bsum, int nb) {
    __shared__ int s[1024];
    int t = threadIdx.x;
    int v = (t < nb) ? bsum[t] : 0;
    s[t] = v;
    __syncthreads();
    for (int o = 1; o < 1024; o <<= 1) {
        int x = (t >= o) ? s[t - o] : 0;
        __syncthreads();
        s[t] += x;
        __syncthreads();
    }
    if (t < nb) bsum[t] = s[t] - v;
}
__global__ void scan_k3(int* __restrict__ off, const int* __restrict__ bsum, int n) {
    int i = blockIdx.x * 256 + threadIdx.x;
    if (i < n) off[i] += bsum[blockIdx.x];
}

// scatter edges into bucket-contiguous ebuf, packed src | (binlocal<<16)
__global__ __launch_bounds__(256) void passA_scatter(
    const int* __restrict__ s0, const int* __restrict__ d0, int E0,
    const int* __restrict__ s1, const int* __restrict__ d1, int E1,
    const int* __restrict__ s2, const int* __restrict__ d2, int E2,
    const int* __restrict__ s3, const int* __restrict__ d3, int E3,
    const int* __restrict__ cnt_scan, int nblk, int Etot, int* __restrict__ ebuf) {
    __shared__ int cur[NBUCK];
    int tid = threadIdx.x;
    for (int i = tid; i < NBUCK; i += 256) cur[i] = cnt_scan[i * nblk + blockIdx.x];
    __syncthreads();
    int base = blockIdx.x * CH;
    int end = min(base + CH, Etot);
    for (int i = base + tid; i < end; i += 256) {
        int src, bin;
        edge_decode(i, s0, d0, E0, s1, d1, E1, s2, d2, E2, s3, d3, src, bin);
        int pos = atomicAdd(&cur[bin >> 8], 1);
        ebuf[pos] = src | ((bin & 255) << 16);
    }
}

// ---------------- fused bucket GAT: LDS fine-sort + per-node softmax-gather ----------------
__device__ __forceinline__ void seg_gat_lds(const int* __restrict__ lsrc, int s0, int s1,
                                            const float* __restrict__ ss, float sd,
                                            const u16* __restrict__ z, int lane,
                                            float4& acc) {
    int cnt = s1 - s0;
    if (cnt <= 0) return;
    int egrp = lane >> 4, cg4 = (lane & 15) * 4;
    if (cnt <= 64) {                    // fast path (essentially always: deg <= ~48)
        int s = 0; float e = -INFINITY;
        if (lane < cnt) {
            s = lsrc[s0 + lane];
            e = ss[s] + sd;
            e = e > 0.f ? e : ALPHA * e;
        }
        float m = e;
#pragma unroll
        for (int o = 32; o > 0; o >>= 1) m = fmaxf(m, __shfl_xor(m, o, 64));
        float w = (lane < cnt) ? __expf(e - m) : 0.f;
        float den = w;
#pragma unroll
        for (int o = 32; o > 0; o >>= 1) den += __shfl_xor(den, o, 64);
        w *= 1.f / den;
        int nit = (cnt + 3) >> 2;
        for (int it = 0; it < nit; ++it) {
            int ei = it * 4 + egrp;
            float wt = __shfl(w, ei, 64);
            int   st = __shfl(s, ei, 64);
            ushort4 q = *(const ushort4*)(z + (long long)st * 64 + cg4);
            acc.x = fmaf(wt, bf2f(q.x), acc.x);
            acc.y = fmaf(wt, bf2f(q.y), acc.y);
            acc.z = fmaf(wt, bf2f(q.z), acc.z);
            acc.w = fmaf(wt, bf2f(q.w), acc.w);
        }
    } else {                            // general path (rare)
        float m = -INFINITY;
        for (int i = s0 + lane; i < s1; i += 64) {
            float e = ss[lsrc[i]] + sd; e = e > 0.f ? e : ALPHA * e; m = fmaxf(m, e);
        }
#pragma unroll
        for (int o = 32; o > 0; o >>= 1) m = fmaxf(m, __shfl_xor(m, o, 64));
        float den = 0.f;
        for (int i = s0 + lane; i < s1; i += 64) {
            float e = ss[lsrc[i]] + sd; e = e > 0.f ? e : ALPHA * e; den += __expf(e - m);
        }
#pragma unroll
        for (int o = 32; o > 0; o >>= 1) den += __shfl_xor(den, o, 64);
        float inv = 1.f / den;
        for (int c = s0; c < s1; c += 64) {
            int i = c + lane; int s = 0; float w = 0.f;
            if (i < s1) {
                s = lsrc[i];
                float e = ss[s] + sd; e = e > 0.f ? e : ALPHA * e;
                w = __expf(e - m) * inv;
            }
            int cc = min(64, s1 - c);
            int nit = (cc + 3) >> 2;
            for (int it = 0; it < nit; ++it) {
                int ei = it * 4 + egrp;
                float wt = __shfl(w, ei, 64);
                int   st = __shfl(s, ei, 64);
                ushort4 q = *(const ushort4*)(z + (long long)st * 64 + cg4);
                acc.x = fmaf(wt, bf2f(q.x), acc.x);
                acc.y = fmaf(wt, bf2f(q.y), acc.y);
                acc.z = fmaf(wt, bf2f(q.z), acc.z);
                acc.w = fmaf(wt, bf2f(q.w), acc.w);
            }
        }
    }
}

__global__ __launch_bounds__(256) void gat_bucket(
    const int* __restrict__ ebuf, const int* __restrict__ cnt_scan, int nblk, int Etot,
    const float* __restrict__ WhP, float* __restrict__ outP,
    const float* __restrict__ WhA, float* __restrict__ outA,
    const float* __restrict__ ss_p2p, const float* __restrict__ sd_p2p, const u16* __restrict__ z_p2p,
    const float* __restrict__ ss_a2p, const float* __restrict__ sd_a2p, const u16* __restrict__ z_a2p,
    const float* __restrict__ ss_p2a, const float* __restrict__ sd_p2a, const u16* __restrict__ z_p2a,
    const float* __restrict__ ss_a2a, const float* __restrict__ sd_a2a, const u16* __restrict__ z_a2a) {
    __shared__ int lsrc[CAP];
    __shared__ int lcnt[256];
    __shared__ int loff[257];
    __shared__ int lcur[256];
    __shared__ int stmp[256];
    int b = blockIdx.x;
    int tid = threadIdx.x;
    int bstart = cnt_scan[b * nblk];
    int bend = (b + 1 < NBUCK) ? cnt_scan[(b + 1) * nblk] : Etot;
    // phase 1: fine histogram over 256 local bins
    lcnt[tid] = 0;
    __syncthreads();
    for (int e = bstart + tid; e < bend; e += 256)
        atomicAdd(&lcnt[((unsigned)ebuf[e]) >> 16], 1);
    __syncthreads();
    // phase 2: exclusive scan
    stmp[tid] = lcnt[tid];
    __syncthreads();
    for (int o = 1; o < 256; o <<= 1) {
        int x = (tid >= o) ? stmp[tid - o] : 0;
        __syncthreads();
        stmp[tid] += x;
        __syncthreads();
    }
    loff[tid] = stmp[tid] - lcnt[tid];
    lcur[tid] = loff[tid];
    if (tid == 255) loff[256] = stmp[255];
    __syncthreads();
    // phase 3: scatter srcs into LDS, sorted by local bin
    for (int e = bstart + tid; e < bend; e += 256) {
        int v = ebuf[e];
        int pos = atomicAdd(&lcur[((unsigned)v) >> 16], 1);
        if (pos < CAP) lsrc[pos] = v & 0xFFFF;
    }
    __syncthreads();
    // phase 4: per-node GAT (wave per node, 4 waves x 32 nodes)
    int wv = tid >> 6, lane = tid & 63;
    for (int i = wv; i < 128; i += 4) {
        int gbin = b * 256 + 2 * i;
        if (gbin >= NBINS) break;
        bool isP = gbin < ABASE;
        int d = isP ? (gbin >> 1) : ((gbin - ABASE) >> 1);
        int e0 = min(loff[2 * i], CAP), e1 = min(loff[2 * i + 1], CAP), e2 = min(loff[2 * i + 2], CAP);
        float4 acc = {0.f, 0.f, 0.f, 0.f};
        if (isP) {
            seg_gat_lds(lsrc, e0, e1, ss_p2p, sd_p2p[d], z_p2p, lane, acc);
            seg_gat_lds(lsrc, e1, e2, ss_a2p, sd_a2p[d], z_a2p, lane, acc);
        } else {
            seg_gat_lds(lsrc, e0, e1, ss_p2a, sd_p2a[d], z_p2a, lane, acc);
            seg_gat_lds(lsrc, e1, e2, ss_a2a, sd_a2a[d], z_a2a, lane, acc);
        }
#pragma unroll
        for (int o = 16; o <= 32; o <<= 1) {
            acc.x += __shfl_xor(acc.x, o, 64);
            acc.y += __shfl_xor(acc.y, o, 64);
            acc.z += __shfl_xor(acc.z, o, 64);
            acc.w += __shfl_xor(acc.w, o, 64);
        }
        if (lane < 16) {
            const float* Wh = isP ? WhP : WhA;
            float* outp = isP ? outP : outA;
            float4 self = *(const float4*)&Wh[(long long)d * 64 + lane * 4];
            float4 r;
            r.x = fmaxf(self.x + acc.x, 0.f);
            r.y = fmaxf(self.y + acc.y, 0.f);
            r.z = fmaxf(self.z + acc.z, 0.f);
            r.w = fmaxf(self.w + acc.w, 0.f);
            *(float4*)&outp[(long long)d * 64 + lane * 4] = r;
        }
    }
}

// ---------------- state (single destination) path ----------------
__global__ void state_prep(const float* __restrict__ fS, const float* __restrict__ W_in,
                           const float* __restrict__ b_in, const float* __restrict__ a_p2s,
                           const float* __restrict__ a_a2s, float* __restrict__ outS,
                           float* __restrict__ sdst2, float* __restrict__ m2,
                           float* __restrict__ den2) {
    int c = threadIdx.x;
    if (c < 2) { m2[c] = -INFINITY; den2[c] = 0.f; }
    float acc = b_in[c];
    for (int k = 0; k < 64; ++k) acc = fmaf(fS[k], W_in[k * 64 + c], acc);
    outS[c] = acc;
    float v0 = acc * a_p2s[64 + c];
    float v1 = acc * a_a2s[64 + c];
#pragma unroll
    for (int off = 32; off > 0; off >>= 1) {
        v0 += __shfl_down(v0, off, 64);
        v1 += __shfl_down(v1, off, 64);
    }
    if (c == 0) { sdst2[0] = v0; sdst2[1] = v1; }
}

__global__ void state_e(const int* __restrict__ srcP, const float* __restrict__ ssP,
                        const int* __restrict__ srcA, const float* __restrict__ ssA,
                        const float* __restrict__ sdst2, float* __restrict__ eP,
                        float* __restrict__ eA, float* __restrict__ m2,
                        int EP, int EA, int nbP) {
    bool isP = (int)blockIdx.x < nbP;
    int bid = isP ? blockIdx.x : blockIdx.x - nbP;
    int i = bid * 256 + threadIdx.x;
    int E = isP ? EP : EA;
    float v = -INFINITY;
    if (i < E) {
        const int* src = isP ? srcP : srcA;
        const float* ss = isP ? ssP : ssA;
        float e = ss[src[i]] + sdst2[isP ? 0 : 1];
        e = e > 0.f ? e : ALPHA * e;
        (isP ? eP : eA)[i] = e;
        v = e;
    }
#pragma unroll
    for (int o = 32; o > 0; o >>= 1) v = fmaxf(v, __shfl_xor(v, o, 64));
    if ((threadIdx.x & 63) == 0) atomicMaxF(&m2[isP ? 0 : 1], v);
}

__global__ void state_den(float* __restrict__ eP, float* __restrict__ eA,
                          const float* __restrict__ m2, float* __restrict__ den2,
                          int EP, int EA, int nbP) {
    bool isP = (int)blockIdx.x < nbP;
    int bid = isP ? blockIdx.x : blockIdx.x - nbP;
    int i = bid * 256 + threadIdx.x;
    int E = isP ? EP : EA;
    float ex = 0.f;
    if (i < E) {
        float* e = isP ? eP : eA;
        ex = __expf(e[i] - m2[isP ? 0 : 1]);
        e[i] = ex;
    }
#pragma unroll
    for (int o = 32; o > 0; o >>= 1) ex += __shfl_xor(ex, o, 64);
    if ((threadIdx.x & 63) == 0) atomicAdd(&den2[isP ? 0 : 1], ex);
}

__global__ void state_acc(const int* __restrict__ srcP, const float* __restrict__ eP,
                          const u16* __restrict__ zP, int EP,
                          const int* __restrict__ srcA, const float* __restrict__ eA,
                          const u16* __restrict__ zA, int EA,
                          const float* __restrict__ den2, float* __restrict__ outS, int nbP) {
    __shared__ float red[4][64];
    bool isP = (int)blockIdx.x < nbP;
    const int* src = isP ? srcP : srcA;
    const float* e = isP ? eP : eA;
    const u16* z = isP ? zP : zA;
    int E = isP ? EP : EA;
    float inv = 1.f / den2[isP ? 0 : 1];
    int bid = isP ? blockIdx.x : blockIdx.x - nbP;
    int nb = isP ? nbP : ((int)gridDim.x - nbP);
    int lane = threadIdx.x & 63, wv = threadIdx.x >> 6;
    int egrp = lane >> 4, cg4 = (lane & 15) * 4;
    int gw = bid * 4 + wv;
    int waves = nb * 4;
    float4 acc = {0.f, 0.f, 0.f, 0.f};
    for (int base = gw * 4; base < E; base += waves * 4) {
        int i = base + egrp;
        float w = (i < E) ? e[i] * inv : 0.f;
        int ri = (i < E) ? src[i] : 0;
        ushort4 q = *(const ushort4*)(z + (long long)ri * 64 + cg4);
        acc.x = fmaf(w, bf2f(q.x), acc.x);
        acc.y = fmaf(w, bf2f(q.y), acc.y);
        acc.z = fmaf(w, bf2f(q.z), acc.z);
        acc.w = fmaf(w, bf2f(q.w), acc.w);
    }
#pragma unroll
    for (int o = 16; o <= 32; o <<= 1) {
        acc.x += __shfl_xor(acc.x, o, 64);
        acc.y += __shfl_xor(acc.y, o, 64);
        acc.z += __shfl_xor(acc.z, o, 64);
        acc.w += __shfl_xor(acc.w, o, 64);
    }
    if (lane < 16) ((float4*)red[wv])[lane] = acc;
    __syncthreads();
    if (wv == 0) {
        float t = red[0][lane] + red[1][lane] + red[2][lane] + red[3][lane];
        atomicAdd(&outS[lane], t);
    }
}

__global__ void relu_small(float* __restrict__ p, int n) {
    int i = threadIdx.x;
    if (i < n) p[i] = fmaxf(p[i], 0.f);
}

extern "C" void kernel_launch(void* const* d_in, const int* in_sizes, int n_in,
                              void* d_out, int out_size, void* d_ws, size_t ws_size,
                              hipStream_t stream) {
    const float* feat_P = (const float*)d_in[0];
    const float* feat_A = (const float*)d_in[1];
    const float* feat_S = (const float*)d_in[2];
    const float* W_P   = (const float*)d_in[3];  const float* b_P   = (const float*)d_in[4];
    const float* W_A   = (const float*)d_in[5];  const float* b_A   = (const float*)d_in[6];
    const float* W_p2p = (const float*)d_in[7];  const float* b_p2p = (const float*)d_in[8];
    const float* W_p2a = (const float*)d_in[9];  const float* b_p2a = (const float*)d_in[10];
    const float* W_a2p = (const float*)d_in[11]; const float* b_a2p = (const float*)d_in[12];
    const float* W_a2a = (const float*)d_in[13]; const float* b_a2a = (const float*)d_in[14];
    const float* W_p2s = (const float*)d_in[15]; const float* b_p2s = (const float*)d_in[16];
    const float* W_a2s = (const float*)d_in[17]; const float* b_a2s = (const float*)d_in[18];
    const float* W_in  = (const float*)d_in[19]; const float* b_in  = (const float*)d_in[20];
    const float* a_p2p = (const float*)d_in[21];
    const float* a_p2a = (const float*)d_in[22];
    const float* a_a2p = (const float*)d_in[23];
    const float* a_a2a = (const float*)d_in[24];
    const float* a_p2s = (const float*)d_in[25];
    const float* a_a2s = (const float*)d_in[26];
    const int* src_p2p = (const int*)d_in[27]; const int* dst_p2p = (const int*)d_in[28];
    const int* src_p2a = (const int*)d_in[29]; const int* dst_p2a = (const int*)d_in[30];
    const int* src_a2p = (const int*)d_in[31]; const int* dst_a2p = (const int*)d_in[32];
    const int* src_a2a = (const int*)d_in[33]; const int* dst_a2a = (const int*)d_in[34];
    const int* src_p2s = (const int*)d_in[35];
    const int* src_a2s = (const int*)d_in[37];
    int E_p2p = in_sizes[27], E_p2a = in_sizes[29], E_a2p = in_sizes[31], E_a2a = in_sizes[33];
    int E_p2s = in_sizes[35], E_a2s = in_sizes[37];
    int E_tot = E_p2p + E_a2p + E_p2a + E_a2a;

    float* out = (float*)d_out;
    float* outP = out;
    float* outA = out + (long long)NP * 64;
    float* outS = out + (long long)(NP + NA) * 64;

    // ---- workspace layout ----
    float* ws = (float*)d_ws;
    float* WhP = ws; ws += (long long)NP * 64;
    float* WhA = ws; ws += (long long)NA * 64;
    u16* z_p2p = (u16*)ws; ws += (long long)NP * 32;
    u16* z_p2a = (u16*)ws; ws += (long long)NP * 32;
    u16* z_p2s = (u16*)ws; ws += (long long)NP * 32;
    u16* z_a2p = (u16*)ws; ws += (long long)NA * 32;
    u16* z_a2a = (u16*)ws; ws += (long long)NA * 32;
    u16* z_a2s = (u16*)ws; ws += (long long)NA * 32;
    float* ss_p2p = ws; ws += NP;  float* sd_p2p = ws; ws += NP;
    float* ss_p2a = ws; ws += NP;  float* sd_p2a = ws; ws += NA;
    float* ss_a2p = ws; ws += NA;  float* sd_a2p = ws; ws += NP;
    float* ss_a2a = ws; ws += NA;  float* sd_a2a = ws; ws += NA;
    float* ss_p2s = ws; ws += NP;
    float* ss_a2s = ws; ws += NA;
    float* sdst2  = ws; ws += 2;
    float* m2     = ws; ws += 2;
    float* den2   = ws; ws += 2;
    float* e_p2s  = ws; ws += NP;
    float* e_a2s  = ws; ws += NA;
    int nblk = (E_tot + CH - 1) / CH;
    int* iw = (int*)ws;
    int* cnt_scan = iw; iw += NBUCK * nblk;    // passA counts -> scanned offsets
    int* bsum     = iw; iw += 1024;
    int* ebuf     = iw; iw += E_tot;           // bucket-grouped packed edges

    const int T = 256;

    // ---- fused transforms + dots ----
    int gP4 = (NP + 31) / 32, gA4 = (NA + 31) / 32;
    xform4<<<gP4, T, 0, stream>>>(feat_P, NP,
        W_P, b_P, WhP, a_p2p + 64, sd_p2p, a_a2p + 64, sd_a2p,
        W_p2p, b_p2p, z_p2p, a_p2p, ss_p2p,
        W_p2a, b_p2a, z_p2a, a_p2a, ss_p2a,
        W_p2s, b_p2s, z_p2s, a_p2s, ss_p2s);
    xform4<<<gA4, T, 0, stream>>>(feat_A, NA,
        W_A, b_A, WhA, a_p2a + 64, sd_p2a, a_a2a + 64, sd_a2a,
        W_a2p, b_a2p, z_a2p, a_a2p, ss_a2p,
        W_a2a, b_a2a, z_a2a, a_a2a, ss_a2a,
        W_a2s, b_a2s, z_a2s, a_a2s, ss_a2s);
    state_prep<<<1, 64, 0, stream>>>(feat_S, W_in, b_in, a_p2s, a_a2s, outS, sdst2, m2, den2);

    // ---- pass A: coarse bucket sort ----
    passA_hist<<<nblk, T, 0, stream>>>(dst_p2p, E_p2p, dst_a2p, E_a2p,
                                       dst_p2a, E_p2a, dst_a2a, E_a2a,
                                       cnt_scan, nblk, E_tot);
    int nScan = NBUCK * nblk;
    int nScanB = (nScan + 255) / 256;
    scan_k1<<<nScanB, 256, 0, stream>>>(cnt_scan, cnt_scan, bsum, nScan);   // in-place ok (elementwise)
    scan_k2<<<1, 1024, 0, stream>>>(bsum, nScanB);
    scan_k3<<<nScanB, 256, 0, stream>>>(cnt_scan, bsum, nScan);
    passA_scatter<<<nblk, T, 0, stream>>>(src_p2p, dst_p2p, E_p2p,
                                          src_a2p, dst_a2p, E_a2p,
                                          src_p2a, dst_p2a, E_p2a,
                                          src_a2a, dst_a2a, E_a2a,
                                          cnt_scan, nblk, E_tot, ebuf);

    // ---- fused bucket GAT + self + relu ----
    gat_bucket<<<NBUCK, T, 0, stream>>>(ebuf, cnt_scan, nblk, E_tot,
        WhP, outP, WhA, outA,
        ss_p2p, sd_p2p, z_p2p, ss_a2p, sd_a2p, z_a2p,
        ss_p2a, sd_p2a, z_p2a, ss_a2a, sd_a2a, z_a2a);

    // ---- state GATs ----
    int nbP = (E_p2s + 255) / 256, nbA = (E_a2s + 255) / 256;
    state_e<<<nbP + nbA, T, 0, stream>>>(src_p2s, ss_p2s, src_a2s, ss_a2s, sdst2,
                                         e_p2s, e_a2s, m2, E_p2s, E_a2s, nbP);
    state_den<<<nbP + nbA, T, 0, stream>>>(e_p2s, e_a2s, m2, den2, E_p2s, E_a2s, nbP);
    state_acc<<<192, T, 0, stream>>>(src_p2s, e_p2s, z_p2s, E_p2s,
                                     src_a2s, e_a2s, z_a2s, E_a2s, den2, outS, 128);
    relu_small<<<1, 64, 0, stream>>>(outS, 64);
}

// Round 5
// 398.922 us; speedup vs baseline: 2.5713x; 1.2764x over previous
//
#include <hip/hip_runtime.h>
#include <math.h>

#define ALPHA 0.2f
#define NP 50000
#define NA 25000
#define NBINS 150000          // P: 2*NP interleaved bins, then A: 2*NA
#define ABASE 100000          // bin base for A nodes
#define NBUCK 586             // ceil(NBINS/256)
#define CH 16384              // edges per passA block
#define CAP 8192              // max edges per bucket held in LDS (mean ~3.5k)

typedef unsigned short u16;

__device__ __forceinline__ float bf2f(u16 u) { return __uint_as_float(((unsigned)u) << 16); }
__device__ __forceinline__ u16 f2bf(float f) {
    unsigned x = __float_as_uint(f);
    return (u16)((x + 0x7fffu + ((x >> 16) & 1u)) >> 16);   // RNE
}

// ---------------- fused 4-matrix transform + attention dots ----------------
__global__ __launch_bounds__(256) void xform4(
    const float* __restrict__ X, int N,
    const float* __restrict__ W0, const float* __restrict__ b0, float* __restrict__ Wh,
    const float* __restrict__ dA, float* __restrict__ sdA,
    const float* __restrict__ dB, float* __restrict__ sdB,
    const float* __restrict__ W1, const float* __restrict__ b1, u16* __restrict__ z1,
    const float* __restrict__ v1, float* __restrict__ s1,
    const float* __restrict__ W2, const float* __restrict__ b2, u16* __restrict__ z2,
    const float* __restrict__ v2, float* __restrict__ s2,
    const float* __restrict__ W3, const float* __restrict__ b3, u16* __restrict__ z3,
    const float* __restrict__ v3, float* __restrict__ s3)
{
    __shared__ float Ws[4][4096];
    int tid = threadIdx.x;
    for (int i = tid; i < 4096; i += 256) {
        Ws[0][i] = W0[i]; Ws[1][i] = W1[i]; Ws[2][i] = W2[i]; Ws[3][i] = W3[i];
    }
    __syncthreads();
    int wv = tid >> 6, lane = tid & 63;
    float bb0 = b0[lane], bb1 = b1[lane], bb2 = b2[lane], bb3 = b3[lane];
    float da = dA[lane], db = dB[lane], dv1 = v1[lane], dv2 = v2[lane], dv3 = v3[lane];
    for (int it = 0; it < 16; ++it) {
        int row = blockIdx.x * 64 + it * 4 + wv;
        if (row >= N) break;                       // wave-uniform
        float xv = X[(long long)row * 64 + lane];
        float a0 = bb0, a1 = bb1, a2 = bb2, a3 = bb3;
#pragma unroll
        for (int k = 0; k < 64; ++k) {
            float xk = __shfl(xv, k, 64);
            a0 = fmaf(xk, Ws[0][k * 64 + lane], a0);
            a1 = fmaf(xk, Ws[1][k * 64 + lane], a1);
            a2 = fmaf(xk, Ws[2][k * 64 + lane], a2);
            a3 = fmaf(xk, Ws[3][k * 64 + lane], a3);
        }
        long long o = (long long)row * 64 + lane;
        Wh[o] = a0;
        z1[o] = f2bf(a1); z2[o] = f2bf(a2); z3[o] = f2bf(a3);
        float t0 = a0 * da, t1 = a0 * db, t2 = a1 * dv1, t3 = a2 * dv2, t4 = a3 * dv3;
#pragma unroll
        for (int of = 32; of > 0; of >>= 1) {
            t0 += __shfl_xor(t0, of, 64); t1 += __shfl_xor(t1, of, 64);
            t2 += __shfl_xor(t2, of, 64); t3 += __shfl_xor(t3, of, 64);
            t4 += __shfl_xor(t4, of, 64);
        }
        if (lane == 0) { sdA[row] = t0; sdB[row] = t1; s1[row] = t2; s2[row] = t3; s3[row] = t4; }
    }
}

// ---------------- pass A: coarse bucket sort (256-bin buckets) ----------------
__device__ __forceinline__ int edge_bin(int k,
    const int* __restrict__ d0, int E0, const int* __restrict__ d1, int E1,
    const int* __restrict__ d2, int E2, const int* __restrict__ d3) {
    if (k < E0) return 2 * d0[k];
    k -= E0; if (k < E1) return 2 * d1[k] + 1;
    k -= E1; if (k < E2) return ABASE + 2 * d2[k];
    k -= E2; return ABASE + 2 * d3[k] + 1;
}
__device__ __forceinline__ void edge_decode(int k,
    const int* __restrict__ s0, const int* __restrict__ d0, int E0,
    const int* __restrict__ s1, const int* __restrict__ d1, int E1,
    const int* __restrict__ s2, const int* __restrict__ d2, int E2,
    const int* __restrict__ s3, const int* __restrict__ d3,
    int& src, int& bin) {
    if (k < E0) { src = s0[k]; bin = 2 * d0[k]; return; }
    k -= E0; if (k < E1) { src = s1[k]; bin = 2 * d1[k] + 1; return; }
    k -= E1; if (k < E2) { src = s2[k]; bin = ABASE + 2 * d2[k]; return; }
    k -= E2; src = s3[k]; bin = ABASE + 2 * d3[k] + 1;
}

__global__ __launch_bounds__(256) void passA_hist(
    const int* __restrict__ d0, int E0, const int* __restrict__ d1, int E1,
    const int* __restrict__ d2, int E2, const int* __restrict__ d3, int E3,
    int* __restrict__ cnt, int nblk, int Etot) {
    __shared__ int h[NBUCK];
    int tid = threadIdx.x;
    for (int i = tid; i < NBUCK; i += 256) h[i] = 0;
    __syncthreads();
    int base = blockIdx.x * CH;
    int end = min(base + CH, Etot);
    for (int i = base + tid; i < end; i += 256) {
        int bin = edge_bin(i, d0, E0, d1, E1, d2, E2, d3);
        atomicAdd(&h[bin >> 8], 1);
    }
    __syncthreads();
    for (int i = tid; i < NBUCK; i += 256) cnt[i * nblk + blockIdx.x] = h[i];
}

__global__ void scan_k1(const int* __restrict__ cnt, int* __restrict__ off,
                        int* __restrict__ bsum, int n) {
    __shared__ int s[256];
    int t = threadIdx.x;
    int i = blockIdx.x * 256 + t;
    int v = (i < n) ? cnt[i] : 0;
    s[t] = v;
    __syncthreads();
    for (int o = 1; o < 256; o <<= 1) {
        int x = (t >= o) ? s[t - o] : 0;
        __syncthreads();
        s[t] += x;
        __syncthreads();
    }
    if (i < n) off[i] = s[t] - v;
    if (t == 255) bsum[blockIdx.x] = s[255];
}
__global__ void scan_k2(int* __restrict__ bsum, int nb) {
    __shared__ int s[1024];
    int t = threadIdx.x;
    int v = (t < nb) ? bsum[t] : 0;
    s[t] = v;
    __syncthreads();
    for (int o = 1; o < 1024; o <<= 1) {
        int x = (t >= o) ? s[t - o] : 0;
        __syncthreads();
        s[t] += x;
        __syncthreads();
    }
    if (t < nb) bsum[t] = s[t] - v;
}
__global__ void scan_k3(int* __restrict__ off, const int* __restrict__ bsum, int n) {
    int i = blockIdx.x * 256 + threadIdx.x;
    if (i < n) off[i] += bsum[blockIdx.x];
}

__global__ __launch_bounds__(256) void passA_scatter(
    const int* __restrict__ s0, const int* __restrict__ d0, int E0,
    const int* __restrict__ s1, const int* __restrict__ d1, int E1,
    const int* __restrict__ s2, const int* __restrict__ d2, int E2,
    const int* __restrict__ s3, const int* __restrict__ d3, int E3,
    const int* __restrict__ cnt_scan, int nblk, int Etot, int* __restrict__ ebuf) {
    __shared__ int cur[NBUCK];
    int tid = threadIdx.x;
    for (int i = tid; i < NBUCK; i += 256) cur[i] = cnt_scan[i * nblk + blockIdx.x];
    __syncthreads();
    int base = blockIdx.x * CH;
    int end = min(base + CH, Etot);
    for (int i = base + tid; i < end; i += 256) {
        int src, bin;
        edge_decode(i, s0, d0, E0, s1, d1, E1, s2, d2, E2, s3, d3, src, bin);
        int pos = atomicAdd(&cur[bin >> 8], 1);
        ebuf[pos] = src | ((bin & 255) << 16);
    }
}

// ---------------- fine sort: bucket -> fully dst-sorted ssrc + global offs ----------------
__global__ __launch_bounds__(256) void fine_sort(
    const int* __restrict__ ebuf, const int* __restrict__ cnt_scan, int nblk, int Etot,
    int* __restrict__ ssrc, int* __restrict__ offs) {
    __shared__ int lsrc[CAP];
    __shared__ int lcnt[256];
    __shared__ int loff[256];
    __shared__ int lcur[256];
    __shared__ int stmp[256];
    int b = blockIdx.x;
    int tid = threadIdx.x;
    int bstart = cnt_scan[b * nblk];
    int bend = (b + 1 < NBUCK) ? cnt_scan[(b + 1) * nblk] : Etot;
    int cnt = bend - bstart;
    // fine histogram over 256 local bins
    lcnt[tid] = 0;
    __syncthreads();
    for (int e = bstart + tid; e < bend; e += 256)
        atomicAdd(&lcnt[((unsigned)ebuf[e]) >> 16], 1);
    __syncthreads();
    // exclusive scan
    stmp[tid] = lcnt[tid];
    __syncthreads();
    for (int o = 1; o < 256; o <<= 1) {
        int x = (tid >= o) ? stmp[tid - o] : 0;
        __syncthreads();
        stmp[tid] += x;
        __syncthreads();
    }
    loff[tid] = stmp[tid] - lcnt[tid];
    lcur[tid] = loff[tid];
    __syncthreads();
    if (cnt <= CAP) {
        for (int e = bstart + tid; e < bend; e += 256) {
            int v = ebuf[e];
            int pos = atomicAdd(&lcur[((unsigned)v) >> 16], 1);
            lsrc[pos] = v & 0xFFFF;
        }
        __syncthreads();
        for (int i = tid; i < cnt; i += 256) ssrc[bstart + i] = lsrc[i];   // coalesced
    } else {                                   // overflow fallback (shouldn't happen)
        for (int e = bstart + tid; e < bend; e += 256) {
            int v = ebuf[e];
            int pos = atomicAdd(&lcur[((unsigned)v) >> 16], 1);
            ssrc[bstart + pos] = v & 0xFFFF;
        }
    }
    int gb = b * 256 + tid;
    if (gb < NBINS) offs[gb] = bstart + loff[tid];
    if (gb == 0) offs[NBINS] = Etot;
}

// ---------------- per-node GAT gather (wave per destination, no LDS) ----------------
// Softmax without max-subtract: |e| <~ 10 here, exp is safe in f32 and the
// result is mathematically identical (shift invariance).
__device__ __forceinline__ void seg_gat_g(const int* __restrict__ ssrc, int s0, int s1,
                                          const float* __restrict__ ss, float sd,
                                          const u16* __restrict__ z, int lane,
                                          float4& acc) {
    int cnt = s1 - s0;
    if (cnt <= 0) return;
    int egrp = lane >> 4, cg4 = (lane & 15) * 4;
    if (cnt <= 64) {                    // fast path (deg <= 64: essentially always)
        int s = 0; float w = 0.f;
        if (lane < cnt) {
            s = ssrc[s0 + lane];        // coalesced
            float e = ss[s] + sd;
            e = e > 0.f ? e : ALPHA * e;
            w = __expf(e);
        }
        float den = w;
#pragma unroll
        for (int o = 32; o > 0; o >>= 1) den += __shfl_xor(den, o, 64);
        w *= 1.f / den;
        int nit = (cnt + 3) >> 2;
        for (int it = 0; it < nit; ++it) {
            int ei = it * 4 + egrp;
            float wt = __shfl(w, ei, 64);
            int   st = __shfl(s, ei, 64);
            ushort4 q = *(const ushort4*)(z + (long long)st * 64 + cg4);
            acc.x = fmaf(wt, bf2f(q.x), acc.x);
            acc.y = fmaf(wt, bf2f(q.y), acc.y);
            acc.z = fmaf(wt, bf2f(q.z), acc.z);
            acc.w = fmaf(wt, bf2f(q.w), acc.w);
        }
    } else {                            // general path (rare)
        float den = 0.f;
        for (int i = s0 + lane; i < s1; i += 64) {
            float e = ss[ssrc[i]] + sd; e = e > 0.f ? e : ALPHA * e; den += __expf(e);
        }
#pragma unroll
        for (int o = 32; o > 0; o >>= 1) den += __shfl_xor(den, o, 64);
        float inv = 1.f / den;
        for (int c = s0; c < s1; c += 64) {
            int i = c + lane; int s = 0; float w = 0.f;
            if (i < s1) {
                s = ssrc[i];
                float e = ss[s] + sd; e = e > 0.f ? e : ALPHA * e;
                w = __expf(e) * inv;
            }
            int cc = min(64, s1 - c);
            int nit = (cc + 3) >> 2;
            for (int it = 0; it < nit; ++it) {
                int ei = it * 4 + egrp;
                float wt = __shfl(w, ei, 64);
                int   st = __shfl(s, ei, 64);
                ushort4 q = *(const ushort4*)(z + (long long)st * 64 + cg4);
                acc.x = fmaf(wt, bf2f(q.x), acc.x);
                acc.y = fmaf(wt, bf2f(q.y), acc.y);
                acc.z = fmaf(wt, bf2f(q.z), acc.z);
                acc.w = fmaf(wt, bf2f(q.w), acc.w);
            }
        }
    }
}

__global__ __launch_bounds__(256) void gat_all(
    const int* __restrict__ ssrc, const int* __restrict__ offs,
    const float* __restrict__ WhP, float* __restrict__ outP,
    const float* __restrict__ WhA, float* __restrict__ outA,
    const float* __restrict__ ss_p2p, const float* __restrict__ sd_p2p, const u16* __restrict__ z_p2p,
    const float* __restrict__ ss_a2p, const float* __restrict__ sd_a2p, const u16* __restrict__ z_a2p,
    const float* __restrict__ ss_p2a, const float* __restrict__ sd_p2a, const u16* __restrict__ z_p2a,
    const float* __restrict__ ss_a2a, const float* __restrict__ sd_a2a, const u16* __restrict__ z_a2a) {
    int lane = threadIdx.x & 63;
    int g = (blockIdx.x * blockDim.x + threadIdx.x) >> 6;   // wave id = node id
    if (g >= NP + NA) return;                               // wave-uniform
    bool isP = g < NP;
    int d = isP ? g : g - NP;
    int bin0 = isP ? 2 * d : ABASE + 2 * d;
    int e0 = offs[bin0], e1 = offs[bin0 + 1], e2 = offs[bin0 + 2];
    float4 acc = {0.f, 0.f, 0.f, 0.f};
    if (isP) {
        seg_gat_g(ssrc, e0, e1, ss_p2p, sd_p2p[d], z_p2p, lane, acc);
        seg_gat_g(ssrc, e1, e2, ss_a2p, sd_a2p[d], z_a2p, lane, acc);
    } else {
        seg_gat_g(ssrc, e0, e1, ss_p2a, sd_p2a[d], z_p2a, lane, acc);
        seg_gat_g(ssrc, e1, e2, ss_a2a, sd_a2a[d], z_a2a, lane, acc);
    }
#pragma unroll
    for (int o = 16; o <= 32; o <<= 1) {
        acc.x += __shfl_xor(acc.x, o, 64);
        acc.y += __shfl_xor(acc.y, o, 64);
        acc.z += __shfl_xor(acc.z, o, 64);
        acc.w += __shfl_xor(acc.w, o, 64);
    }
    if (lane < 16) {
        const float* Wh = isP ? WhP : WhA;
        float* outp = isP ? outP : outA;
        float4 self = *(const float4*)&Wh[(long long)d * 64 + lane * 4];
        float4 r;
        r.x = fmaxf(self.x + acc.x, 0.f);
        r.y = fmaxf(self.y + acc.y, 0.f);
        r.z = fmaxf(self.z + acc.z, 0.f);
        r.w = fmaxf(self.w + acc.w, 0.f);
        *(float4*)&outp[(long long)d * 64 + lane * 4] = r;
    }
}

// ---------------- state (single destination) path ----------------
__global__ void state_prep(const float* __restrict__ fS, const float* __restrict__ W_in,
                           const float* __restrict__ b_in, const float* __restrict__ a_p2s,
                           const float* __restrict__ a_a2s, float* __restrict__ outS,
                           float* __restrict__ sdst2, float* __restrict__ den2) {
    int c = threadIdx.x;
    if (c < 2) den2[c] = 0.f;
    float acc = b_in[c];
    for (int k = 0; k < 64; ++k) acc = fmaf(fS[k], W_in[k * 64 + c], acc);
    outS[c] = acc;
    float v0 = acc * a_p2s[64 + c];
    float v1 = acc * a_a2s[64 + c];
#pragma unroll
    for (int off = 32; off > 0; off >>= 1) {
        v0 += __shfl_down(v0, off, 64);
        v1 += __shfl_down(v1, off, 64);
    }
    if (c == 0) { sdst2[0] = v0; sdst2[1] = v1; }
}

// ex = exp(leaky(ss[src]+sdst)) (no max-subtract); den += wave-partials
__global__ void state_eden(const int* __restrict__ srcP, const float* __restrict__ ssP,
                           const int* __restrict__ srcA, const float* __restrict__ ssA,
                           const float* __restrict__ sdst2, float* __restrict__ eP,
                           float* __restrict__ eA, float* __restrict__ den2,
                           int EP, int EA, int nbP) {
    bool isP = (int)blockIdx.x < nbP;
    int bid = isP ? blockIdx.x : blockIdx.x - nbP;
    int i = bid * 256 + threadIdx.x;
    int E = isP ? EP : EA;
    float ex = 0.f;
    if (i < E) {
        const int* src = isP ? srcP : srcA;
        const float* ss = isP ? ssP : ssA;
        float e = ss[src[i]] + sdst2[isP ? 0 : 1];
        e = e > 0.f ? e : ALPHA * e;
        ex = __expf(e);
        (isP ? eP : eA)[i] = ex;
    }
#pragma unroll
    for (int o = 32; o > 0; o >>= 1) ex += __shfl_xor(ex, o, 64);
    if ((threadIdx.x & 63) == 0) atomicAdd(&den2[isP ? 0 : 1], ex);
}

__global__ void state_acc(const int* __restrict__ srcP, const float* __restrict__ eP,
                          const u16* __restrict__ zP, int EP,
                          const int* __restrict__ srcA, const float* __restrict__ eA,
                          const u16* __restrict__ zA, int EA,
                          const float* __restrict__ den2, float* __restrict__ outS, int nbP) {
    __shared__ float red[4][64];
    bool isP = (int)blockIdx.x < nbP;
    const int* src = isP ? srcP : srcA;
    const float* e = isP ? eP : eA;
    const u16* z = isP ? zP : zA;
    int E = isP ? EP : EA;
    float inv = 1.f / den2[isP ? 0 : 1];
    int bid = isP ? blockIdx.x : blockIdx.x - nbP;
    int nb = isP ? nbP : ((int)gridDim.x - nbP);
    int lane = threadIdx.x & 63, wv = threadIdx.x >> 6;
    int egrp = lane >> 4, cg4 = (lane & 15) * 4;
    int gw = bid * 4 + wv;
    int waves = nb * 4;
    float4 acc = {0.f, 0.f, 0.f, 0.f};
    for (int base = gw * 4; base < E; base += waves * 4) {
        int i = base + egrp;
        float w = (i < E) ? e[i] * inv : 0.f;
        int ri = (i < E) ? src[i] : 0;
        ushort4 q = *(const ushort4*)(z + (long long)ri * 64 + cg4);
        acc.x = fmaf(w, bf2f(q.x), acc.x);
        acc.y = fmaf(w, bf2f(q.y), acc.y);
        acc.z = fmaf(w, bf2f(q.z), acc.z);
        acc.w = fmaf(w, bf2f(q.w), acc.w);
    }
#pragma unroll
    for (int o = 16; o <= 32; o <<= 1) {
        acc.x += __shfl_xor(acc.x, o, 64);
        acc.y += __shfl_xor(acc.y, o, 64);
        acc.z += __shfl_xor(acc.z, o, 64);
        acc.w += __shfl_xor(acc.w, o, 64);
    }
    if (lane < 16) ((float4*)red[wv])[lane] = acc;
    __syncthreads();
    if (wv == 0) {
        float t = red[0][lane] + red[1][lane] + red[2][lane] + red[3][lane];
        atomicAdd(&outS[lane], t);
    }
}

__global__ void relu_small(float* __restrict__ p, int n) {
    int i = threadIdx.x;
    if (i < n) p[i] = fmaxf(p[i], 0.f);
}

extern "C" void kernel_launch(void* const* d_in, const int* in_sizes, int n_in,
                              void* d_out, int out_size, void* d_ws, size_t ws_size,
                              hipStream_t stream) {
    const float* feat_P = (const float*)d_in[0];
    const float* feat_A = (const float*)d_in[1];
    const float* feat_S = (const float*)d_in[2];
    const float* W_P   = (const float*)d_in[3];  const float* b_P   = (const float*)d_in[4];
    const float* W_A   = (const float*)d_in[5];  const float* b_A   = (const float*)d_in[6];
    const float* W_p2p = (const float*)d_in[7];  const float* b_p2p = (const float*)d_in[8];
    const float* W_p2a = (const float*)d_in[9];  const float* b_p2a = (const float*)d_in[10];
    const float* W_a2p = (const float*)d_in[11]; const float* b_a2p = (const float*)d_in[12];
    const float* W_a2a = (const float*)d_in[13]; const float* b_a2a = (const float*)d_in[14];
    const float* W_p2s = (const float*)d_in[15]; const float* b_p2s = (const float*)d_in[16];
    const float* W_a2s = (const float*)d_in[17]; const float* b_a2s = (const float*)d_in[18];
    const float* W_in  = (const float*)d_in[19]; const float* b_in  = (const float*)d_in[20];
    const float* a_p2p = (const float*)d_in[21];
    const float* a_p2a = (const float*)d_in[22];
    const float* a_a2p = (const float*)d_in[23];
    const float* a_a2a = (const float*)d_in[24];
    const float* a_p2s = (const float*)d_in[25];
    const float* a_a2s = (const float*)d_in[26];
    const int* src_p2p = (const int*)d_in[27]; const int* dst_p2p = (const int*)d_in[28];
    const int* src_p2a = (const int*)d_in[29]; const int* dst_p2a = (const int*)d_in[30];
    const int* src_a2p = (const int*)d_in[31]; const int* dst_a2p = (const int*)d_in[32];
    const int* src_a2a = (const int*)d_in[33]; const int* dst_a2a = (const int*)d_in[34];
    const int* src_p2s = (const int*)d_in[35];
    const int* src_a2s = (const int*)d_in[37];
    int E_p2p = in_sizes[27], E_p2a = in_sizes[29], E_a2p = in_sizes[31], E_a2a = in_sizes[33];
    int E_p2s = in_sizes[35], E_a2s = in_sizes[37];
    int E_tot = E_p2p + E_a2p + E_p2a + E_a2a;

    float* out = (float*)d_out;
    float* outP = out;
    float* outA = out + (long long)NP * 64;
    float* outS = out + (long long)(NP + NA) * 64;

    // ---- workspace layout ----
    float* ws = (float*)d_ws;
    float* WhP = ws; ws += (long long)NP * 64;
    float* WhA = ws; ws += (long long)NA * 64;
    u16* z_p2p = (u16*)ws; ws += (long long)NP * 32;
    u16* z_p2a = (u16*)ws; ws += (long long)NP * 32;
    u16* z_p2s = (u16*)ws; ws += (long long)NP * 32;
    u16* z_a2p = (u16*)ws; ws += (long long)NA * 32;
    u16* z_a2a = (u16*)ws; ws += (long long)NA * 32;
    u16* z_a2s = (u16*)ws; ws += (long long)NA * 32;
    float* ss_p2p = ws; ws += NP;  float* sd_p2p = ws; ws += NP;
    float* ss_p2a = ws; ws += NP;  float* sd_p2a = ws; ws += NA;
    float* ss_a2p = ws; ws += NA;  float* sd_a2p = ws; ws += NP;
    float* ss_a2a = ws; ws += NA;  float* sd_a2a = ws; ws += NA;
    float* ss_p2s = ws; ws += NP;
    float* ss_a2s = ws; ws += NA;
    float* sdst2  = ws; ws += 2;
    float* den2   = ws; ws += 2;
    float* e_p2s  = ws; ws += NP;
    float* e_a2s  = ws; ws += NA;
    int nblk = (E_tot + CH - 1) / CH;
    int* iw = (int*)ws;
    int* cnt_scan = iw; iw += NBUCK * nblk;    // passA counts -> scanned offsets
    int* bsum     = iw; iw += 1024;
    int* ebuf     = iw; iw += E_tot;           // bucket-grouped packed edges
    int* ssrc     = iw; iw += E_tot;           // fully dst-sorted src indices
    int* offs     = iw; iw += NBINS + 1;       // per-bin global offsets

    const int T = 256;

    // ---- fused transforms + dots ----
    int gP4 = (NP + 63) / 64, gA4 = (NA + 63) / 64;
    xform4<<<gP4, T, 0, stream>>>(feat_P, NP,
        W_P, b_P, WhP, a_p2p + 64, sd_p2p, a_a2p + 64, sd_a2p,
        W_p2p, b_p2p, z_p2p, a_p2p, ss_p2p,
        W_p2a, b_p2a, z_p2a, a_p2a, ss_p2a,
        W_p2s, b_p2s, z_p2s, a_p2s, ss_p2s);
    xform4<<<gA4, T, 0, stream>>>(feat_A, NA,
        W_A, b_A, WhA, a_p2a + 64, sd_p2a, a_a2a + 64, sd_a2a,
        W_a2p, b_a2p, z_a2p, a_a2p, ss_a2p,
        W_a2a, b_a2a, z_a2a, a_a2a, ss_a2a,
        W_a2s, b_a2s, z_a2s, a_a2s, ss_a2s);
    state_prep<<<1, 64, 0, stream>>>(feat_S, W_in, b_in, a_p2s, a_a2s, outS, sdst2, den2);

    // ---- pass A: coarse bucket sort ----
    passA_hist<<<nblk, T, 0, stream>>>(dst_p2p, E_p2p, dst_a2p, E_a2p,
                                       dst_p2a, E_p2a, dst_a2a, E_a2a,
                                       cnt_scan, nblk, E_tot);
    int nScan = NBUCK * nblk;
    int nScanB = (nScan + 255) / 256;
    scan_k1<<<nScanB, 256, 0, stream>>>(cnt_scan, cnt_scan, bsum, nScan);
    scan_k2<<<1, 1024, 0, stream>>>(bsum, nScanB);
    scan_k3<<<nScanB, 256, 0, stream>>>(cnt_scan, bsum, nScan);
    passA_scatter<<<nblk, T, 0, stream>>>(src_p2p, dst_p2p, E_p2p,
                                          src_a2p, dst_a2p, E_a2p,
                                          src_p2a, dst_p2a, E_p2a,
                                          src_a2a, dst_a2a, E_a2a,
                                          cnt_scan, nblk, E_tot, ebuf);
    fine_sort<<<NBUCK, T, 0, stream>>>(ebuf, cnt_scan, nblk, E_tot, ssrc, offs);

    // ---- per-node GAT + self + relu (P and A in one launch, wave per node) ----
    gat_all<<<((NP + NA) * 64 + T - 1) / T, T, 0, stream>>>(ssrc, offs,
        WhP, outP, WhA, outA,
        ss_p2p, sd_p2p, z_p2p, ss_a2p, sd_a2p, z_a2p,
        ss_p2a, sd_p2a, z_p2a, ss_a2a, sd_a2a, z_a2a);

    // ---- state GATs ----
    int nbP = (E_p2s + 255) / 256, nbA = (E_a2s + 255) / 256;
    state_eden<<<nbP + nbA, T, 0, stream>>>(src_p2s, ss_p2s, src_a2s, ss_a2s, sdst2,
                                            e_p2s, e_a2s, den2, E_p2s, E_a2s, nbP);
    state_acc<<<192, T, 0, stream>>>(src_p2s, e_p2s, z_p2s, E_p2s,
                                     src_a2s, e_a2s, z_a2s, E_a2s, den2, outS, 128);
    relu_small<<<1, 64, 0, stream>>>(outS, 64);
}

// Round 6
// 231.289 us; speedup vs baseline: 4.4349x; 1.7248x over previous
//
#include <hip/hip_runtime.h>
#include <math.h>

#define ALPHA 0.2f
#define NP 50000
#define NA 25000
#define NBINS 150000          // P: 2*NP interleaved bins, then A: 2*NA
#define ABASE 100000          // bin base for A nodes
#define NBUCK 586             // ceil(NBINS/256)
#define CH 16384              // edges per passA block
#define CAP 8192              // max edges per bucket held in LDS (mean ~3.5k)

typedef unsigned short u16;
typedef __attribute__((ext_vector_type(8))) short bf16x8;
typedef __attribute__((ext_vector_type(4))) float f32x4;

__device__ __forceinline__ float bf2f(u16 u) { return __uint_as_float(((unsigned)u) << 16); }
__device__ __forceinline__ u16 f2bf(float f) {
    unsigned x = __float_as_uint(f);
    return (u16)((x + 0x7fffu + ((x >> 16) & 1u)) >> 16);   // RNE
}

// ---------------- MFMA 4-matrix transform + attention dots ----------------
// Block = 64 rows; wave w owns matrix w. mat0 -> Wh (f32) + two dst dots;
// mats 1-3 -> z (bf16) + one src dot each. K=64 via 2x mfma_f32_16x16x32_bf16.
// A-frag: lane holds X[row=base+li][k=g*8+j+kc*32]; B-frag: W[k][col=cb*16+li];
// D: row=g*4+reg, col=cb*16+li  (g=lane>>4, li=lane&15).
__global__ __launch_bounds__(256) void xform4m(
    const float* __restrict__ X, int N,
    const float* __restrict__ W0, const float* __restrict__ b0, float* __restrict__ Wh,
    const float* __restrict__ dA, float* __restrict__ sdA,
    const float* __restrict__ dB, float* __restrict__ sdB,
    const float* __restrict__ W1, const float* __restrict__ b1, u16* __restrict__ z1,
    const float* __restrict__ v1, float* __restrict__ s1,
    const float* __restrict__ W2, const float* __restrict__ b2, u16* __restrict__ z2,
    const float* __restrict__ v2, float* __restrict__ s2,
    const float* __restrict__ W3, const float* __restrict__ b3, u16* __restrict__ z3,
    const float* __restrict__ v3, float* __restrict__ s3)
{
    int tid = threadIdx.x, wv = tid >> 6, lane = tid & 63;
    int g = lane >> 4, li = lane & 15;
    const float* Wm = wv == 0 ? W0 : wv == 1 ? W1 : wv == 2 ? W2 : W3;
    const float* bm = wv == 0 ? b0 : wv == 1 ? b1 : wv == 2 ? b2 : b3;
    const float* dv = wv == 0 ? dA : wv == 1 ? v1 : wv == 2 ? v2 : v3;
    float* sm       = wv == 0 ? sdA : wv == 1 ? s1 : wv == 2 ? s2 : s3;
    u16* zm         = wv == 1 ? z1 : wv == 2 ? z2 : wv == 3 ? z3 : nullptr;

    // loop-invariant B fragments (one matrix per wave)
    bf16x8 Bf[4][2];
#pragma unroll
    for (int cb = 0; cb < 4; ++cb)
#pragma unroll
        for (int kc = 0; kc < 2; ++kc) {
            bf16x8 t;
#pragma unroll
            for (int j = 0; j < 8; ++j)
                t[j] = (short)f2bf(Wm[(kc * 32 + g * 8 + j) * 64 + cb * 16 + li]);
            Bf[cb][kc] = t;
        }
    float bl[4], dvl[4], dbl[4];
#pragma unroll
    for (int cb = 0; cb < 4; ++cb) {
        bl[cb]  = bm[cb * 16 + li];
        dvl[cb] = dv[cb * 16 + li];
        dbl[cb] = (wv == 0) ? dB[cb * 16 + li] : 0.f;
    }

    int base0 = blockIdx.x * 64;
#pragma unroll
    for (int rt = 0; rt < 4; ++rt) {
        int rbase = base0 + rt * 16;
        if (rbase >= N) break;
        int rowC = min(rbase + li, N - 1);
        bf16x8 Af[2];
#pragma unroll
        for (int kc = 0; kc < 2; ++kc) {
            const float* xp = X + (long long)rowC * 64 + kc * 32 + g * 8;
            float4 x0 = *(const float4*)xp;
            float4 x1 = *(const float4*)(xp + 4);
            bf16x8 t;
            t[0] = (short)f2bf(x0.x); t[1] = (short)f2bf(x0.y);
            t[2] = (short)f2bf(x0.z); t[3] = (short)f2bf(x0.w);
            t[4] = (short)f2bf(x1.x); t[5] = (short)f2bf(x1.y);
            t[6] = (short)f2bf(x1.z); t[7] = (short)f2bf(x1.w);
            Af[kc] = t;
        }
        f32x4 acc[4] = {{0,0,0,0},{0,0,0,0},{0,0,0,0},{0,0,0,0}};
#pragma unroll
        for (int kc = 0; kc < 2; ++kc)
#pragma unroll
            for (int cb = 0; cb < 4; ++cb)
                acc[cb] = __builtin_amdgcn_mfma_f32_16x16x32_bf16(Af[kc], Bf[cb][kc], acc[cb], 0, 0, 0);
        // bias + dot partials (per reg = per row within group)
        float pd[4] = {0,0,0,0}, pb[4] = {0,0,0,0};
#pragma unroll
        for (int cb = 0; cb < 4; ++cb)
#pragma unroll
            for (int r = 0; r < 4; ++r) {
                float val = acc[cb][r] + bl[cb];
                acc[cb][r] = val;
                pd[r] = fmaf(val, dvl[cb], pd[r]);
                pb[r] = fmaf(val, dbl[cb], pb[r]);
            }
#pragma unroll
        for (int o = 1; o < 16; o <<= 1)
#pragma unroll
            for (int r = 0; r < 4; ++r) {
                pd[r] += __shfl_xor(pd[r], o, 64);
                pb[r] += __shfl_xor(pb[r], o, 64);
            }
        int rg = rbase + g * 4;
        if (li == 0) {
#pragma unroll
            for (int r = 0; r < 4; ++r) {
                int row = rg + r;
                if (row < N) {
                    sm[row] = pd[r];
                    if (wv == 0) sdB[row] = pb[r];
                }
            }
        }
        if (wv == 0) {
#pragma unroll
            for (int r = 0; r < 4; ++r) {
                int row = rg + r;
                if (row < N)
#pragma unroll
                    for (int cb = 0; cb < 4; ++cb)
                        Wh[(long long)row * 64 + cb * 16 + li] = acc[cb][r];
            }
        } else {
#pragma unroll
            for (int r = 0; r < 4; ++r) {
                int row = rg + r;
                if (row < N)
#pragma unroll
                    for (int cb = 0; cb < 4; ++cb)
                        zm[(long long)row * 64 + cb * 16 + li] = f2bf(acc[cb][r]);
            }
        }
    }
}

// ---------------- pass A: coarse bucket sort (256-bin buckets) ----------------
__device__ __forceinline__ int edge_bin(int k,
    const int* __restrict__ d0, int E0, const int* __restrict__ d1, int E1,
    const int* __restrict__ d2, int E2, const int* __restrict__ d3) {
    if (k < E0) return 2 * d0[k];
    k -= E0; if (k < E1) return 2 * d1[k] + 1;
    k -= E1; if (k < E2) return ABASE + 2 * d2[k];
    k -= E2; return ABASE + 2 * d3[k] + 1;
}
__device__ __forceinline__ void edge_decode(int k,
    const int* __restrict__ s0, const int* __restrict__ d0, int E0,
    const int* __restrict__ s1, const int* __restrict__ d1, int E1,
    const int* __restrict__ s2, const int* __restrict__ d2, int E2,
    const int* __restrict__ s3, const int* __restrict__ d3,
    int& src, int& bin) {
    if (k < E0) { src = s0[k]; bin = 2 * d0[k]; return; }
    k -= E0; if (k < E1) { src = s1[k]; bin = 2 * d1[k] + 1; return; }
    k -= E1; if (k < E2) { src = s2[k]; bin = ABASE + 2 * d2[k]; return; }
    k -= E2; src = s3[k]; bin = ABASE + 2 * d3[k] + 1;
}

__global__ __launch_bounds__(256) void passA_hist(
    const int* __restrict__ d0, int E0, const int* __restrict__ d1, int E1,
    const int* __restrict__ d2, int E2, const int* __restrict__ d3, int E3,
    int* __restrict__ cnt, int nblk, int Etot) {
    __shared__ int h[NBUCK];
    int tid = threadIdx.x;
    for (int i = tid; i < NBUCK; i += 256) h[i] = 0;
    __syncthreads();
    int base = blockIdx.x * CH;
    int end = min(base + CH, Etot);
    for (int i = base + tid; i < end; i += 256) {
        int bin = edge_bin(i, d0, E0, d1, E1, d2, E2, d3);
        atomicAdd(&h[bin >> 8], 1);
    }
    __syncthreads();
    for (int i = tid; i < NBUCK; i += 256) cnt[i * nblk + blockIdx.x] = h[i];
}

__global__ void scan_k1(const int* __restrict__ cnt, int* __restrict__ off,
                        int* __restrict__ bsum, int n) {
    __shared__ int s[256];
    int t = threadIdx.x;
    int i = blockIdx.x * 256 + t;
    int v = (i < n) ? cnt[i] : 0;
    s[t] = v;
    __syncthreads();
    for (int o = 1; o < 256; o <<= 1) {
        int x = (t >= o) ? s[t - o] : 0;
        __syncthreads();
        s[t] += x;
        __syncthreads();
    }
    if (i < n) off[i] = s[t] - v;
    if (t == 255) bsum[blockIdx.x] = s[255];
}
__global__ void scan_k2(int* __restrict__ bsum, int nb) {
    __shared__ int s[1024];
    int t = threadIdx.x;
    int v = (t < nb) ? bsum[t] : 0;
    s[t] = v;
    __syncthreads();
    for (int o = 1; o < 1024; o <<= 1) {
        int x = (t >= o) ? s[t - o] : 0;
        __syncthreads();
        s[t] += x;
        __syncthreads();
    }
    if (t < nb) bsum[t] = s[t] - v;
}
__global__ void scan_k3(int* __restrict__ off, const int* __restrict__ bsum, int n) {
    int i = blockIdx.x * 256 + threadIdx.x;
    if (i < n) off[i] += bsum[blockIdx.x];
}

__global__ __launch_bounds__(256) void passA_scatter(
    const int* __restrict__ s0, const int* __restrict__ d0, int E0,
    const int* __restrict__ s1, const int* __restrict__ d1, int E1,
    const int* __restrict__ s2, const int* __restrict__ d2, int E2,
    const int* __restrict__ s3, const int* __restrict__ d3, int E3,
    const int* __restrict__ cnt_scan, int nblk, int Etot, int* __restrict__ ebuf) {
    __shared__ int cur[NBUCK];
    int tid = threadIdx.x;
    for (int i = tid; i < NBUCK; i += 256) cur[i] = cnt_scan[i * nblk + blockIdx.x];
    __syncthreads();
    int base = blockIdx.x * CH;
    int end = min(base + CH, Etot);
    for (int i = base + tid; i < end; i += 256) {
        int src, bin;
        edge_decode(i, s0, d0, E0, s1, d1, E1, s2, d2, E2, s3, d3, src, bin);
        int pos = atomicAdd(&cur[bin >> 8], 1);
        ebuf[pos] = src | ((bin & 255) << 16);
    }
}

// ---------------- fine sort: bucket -> fully dst-sorted ssrc + global offs ----------------
__global__ __launch_bounds__(256) void fine_sort(
    const int* __restrict__ ebuf, const int* __restrict__ cnt_scan, int nblk, int Etot,
    int* __restrict__ ssrc, int* __restrict__ offs) {
    __shared__ int lsrc[CAP];
    __shared__ int lcnt[256];
    __shared__ int loff[256];
    __shared__ int lcur[256];
    __shared__ int stmp[256];
    int b = blockIdx.x;
    int tid = threadIdx.x;
    int bstart = cnt_scan[b * nblk];
    int bend = (b + 1 < NBUCK) ? cnt_scan[(b + 1) * nblk] : Etot;
    int cnt = bend - bstart;
    lcnt[tid] = 0;
    __syncthreads();
    for (int e = bstart + tid; e < bend; e += 256)
        atomicAdd(&lcnt[((unsigned)ebuf[e]) >> 16], 1);
    __syncthreads();
    stmp[tid] = lcnt[tid];
    __syncthreads();
    for (int o = 1; o < 256; o <<= 1) {
        int x = (tid >= o) ? stmp[tid - o] : 0;
        __syncthreads();
        stmp[tid] += x;
        __syncthreads();
    }
    loff[tid] = stmp[tid] - lcnt[tid];
    lcur[tid] = loff[tid];
    __syncthreads();
    if (cnt <= CAP) {
        for (int e = bstart + tid; e < bend; e += 256) {
            int v = ebuf[e];
            int pos = atomicAdd(&lcur[((unsigned)v) >> 16], 1);
            lsrc[pos] = v & 0xFFFF;
        }
        __syncthreads();
        for (int i = tid; i < cnt; i += 256) ssrc[bstart + i] = lsrc[i];   // coalesced
    } else {
        for (int e = bstart + tid; e < bend; e += 256) {
            int v = ebuf[e];
            int pos = atomicAdd(&lcur[((unsigned)v) >> 16], 1);
            ssrc[bstart + pos] = v & 0xFFFF;
        }
    }
    int gb = b * 256 + tid;
    if (gb < NBINS) offs[gb] = bstart + loff[tid];
    if (gb == 0) offs[NBINS] = Etot;
}

// ---------------- per-node GAT gather (wave per destination, no LDS) ----------------
__device__ __forceinline__ void seg_gat_g(const int* __restrict__ ssrc, int s0, int s1,
                                          const float* __restrict__ ss, float sd,
                                          const u16* __restrict__ z, int lane,
                                          float4& acc) {
    int cnt = s1 - s0;
    if (cnt <= 0) return;
    int egrp = lane >> 4, cg4 = (lane & 15) * 4;
    if (cnt <= 64) {                    // fast path (deg <= 64: essentially always)
        int s = 0; float w = 0.f;
        if (lane < cnt) {
            s = ssrc[s0 + lane];        // coalesced
            float e = ss[s] + sd;
            e = e > 0.f ? e : ALPHA * e;
            w = __expf(e);
        }
        float den = w;
#pragma unroll
        for (int o = 32; o > 0; o >>= 1) den += __shfl_xor(den, o, 64);
        w *= 1.f / den;
        int nit = (cnt + 3) >> 2;
        for (int it = 0; it < nit; ++it) {
            int ei = it * 4 + egrp;
            float wt = __shfl(w, ei, 64);
            int   st = __shfl(s, ei, 64);
            ushort4 q = *(const ushort4*)(z + (long long)st * 64 + cg4);
            acc.x = fmaf(wt, bf2f(q.x), acc.x);
            acc.y = fmaf(wt, bf2f(q.y), acc.y);
            acc.z = fmaf(wt, bf2f(q.z), acc.z);
            acc.w = fmaf(wt, bf2f(q.w), acc.w);
        }
    } else {                            // general path (rare)
        float den = 0.f;
        for (int i = s0 + lane; i < s1; i += 64) {
            float e = ss[ssrc[i]] + sd; e = e > 0.f ? e : ALPHA * e; den += __expf(e);
        }
#pragma unroll
        for (int o = 32; o > 0; o >>= 1) den += __shfl_xor(den, o, 64);
        float inv = 1.f / den;
        for (int c = s0; c < s1; c += 64) {
            int i = c + lane; int s = 0; float w = 0.f;
            if (i < s1) {
                s = ssrc[i];
                float e = ss[s] + sd; e = e > 0.f ? e : ALPHA * e;
                w = __expf(e) * inv;
            }
            int cc = min(64, s1 - c);
            int nit = (cc + 3) >> 2;
            for (int it = 0; it < nit; ++it) {
                int ei = it * 4 + egrp;
                float wt = __shfl(w, ei, 64);
                int   st = __shfl(s, ei, 64);
                ushort4 q = *(const ushort4*)(z + (long long)st * 64 + cg4);
                acc.x = fmaf(wt, bf2f(q.x), acc.x);
                acc.y = fmaf(wt, bf2f(q.y), acc.y);
                acc.z = fmaf(wt, bf2f(q.z), acc.z);
                acc.w = fmaf(wt, bf2f(q.w), acc.w);
            }
        }
    }
}

__global__ __launch_bounds__(256) void gat_all(
    const int* __restrict__ ssrc, const int* __restrict__ offs,
    const float* __restrict__ WhP, float* __restrict__ outP,
    const float* __restrict__ WhA, float* __restrict__ outA,
    const float* __restrict__ ss_p2p, const float* __restrict__ sd_p2p, const u16* __restrict__ z_p2p,
    const float* __restrict__ ss_a2p, const float* __restrict__ sd_a2p, const u16* __restrict__ z_a2p,
    const float* __restrict__ ss_p2a, const float* __restrict__ sd_p2a, const u16* __restrict__ z_p2a,
    const float* __restrict__ ss_a2a, const float* __restrict__ sd_a2a, const u16* __restrict__ z_a2a) {
    int lane = threadIdx.x & 63;
    int g = (blockIdx.x * blockDim.x + threadIdx.x) >> 6;   // wave id = node id
    if (g >= NP + NA) return;                               // wave-uniform
    bool isP = g < NP;
    int d = isP ? g : g - NP;
    int bin0 = isP ? 2 * d : ABASE + 2 * d;
    int e0 = offs[bin0], e1 = offs[bin0 + 1], e2 = offs[bin0 + 2];
    float4 acc = {0.f, 0.f, 0.f, 0.f};
    if (isP) {
        seg_gat_g(ssrc, e0, e1, ss_p2p, sd_p2p[d], z_p2p, lane, acc);
        seg_gat_g(ssrc, e1, e2, ss_a2p, sd_a2p[d], z_a2p, lane, acc);
    } else {
        seg_gat_g(ssrc, e0, e1, ss_p2a, sd_p2a[d], z_p2a, lane, acc);
        seg_gat_g(ssrc, e1, e2, ss_a2a, sd_a2a[d], z_a2a, lane, acc);
    }
#pragma unroll
    for (int o = 16; o <= 32; o <<= 1) {
        acc.x += __shfl_xor(acc.x, o, 64);
        acc.y += __shfl_xor(acc.y, o, 64);
        acc.z += __shfl_xor(acc.z, o, 64);
        acc.w += __shfl_xor(acc.w, o, 64);
    }
    if (lane < 16) {
        const float* Wh = isP ? WhP : WhA;
        float* outp = isP ? outP : outA;
        float4 self = *(const float4*)&Wh[(long long)d * 64 + lane * 4];
        float4 r;
        r.x = fmaxf(self.x + acc.x, 0.f);
        r.y = fmaxf(self.y + acc.y, 0.f);
        r.z = fmaxf(self.z + acc.z, 0.f);
        r.w = fmaxf(self.w + acc.w, 0.f);
        *(float4*)&outp[(long long)d * 64 + lane * 4] = r;
    }
}

// ---------------- state (single destination) path ----------------
__global__ void state_prep(const float* __restrict__ fS, const float* __restrict__ W_in,
                           const float* __restrict__ b_in, const float* __restrict__ a_p2s,
                           const float* __restrict__ a_a2s, float* __restrict__ outS,
                           float* __restrict__ sdst2, float* __restrict__ den2) {
    int c = threadIdx.x;
    if (c < 2) den2[c] = 0.f;
    float acc = b_in[c];
    for (int k = 0; k < 64; ++k) acc = fmaf(fS[k], W_in[k * 64 + c], acc);
    outS[c] = acc;
    float v0 = acc * a_p2s[64 + c];
    float v1 = acc * a_a2s[64 + c];
#pragma unroll
    for (int off = 32; off > 0; off >>= 1) {
        v0 += __shfl_down(v0, off, 64);
        v1 += __shfl_down(v1, off, 64);
    }
    if (c == 0) { sdst2[0] = v0; sdst2[1] = v1; }
}

__global__ void state_eden(const int* __restrict__ srcP, const float* __restrict__ ssP,
                           const int* __restrict__ srcA, const float* __restrict__ ssA,
                           const float* __restrict__ sdst2, float* __restrict__ eP,
                           float* __restrict__ eA, float* __restrict__ den2,
                           int EP, int EA, int nbP) {
    bool isP = (int)blockIdx.x < nbP;
    int bid = isP ? blockIdx.x : blockIdx.x - nbP;
    int i = bid * 256 + threadIdx.x;
    int E = isP ? EP : EA;
    float ex = 0.f;
    if (i < E) {
        const int* src = isP ? srcP : srcA;
        const float* ss = isP ? ssP : ssA;
        float e = ss[src[i]] + sdst2[isP ? 0 : 1];
        e = e > 0.f ? e : ALPHA * e;
        ex = __expf(e);
        (isP ? eP : eA)[i] = ex;
    }
#pragma unroll
    for (int o = 32; o > 0; o >>= 1) ex += __shfl_xor(ex, o, 64);
    if ((threadIdx.x & 63) == 0) atomicAdd(&den2[isP ? 0 : 1], ex);
}

__global__ void state_acc(const int* __restrict__ srcP, const float* __restrict__ eP,
                          const u16* __restrict__ zP, int EP,
                          const int* __restrict__ srcA, const float* __restrict__ eA,
                          const u16* __restrict__ zA, int EA,
                          const float* __restrict__ den2, float* __restrict__ outS, int nbP) {
    __shared__ float red[4][64];
    bool isP = (int)blockIdx.x < nbP;
    const int* src = isP ? srcP : srcA;
    const float* e = isP ? eP : eA;
    const u16* z = isP ? zP : zA;
    int E = isP ? EP : EA;
    float inv = 1.f / den2[isP ? 0 : 1];
    int bid = isP ? blockIdx.x : blockIdx.x - nbP;
    int nb = isP ? nbP : ((int)gridDim.x - nbP);
    int lane = threadIdx.x & 63, wv = threadIdx.x >> 6;
    int egrp = lane >> 4, cg4 = (lane & 15) * 4;
    int gw = bid * 4 + wv;
    int waves = nb * 4;
    float4 acc = {0.f, 0.f, 0.f, 0.f};
    for (int base = gw * 4; base < E; base += waves * 4) {
        int i = base + egrp;
        float w = (i < E) ? e[i] * inv : 0.f;
        int ri = (i < E) ? src[i] : 0;
        ushort4 q = *(const ushort4*)(z + (long long)ri * 64 + cg4);
        acc.x = fmaf(w, bf2f(q.x), acc.x);
        acc.y = fmaf(w, bf2f(q.y), acc.y);
        acc.z = fmaf(w, bf2f(q.z), acc.z);
        acc.w = fmaf(w, bf2f(q.w), acc.w);
    }
#pragma unroll
    for (int o = 16; o <= 32; o <<= 1) {
        acc.x += __shfl_xor(acc.x, o, 64);
        acc.y += __shfl_xor(acc.y, o, 64);
        acc.z += __shfl_xor(acc.z, o, 64);
        acc.w += __shfl_xor(acc.w, o, 64);
    }
    if (lane < 16) ((float4*)red[wv])[lane] = acc;
    __syncthreads();
    if (wv == 0) {
        float t = red[0][lane] + red[1][lane] + red[2][lane] + red[3][lane];
        atomicAdd(&outS[lane], t);
    }
}

__global__ void relu_small(float* __restrict__ p, int n) {
    int i = threadIdx.x;
    if (i < n) p[i] = fmaxf(p[i], 0.f);
}

extern "C" void kernel_launch(void* const* d_in, const int* in_sizes, int n_in,
                              void* d_out, int out_size, void* d_ws, size_t ws_size,
                              hipStream_t stream) {
    const float* feat_P = (const float*)d_in[0];
    const float* feat_A = (const float*)d_in[1];
    const float* feat_S = (const float*)d_in[2];
    const float* W_P   = (const float*)d_in[3];  const float* b_P   = (const float*)d_in[4];
    const float* W_A   = (const float*)d_in[5];  const float* b_A   = (const float*)d_in[6];
    const float* W_p2p = (const float*)d_in[7];  const float* b_p2p = (const float*)d_in[8];
    const float* W_p2a = (const float*)d_in[9];  const float* b_p2a = (const float*)d_in[10];
    const float* W_a2p = (const float*)d_in[11]; const float* b_a2p = (const float*)d_in[12];
    const float* W_a2a = (const float*)d_in[13]; const float* b_a2a = (const float*)d_in[14];
    const float* W_p2s = (const float*)d_in[15]; const float* b_p2s = (const float*)d_in[16];
    const float* W_a2s = (const float*)d_in[17]; const float* b_a2s = (const float*)d_in[18];
    const float* W_in  = (const float*)d_in[19]; const float* b_in  = (const float*)d_in[20];
    const float* a_p2p = (const float*)d_in[21];
    const float* a_p2a = (const float*)d_in[22];
    const float* a_a2p = (const float*)d_in[23];
    const float* a_a2a = (const float*)d_in[24];
    const float* a_p2s = (const float*)d_in[25];
    const float* a_a2s = (const float*)d_in[26];
    const int* src_p2p = (const int*)d_in[27]; const int* dst_p2p = (const int*)d_in[28];
    const int* src_p2a = (const int*)d_in[29]; const int* dst_p2a = (const int*)d_in[30];
    const int* src_a2p = (const int*)d_in[31]; const int* dst_a2p = (const int*)d_in[32];
    const int* src_a2a = (const int*)d_in[33]; const int* dst_a2a = (const int*)d_in[34];
    const int* src_p2s = (const int*)d_in[35];
    const int* src_a2s = (const int*)d_in[37];
    int E_p2p = in_sizes[27], E_p2a = in_sizes[29], E_a2p = in_sizes[31], E_a2a = in_sizes[33];
    int E_p2s = in_sizes[35], E_a2s = in_sizes[37];
    int E_tot = E_p2p + E_a2p + E_p2a + E_a2a;

    float* out = (float*)d_out;
    float* outP = out;
    float* outA = out + (long long)NP * 64;
    float* outS = out + (long long)(NP + NA) * 64;

    // ---- workspace layout ----
    float* ws = (float*)d_ws;
    float* WhP = ws; ws += (long long)NP * 64;
    float* WhA = ws; ws += (long long)NA * 64;
    u16* z_p2p = (u16*)ws; ws += (long long)NP * 32;
    u16* z_p2a = (u16*)ws; ws += (long long)NP * 32;
    u16* z_p2s = (u16*)ws; ws += (long long)NP * 32;
    u16* z_a2p = (u16*)ws; ws += (long long)NA * 32;
    u16* z_a2a = (u16*)ws; ws += (long long)NA * 32;
    u16* z_a2s = (u16*)ws; ws += (long long)NA * 32;
    float* ss_p2p = ws; ws += NP;  float* sd_p2p = ws; ws += NP;
    float* ss_p2a = ws; ws += NP;  float* sd_p2a = ws; ws += NA;
    float* ss_a2p = ws; ws += NA;  float* sd_a2p = ws; ws += NP;
    float* ss_a2a = ws; ws += NA;  float* sd_a2a = ws; ws += NA;
    float* ss_p2s = ws; ws += NP;
    float* ss_a2s = ws; ws += NA;
    float* sdst2  = ws; ws += 2;
    float* den2   = ws; ws += 2;
    float* e_p2s  = ws; ws += NP;
    float* e_a2s  = ws; ws += NA;
    int nblk = (E_tot + CH - 1) / CH;
    int* iw = (int*)ws;
    int* cnt_scan = iw; iw += NBUCK * nblk;    // passA counts -> scanned offsets
    int* bsum     = iw; iw += 1024;
    int* ebuf     = iw; iw += E_tot;           // bucket-grouped packed edges
    int* ssrc     = iw; iw += E_tot;           // fully dst-sorted src indices
    int* offs     = iw; iw += NBINS + 1;       // per-bin global offsets

    const int T = 256;

    // ---- MFMA transforms + dots ----
    int gP = (NP + 63) / 64, gA = (NA + 63) / 64;
    xform4m<<<gP, T, 0, stream>>>(feat_P, NP,
        W_P, b_P, WhP, a_p2p + 64, sd_p2p, a_a2p + 64, sd_a2p,
        W_p2p, b_p2p, z_p2p, a_p2p, ss_p2p,
        W_p2a, b_p2a, z_p2a, a_p2a, ss_p2a,
        W_p2s, b_p2s, z_p2s, a_p2s, ss_p2s);
    xform4m<<<gA, T, 0, stream>>>(feat_A, NA,
        W_A, b_A, WhA, a_p2a + 64, sd_p2a, a_a2a + 64, sd_a2a,
        W_a2p, b_a2p, z_a2p, a_a2p, ss_a2p,
        W_a2a, b_a2a, z_a2a, a_a2a, ss_a2a,
        W_a2s, b_a2s, z_a2s, a_a2s, ss_a2s);
    state_prep<<<1, 64, 0, stream>>>(feat_S, W_in, b_in, a_p2s, a_a2s, outS, sdst2, den2);

    // ---- pass A: coarse bucket sort ----
    passA_hist<<<nblk, T, 0, stream>>>(dst_p2p, E_p2p, dst_a2p, E_a2p,
                                       dst_p2a, E_p2a, dst_a2a, E_a2a,
                                       cnt_scan, nblk, E_tot);
    int nScan = NBUCK * nblk;
    int nScanB = (nScan + 255) / 256;
    scan_k1<<<nScanB, 256, 0, stream>>>(cnt_scan, cnt_scan, bsum, nScan);
    scan_k2<<<1, 1024, 0, stream>>>(bsum, nScanB);
    scan_k3<<<nScanB, 256, 0, stream>>>(cnt_scan, bsum, nScan);
    passA_scatter<<<nblk, T, 0, stream>>>(src_p2p, dst_p2p, E_p2p,
                                          src_a2p, dst_a2p, E_a2p,
                                          src_p2a, dst_p2a, E_p2a,
                                          src_a2a, dst_a2a, E_a2a,
                                          cnt_scan, nblk, E_tot, ebuf);
    fine_sort<<<NBUCK, T, 0, stream>>>(ebuf, cnt_scan, nblk, E_tot, ssrc, offs);

    // ---- per-node GAT + self + relu (P and A in one launch, wave per node) ----
    gat_all<<<((NP + NA) * 64 + T - 1) / T, T, 0, stream>>>(ssrc, offs,
        WhP, outP, WhA, outA,
        ss_p2p, sd_p2p, z_p2p, ss_a2p, sd_a2p, z_a2p,
        ss_p2a, sd_p2a, z_p2a, ss_a2a, sd_a2a, z_a2a);

    // ---- state GATs ----
    int nbP = (E_p2s + 255) / 256, nbA = (E_a2s + 255) / 256;
    state_eden<<<nbP + nbA, T, 0, stream>>>(src_p2s, ss_p2s, src_a2s, ss_a2s, sdst2,
                                            e_p2s, e_a2s, den2, E_p2s, E_a2s, nbP);
    state_acc<<<192, T, 0, stream>>>(src_p2s, e_p2s, z_p2s, E_p2s,
                                     src_a2s, e_a2s, z_a2s, E_a2s, den2, outS, 128);
    relu_small<<<1, 64, 0, stream>>>(outS, 64);
}

// Round 7
// 230.679 us; speedup vs baseline: 4.4466x; 1.0026x over previous
//
#include <hip/hip_runtime.h>
#include <math.h>

#define ALPHA 0.2f
#define NP 50000
#define NA 25000
#define NBINS 150000          // P: 2*NP interleaved bins, then A: 2*NA
#define ABASE 100000          // bin base for A nodes
#define NBUCK 586             // ceil(NBINS/256)
#define CH 16384              // edges per scatter block
#define CAP 8192              // max edges per bucket held in LDS (mean ~3.5k)

typedef unsigned short u16;
typedef __attribute__((ext_vector_type(8))) short bf16x8;
typedef __attribute__((ext_vector_type(8))) unsigned short u16x8;
typedef __attribute__((ext_vector_type(4))) float f32x4;

__device__ __forceinline__ float bf2f(u16 u) { return __uint_as_float(((unsigned)u) << 16); }
__device__ __forceinline__ u16 f2bf(float f) {
    unsigned x = __float_as_uint(f);
    return (u16)((x + 0x7fffu + ((x >> 16) & 1u)) >> 16);   // RNE
}

// ---------------- MFMA 4-matrix transform + attention dots (unchanged from R6) ----------------
__global__ __launch_bounds__(256) void xform4m(
    const float* __restrict__ X, int N,
    const float* __restrict__ W0, const float* __restrict__ b0, float* __restrict__ Wh,
    const float* __restrict__ dA, float* __restrict__ sdA,
    const float* __restrict__ dB, float* __restrict__ sdB,
    const float* __restrict__ W1, const float* __restrict__ b1, u16* __restrict__ z1,
    const float* __restrict__ v1, float* __restrict__ s1,
    const float* __restrict__ W2, const float* __restrict__ b2, u16* __restrict__ z2,
    const float* __restrict__ v2, float* __restrict__ s2,
    const float* __restrict__ W3, const float* __restrict__ b3, u16* __restrict__ z3,
    const float* __restrict__ v3, float* __restrict__ s3)
{
    int tid = threadIdx.x, wv = tid >> 6, lane = tid & 63;
    int g = lane >> 4, li = lane & 15;
    const float* Wm = wv == 0 ? W0 : wv == 1 ? W1 : wv == 2 ? W2 : W3;
    const float* bm = wv == 0 ? b0 : wv == 1 ? b1 : wv == 2 ? b2 : b3;
    const float* dv = wv == 0 ? dA : wv == 1 ? v1 : wv == 2 ? v2 : v3;
    float* sm       = wv == 0 ? sdA : wv == 1 ? s1 : wv == 2 ? s2 : s3;
    u16* zm         = wv == 1 ? z1 : wv == 2 ? z2 : wv == 3 ? z3 : nullptr;

    bf16x8 Bf[4][2];
#pragma unroll
    for (int cb = 0; cb < 4; ++cb)
#pragma unroll
        for (int kc = 0; kc < 2; ++kc) {
            bf16x8 t;
#pragma unroll
            for (int j = 0; j < 8; ++j)
                t[j] = (short)f2bf(Wm[(kc * 32 + g * 8 + j) * 64 + cb * 16 + li]);
            Bf[cb][kc] = t;
        }
    float bl[4], dvl[4], dbl[4];
#pragma unroll
    for (int cb = 0; cb < 4; ++cb) {
        bl[cb]  = bm[cb * 16 + li];
        dvl[cb] = dv[cb * 16 + li];
        dbl[cb] = (wv == 0) ? dB[cb * 16 + li] : 0.f;
    }

    int base0 = blockIdx.x * 64;
#pragma unroll
    for (int rt = 0; rt < 4; ++rt) {
        int rbase = base0 + rt * 16;
        if (rbase >= N) break;
        int rowC = min(rbase + li, N - 1);
        bf16x8 Af[2];
#pragma unroll
        for (int kc = 0; kc < 2; ++kc) {
            const float* xp = X + (long long)rowC * 64 + kc * 32 + g * 8;
            float4 x0 = *(const float4*)xp;
            float4 x1 = *(const float4*)(xp + 4);
            bf16x8 t;
            t[0] = (short)f2bf(x0.x); t[1] = (short)f2bf(x0.y);
            t[2] = (short)f2bf(x0.z); t[3] = (short)f2bf(x0.w);
            t[4] = (short)f2bf(x1.x); t[5] = (short)f2bf(x1.y);
            t[6] = (short)f2bf(x1.z); t[7] = (short)f2bf(x1.w);
            Af[kc] = t;
        }
        f32x4 acc[4] = {{0,0,0,0},{0,0,0,0},{0,0,0,0},{0,0,0,0}};
#pragma unroll
        for (int kc = 0; kc < 2; ++kc)
#pragma unroll
            for (int cb = 0; cb < 4; ++cb)
                acc[cb] = __builtin_amdgcn_mfma_f32_16x16x32_bf16(Af[kc], Bf[cb][kc], acc[cb], 0, 0, 0);
        float pd[4] = {0,0,0,0}, pb[4] = {0,0,0,0};
#pragma unroll
        for (int cb = 0; cb < 4; ++cb)
#pragma unroll
            for (int r = 0; r < 4; ++r) {
                float val = acc[cb][r] + bl[cb];
                acc[cb][r] = val;
                pd[r] = fmaf(val, dvl[cb], pd[r]);
                pb[r] = fmaf(val, dbl[cb], pb[r]);
            }
#pragma unroll
        for (int o = 1; o < 16; o <<= 1)
#pragma unroll
            for (int r = 0; r < 4; ++r) {
                pd[r] += __shfl_xor(pd[r], o, 64);
                pb[r] += __shfl_xor(pb[r], o, 64);
            }
        int rg = rbase + g * 4;
        if (li == 0) {
#pragma unroll
            for (int r = 0; r < 4; ++r) {
                int row = rg + r;
                if (row < N) {
                    sm[row] = pd[r];
                    if (wv == 0) sdB[row] = pb[r];
                }
            }
        }
        if (wv == 0) {
#pragma unroll
            for (int r = 0; r < 4; ++r) {
                int row = rg + r;
                if (row < N)
#pragma unroll
                    for (int cb = 0; cb < 4; ++cb)
                        Wh[(long long)row * 64 + cb * 16 + li] = acc[cb][r];
            }
        } else {
#pragma unroll
            for (int r = 0; r < 4; ++r) {
                int row = rg + r;
                if (row < N)
#pragma unroll
                    for (int cb = 0; cb < 4; ++cb)
                        zm[(long long)row * 64 + cb * 16 + li] = f2bf(acc[cb][r]);
            }
        }
    }
}

// ---------------- edge decode helpers ----------------
__device__ __forceinline__ int edge_bin(int k,
    const int* __restrict__ d0, int E0, const int* __restrict__ d1, int E1,
    const int* __restrict__ d2, int E2, const int* __restrict__ d3) {
    if (k < E0) return 2 * d0[k];
    k -= E0; if (k < E1) return 2 * d1[k] + 1;
    k -= E1; if (k < E2) return ABASE + 2 * d2[k];
    k -= E2; return ABASE + 2 * d3[k] + 1;
}
__device__ __forceinline__ void edge_decode(int k,
    const int* __restrict__ s0, const int* __restrict__ d0, int E0,
    const int* __restrict__ s1, const int* __restrict__ d1, int E1,
    const int* __restrict__ s2, const int* __restrict__ d2, int E2,
    const int* __restrict__ s3, const int* __restrict__ d3,
    int& src, int& bin) {
    if (k < E0) { src = s0[k]; bin = 2 * d0[k]; return; }
    k -= E0; if (k < E1) { src = s1[k]; bin = 2 * d1[k] + 1; return; }
    k -= E1; if (k < E2) { src = s2[k]; bin = ABASE + 2 * d2[k]; return; }
    k -= E2; src = s3[k]; bin = ABASE + 2 * d3[k] + 1;
}

// ---------------- bucket totals (LDS hist -> global atomics) ----------------
__global__ __launch_bounds__(256) void bucket_count(
    const int* __restrict__ d0, int E0, const int* __restrict__ d1, int E1,
    const int* __restrict__ d2, int E2, const int* __restrict__ d3, int E3,
    int* __restrict__ bucktot, int Etot) {
    __shared__ int h[NBUCK];
    int tid = threadIdx.x;
    for (int i = tid; i < NBUCK; i += 256) h[i] = 0;
    __syncthreads();
    int stride = gridDim.x * 256;
    for (int i = blockIdx.x * 256 + tid; i < Etot; i += stride) {
        int bin = edge_bin(i, d0, E0, d1, E1, d2, E2, d3);
        atomicAdd(&h[bin >> 8], 1);
    }
    __syncthreads();
    for (int i = tid; i < NBUCK; i += 256)
        if (h[i]) atomicAdd(&bucktot[i], h[i]);
}

// ---------------- tiny single-block scan of 586 bucket totals ----------------
__global__ __launch_bounds__(1024) void bucket_scan(const int* __restrict__ bucktot,
                                                    int* __restrict__ starts,
                                                    int* __restrict__ cursor, int Etot) {
    __shared__ int wtot[16];
    int t = threadIdx.x, lane = t & 63, wv = t >> 6;
    int v = (t < NBUCK) ? bucktot[t] : 0;
    int x = v;
#pragma unroll
    for (int o = 1; o < 64; o <<= 1) {
        int y = __shfl_up(x, o, 64);
        if (lane >= o) x += y;
    }
    if (lane == 63) wtot[wv] = x;
    __syncthreads();
    int woff = 0;
    for (int j = 0; j < wv; ++j) woff += wtot[j];
    int excl = x + woff - v;
    if (t < NBUCK) { starts[t] = excl; cursor[t] = excl; }
    if (t == 0) starts[NBUCK] = Etot;
}

// ---------------- scatter: per-block window reservation + packed write ----------------
__global__ __launch_bounds__(256) void passA_scatter(
    const int* __restrict__ s0, const int* __restrict__ d0, int E0,
    const int* __restrict__ s1, const int* __restrict__ d1, int E1,
    const int* __restrict__ s2, const int* __restrict__ d2, int E2,
    const int* __restrict__ s3, const int* __restrict__ d3, int E3,
    int* __restrict__ cursor, int Etot, int* __restrict__ ebuf) {
    __shared__ int h[NBUCK];
    __shared__ int base[NBUCK];
    int tid = threadIdx.x;
    for (int i = tid; i < NBUCK; i += 256) h[i] = 0;
    __syncthreads();
    int b0 = blockIdx.x * CH;
    int b1 = min(b0 + CH, Etot);
    for (int i = b0 + tid; i < b1; i += 256) {
        int bin = edge_bin(i, d0, E0, d1, E1, d2, E2, d3);
        atomicAdd(&h[bin >> 8], 1);
    }
    __syncthreads();
    for (int i = tid; i < NBUCK; i += 256) {
        int c = h[i];
        base[i] = c ? atomicAdd(&cursor[i], c) : 0;
        h[i] = 0;                               // reuse as local cursor
    }
    __syncthreads();
    for (int i = b0 + tid; i < b1; i += 256) {
        int src, bin;
        edge_decode(i, s0, d0, E0, s1, d1, E1, s2, d2, E2, s3, d3, src, bin);
        int bk = bin >> 8;
        int pos = base[bk] + atomicAdd(&h[bk], 1);
        ebuf[pos] = src | ((bin & 255) << 16);
    }
}

// ---------------- fine sort: bucket -> fully dst-sorted ssrc + global offs ----------------
__global__ __launch_bounds__(256) void fine_sort(
    const int* __restrict__ ebuf, const int* __restrict__ starts, int Etot,
    int* __restrict__ ssrc, int* __restrict__ offs) {
    __shared__ int lsrc[CAP];
    __shared__ int lcnt[256];
    __shared__ int loff[256];
    __shared__ int lcur[256];
    __shared__ int wtot[4];
    int b = blockIdx.x;
    int tid = threadIdx.x, lane = tid & 63, wv = tid >> 6;
    int bstart = starts[b];
    int bend = starts[b + 1];
    int cnt = bend - bstart;
    lcnt[tid] = 0;
    __syncthreads();
    for (int e = bstart + tid; e < bend; e += 256)
        atomicAdd(&lcnt[((unsigned)ebuf[e]) >> 16], 1);
    __syncthreads();
    // wave-level exclusive scan over 256 bins (2 barriers total)
    int v = lcnt[tid];
    int x = v;
#pragma unroll
    for (int o = 1; o < 64; o <<= 1) {
        int y = __shfl_up(x, o, 64);
        if (lane >= o) x += y;
    }
    if (lane == 63) wtot[wv] = x;
    __syncthreads();
    int woff = 0;
    for (int j = 0; j < wv; ++j) woff += wtot[j];
    int excl = x + woff - v;
    loff[tid] = excl;
    lcur[tid] = excl;
    __syncthreads();
    if (cnt <= CAP) {
        for (int e = bstart + tid; e < bend; e += 256) {
            int val = ebuf[e];
            int pos = atomicAdd(&lcur[((unsigned)val) >> 16], 1);
            lsrc[pos] = val & 0xFFFF;
        }
        __syncthreads();
        for (int i = tid; i < cnt; i += 256) ssrc[bstart + i] = lsrc[i];   // coalesced
    } else {                                   // overflow fallback
        for (int e = bstart + tid; e < bend; e += 256) {
            int val = ebuf[e];
            int pos = atomicAdd(&lcur[((unsigned)val) >> 16], 1);
            ssrc[bstart + pos] = val & 0xFFFF;
        }
    }
    int gb = b * 256 + tid;
    if (gb < NBINS) offs[gb] = bstart + loff[tid];
    if (gb == 0) offs[NBINS] = Etot;
}

// ---------------- per-node GAT gather: 8 edges in flight, 16B z loads ----------------
__device__ __forceinline__ void seg_gat_g8(const int* __restrict__ ssrc, int s0, int s1,
                                           const float* __restrict__ ss, float sd,
                                           const u16* __restrict__ z, int lane,
                                           float* __restrict__ acc) {
    int cnt = s1 - s0;
    if (cnt <= 0) return;
    int egrp = lane >> 3, cg8 = (lane & 7) * 8;
    if (cnt <= 64) {                    // fast path (deg <= 64: essentially always)
        int s = 0; float w = 0.f;
        if (lane < cnt) {
            s = ssrc[s0 + lane];        // coalesced
            float e = ss[s] + sd;
            e = e > 0.f ? e : ALPHA * e;
            w = __expf(e);
        }
        float den = w;
#pragma unroll
        for (int o = 32; o > 0; o >>= 1) den += __shfl_xor(den, o, 64);
        w *= 1.f / den;
        int nit = (cnt + 7) >> 3;
        for (int it = 0; it < nit; ++it) {
            int ei = it * 8 + egrp;
            float wt = __shfl(w, ei, 64);   // 0 for ei >= cnt
            int   st = __shfl(s, ei, 64);
            u16x8 q = *(const u16x8*)(z + (long long)st * 64 + cg8);
#pragma unroll
            for (int j = 0; j < 8; ++j)
                acc[j] = fmaf(wt, bf2f(q[j]), acc[j]);
        }
    } else {                            // general path (rare)
        float den = 0.f;
        for (int i = s0 + lane; i < s1; i += 64) {
            float e = ss[ssrc[i]] + sd; e = e > 0.f ? e : ALPHA * e; den += __expf(e);
        }
#pragma unroll
        for (int o = 32; o > 0; o >>= 1) den += __shfl_xor(den, o, 64);
        float inv = 1.f / den;
        for (int c = s0; c < s1; c += 64) {
            int i = c + lane; int s = 0; float w = 0.f;
            if (i < s1) {
                s = ssrc[i];
                float e = ss[s] + sd; e = e > 0.f ? e : ALPHA * e;
                w = __expf(e) * inv;
            }
            int cc = min(64, s1 - c);
            int nit = (cc + 7) >> 3;
            for (int it = 0; it < nit; ++it) {
                int ei = it * 8 + egrp;
                float wt = __shfl(w, ei, 64);
                int   st = __shfl(s, ei, 64);
                u16x8 q = *(const u16x8*)(z + (long long)st * 64 + cg8);
#pragma unroll
                for (int j = 0; j < 8; ++j)
                    acc[j] = fmaf(wt, bf2f(q[j]), acc[j]);
            }
        }
    }
}

__global__ __launch_bounds__(256) void gat_all(
    const int* __restrict__ ssrc, const int* __restrict__ offs,
    const float* __restrict__ WhP, float* __restrict__ outP,
    const float* __restrict__ WhA, float* __restrict__ outA,
    const float* __restrict__ ss_p2p, const float* __restrict__ sd_p2p, const u16* __restrict__ z_p2p,
    const float* __restrict__ ss_a2p, const float* __restrict__ sd_a2p, const u16* __restrict__ z_a2p,
    const float* __restrict__ ss_p2a, const float* __restrict__ sd_p2a, const u16* __restrict__ z_p2a,
    const float* __restrict__ ss_a2a, const float* __restrict__ sd_a2a, const u16* __restrict__ z_a2a) {
    int lane = threadIdx.x & 63;
    int g = (blockIdx.x * blockDim.x + threadIdx.x) >> 6;   // wave id = node id
    if (g >= NP + NA) return;                               // wave-uniform
    bool isP = g < NP;
    int d = isP ? g : g - NP;
    int bin0 = isP ? 2 * d : ABASE + 2 * d;
    int e0 = offs[bin0], e1 = offs[bin0 + 1], e2 = offs[bin0 + 2];
    float acc[8] = {0.f, 0.f, 0.f, 0.f, 0.f, 0.f, 0.f, 0.f};
    if (isP) {
        seg_gat_g8(ssrc, e0, e1, ss_p2p, sd_p2p[d], z_p2p, lane, acc);
        seg_gat_g8(ssrc, e1, e2, ss_a2p, sd_a2p[d], z_a2p, lane, acc);
    } else {
        seg_gat_g8(ssrc, e0, e1, ss_p2a, sd_p2a[d], z_p2a, lane, acc);
        seg_gat_g8(ssrc, e1, e2, ss_a2a, sd_a2a[d], z_a2a, lane, acc);
    }
    // lanes {l, l+8, .., l+56} hold identical column ranges -> 3-step reduce
#pragma unroll
    for (int o = 8; o <= 32; o <<= 1)
#pragma unroll
        for (int j = 0; j < 8; ++j)
            acc[j] += __shfl_xor(acc[j], o, 64);
    if (lane < 8) {
        const float* Wh = isP ? WhP : WhA;
        float* outp = isP ? outP : outA;
        const float* sp = &Wh[(long long)d * 64 + lane * 8];
        float4 s0v = *(const float4*)sp;
        float4 s1v = *(const float4*)(sp + 4);
        float4 r0, r1;
        r0.x = fmaxf(s0v.x + acc[0], 0.f); r0.y = fmaxf(s0v.y + acc[1], 0.f);
        r0.z = fmaxf(s0v.z + acc[2], 0.f); r0.w = fmaxf(s0v.w + acc[3], 0.f);
        r1.x = fmaxf(s1v.x + acc[4], 0.f); r1.y = fmaxf(s1v.y + acc[5], 0.f);
        r1.z = fmaxf(s1v.z + acc[6], 0.f); r1.w = fmaxf(s1v.w + acc[7], 0.f);
        float* op = &outp[(long long)d * 64 + lane * 8];
        *(float4*)op = r0;
        *(float4*)(op + 4) = r1;
    }
}

// ---------------- state path ----------------
__global__ void state_prep(const float* __restrict__ fS, const float* __restrict__ W_in,
                           const float* __restrict__ b_in, const float* __restrict__ a_p2s,
                           const float* __restrict__ a_a2s, float* __restrict__ outS,
                           float* __restrict__ sdst2) {
    int c = threadIdx.x;
    float acc = b_in[c];
    for (int k = 0; k < 64; ++k) acc = fmaf(fS[k], W_in[k * 64 + c], acc);
    outS[c] = acc;                         // Wh_in staged in outS
    float v0 = acc * a_p2s[64 + c];
    float v1 = acc * a_a2s[64 + c];
#pragma unroll
    for (int off = 32; off > 0; off >>= 1) {
        v0 += __shfl_down(v0, off, 64);
        v1 += __shfl_down(v1, off, 64);
    }
    if (c == 0) { sdst2[0] = v0; sdst2[1] = v1; }
}

#define SNB_P 128
#define SNB_A 64
// single-pass state GAT: per-block partial num/den -> atomics -> last block finalizes
__global__ __launch_bounds__(256) void state_all(
    const int* __restrict__ srcP, const float* __restrict__ ssP, const u16* __restrict__ zP, int EP,
    const int* __restrict__ srcA, const float* __restrict__ ssA, const u16* __restrict__ zA, int EA,
    const float* __restrict__ sdst2, float* __restrict__ numP, float* __restrict__ numA,
    float* __restrict__ den2, int* __restrict__ done, float* __restrict__ outS) {
    __shared__ float red[4][64];
    __shared__ float dred[4];
    __shared__ int tick;
    bool isP = (int)blockIdx.x < SNB_P;
    const int* src = isP ? srcP : srcA;
    const float* ss = isP ? ssP : ssA;
    const u16* z = isP ? zP : zA;
    int E = isP ? EP : EA;
    float sdst = sdst2[isP ? 0 : 1];
    float* num = isP ? numP : numA;
    int bid = isP ? blockIdx.x : blockIdx.x - SNB_P;
    int nb = isP ? SNB_P : SNB_A;
    int tid = threadIdx.x, lane = tid & 63, wv = tid >> 6;
    int egrp = lane >> 3, cg8 = (lane & 7) * 8;
    int gw = bid * 4 + wv;
    int waves = nb * 4;
    float acc[8] = {0,0,0,0,0,0,0,0};
    float dpart = 0.f;
    for (int base = gw * 8; base < E; base += waves * 8) {
        int i = base + egrp;
        float w = 0.f; int ri = 0;
        if (i < E) {
            ri = src[i];
            float e = ss[ri] + sdst;
            e = e > 0.f ? e : ALPHA * e;
            w = __expf(e);
        }
        dpart += w;                              // each edge counted by 8 lanes -> /8 later
        u16x8 q = *(const u16x8*)(z + (long long)ri * 64 + cg8);
#pragma unroll
        for (int j = 0; j < 8; ++j)
            acc[j] = fmaf(w, bf2f(q[j]), acc[j]);
    }
#pragma unroll
    for (int o = 8; o <= 32; o <<= 1)
#pragma unroll
        for (int j = 0; j < 8; ++j)
            acc[j] += __shfl_xor(acc[j], o, 64);
#pragma unroll
    for (int o = 32; o > 0; o >>= 1) dpart += __shfl_xor(dpart, o, 64);
    if (lane < 8)
#pragma unroll
        for (int j = 0; j < 8; ++j) red[wv][lane * 8 + j] = acc[j];
    if (lane == 0) dred[wv] = dpart;
    __syncthreads();
    if (tid < 64) {
        float t = red[0][tid] + red[1][tid] + red[2][tid] + red[3][tid];
        atomicAdd(&num[tid], t);
    }
    if (tid == 64) {
        float dtot = (dred[0] + dred[1] + dred[2] + dred[3]) * 0.125f;
        atomicAdd(&den2[isP ? 0 : 1], dtot);
    }
    __threadfence();
    __syncthreads();
    if (tid == 0) tick = atomicAdd(done, 1);
    __syncthreads();
    if (tick == SNB_P + SNB_A - 1 && tid < 64) {    // last block finalizes
        float dP = __hip_atomic_load(&den2[0], __ATOMIC_ACQUIRE, __HIP_MEMORY_SCOPE_AGENT);
        float dA = __hip_atomic_load(&den2[1], __ATOMIC_ACQUIRE, __HIP_MEMORY_SCOPE_AGENT);
        float nP = __hip_atomic_load(&numP[tid], __ATOMIC_ACQUIRE, __HIP_MEMORY_SCOPE_AGENT);
        float nA = __hip_atomic_load(&numA[tid], __ATOMIC_ACQUIRE, __HIP_MEMORY_SCOPE_AGENT);
        float whin = outS[tid];
        outS[tid] = fmaxf(whin + nP / dP + nA / dA, 0.f);
    }
}

extern "C" void kernel_launch(void* const* d_in, const int* in_sizes, int n_in,
                              void* d_out, int out_size, void* d_ws, size_t ws_size,
                              hipStream_t stream) {
    const float* feat_P = (const float*)d_in[0];
    const float* feat_A = (const float*)d_in[1];
    const float* feat_S = (const float*)d_in[2];
    const float* W_P   = (const float*)d_in[3];  const float* b_P   = (const float*)d_in[4];
    const float* W_A   = (const float*)d_in[5];  const float* b_A   = (const float*)d_in[6];
    const float* W_p2p = (const float*)d_in[7];  const float* b_p2p = (const float*)d_in[8];
    const float* W_p2a = (const float*)d_in[9];  const float* b_p2a = (const float*)d_in[10];
    const float* W_a2p = (const float*)d_in[11]; const float* b_a2p = (const float*)d_in[12];
    const float* W_a2a = (const float*)d_in[13]; const float* b_a2a = (const float*)d_in[14];
    const float* W_p2s = (const float*)d_in[15]; const float* b_p2s = (const float*)d_in[16];
    const float* W_a2s = (const float*)d_in[17]; const float* b_a2s = (const float*)d_in[18];
    const float* W_in  = (const float*)d_in[19]; const float* b_in  = (const float*)d_in[20];
    const float* a_p2p = (const float*)d_in[21];
    const float* a_p2a = (const float*)d_in[22];
    const float* a_a2p = (const float*)d_in[23];
    const float* a_a2a = (const float*)d_in[24];
    const float* a_p2s = (const float*)d_in[25];
    const float* a_a2s = (const float*)d_in[26];
    const int* src_p2p = (const int*)d_in[27]; const int* dst_p2p = (const int*)d_in[28];
    const int* src_p2a = (const int*)d_in[29]; const int* dst_p2a = (const int*)d_in[30];
    const int* src_a2p = (const int*)d_in[31]; const int* dst_a2p = (const int*)d_in[32];
    const int* src_a2a = (const int*)d_in[33]; const int* dst_a2a = (const int*)d_in[34];
    const int* src_p2s = (const int*)d_in[35];
    const int* src_a2s = (const int*)d_in[37];
    int E_p2p = in_sizes[27], E_p2a = in_sizes[29], E_a2p = in_sizes[31], E_a2a = in_sizes[33];
    int E_p2s = in_sizes[35], E_a2s = in_sizes[37];
    int E_tot = E_p2p + E_a2p + E_p2a + E_a2a;

    float* out = (float*)d_out;
    float* outP = out;
    float* outA = out + (long long)NP * 64;
    float* outS = out + (long long)(NP + NA) * 64;

    // ---- workspace layout ----
    float* ws = (float*)d_ws;
    float* WhP = ws; ws += (long long)NP * 64;
    float* WhA = ws; ws += (long long)NA * 64;
    u16* z_p2p = (u16*)ws; ws += (long long)NP * 32;
    u16* z_p2a = (u16*)ws; ws += (long long)NP * 32;
    u16* z_p2s = (u16*)ws; ws += (long long)NP * 32;
    u16* z_a2p = (u16*)ws; ws += (long long)NA * 32;
    u16* z_a2a = (u16*)ws; ws += (long long)NA * 32;
    u16* z_a2s = (u16*)ws; ws += (long long)NA * 32;
    float* ss_p2p = ws; ws += NP;  float* sd_p2p = ws; ws += NP;
    float* ss_p2a = ws; ws += NP;  float* sd_p2a = ws; ws += NA;
    float* ss_a2p = ws; ws += NA;  float* sd_a2p = ws; ws += NP;
    float* ss_a2a = ws; ws += NA;  float* sd_a2a = ws; ws += NA;
    float* ss_p2s = ws; ws += NP;
    float* ss_a2s = ws; ws += NA;
    float* sdst2  = ws; ws += 2;
    // ---- zeroed-every-call region (one memset) ----
    float* zreg   = ws;
    int*   bucktot = (int*)ws;  ws += NBUCK;
    float* den2   = ws; ws += 2;
    float* numP   = ws; ws += 64;
    float* numA   = ws; ws += 64;
    int*   done   = (int*)ws; ws += 1;
    size_t zbytes = (size_t)((char*)ws - (char*)zreg);
    // ---- rest ----
    int* iw = (int*)ws;
    int* starts  = iw; iw += NBUCK + 1;
    int* cursor  = iw; iw += NBUCK;
    int* ebuf    = iw; iw += E_tot;
    int* ssrc    = iw; iw += E_tot;
    int* offs    = iw; iw += NBINS + 1;

    const int T = 256;
    int nblk = (E_tot + CH - 1) / CH;

    hipMemsetAsync(zreg, 0, zbytes, stream);

    // ---- MFMA transforms + dots ----
    int gP = (NP + 63) / 64, gA = (NA + 63) / 64;
    xform4m<<<gP, T, 0, stream>>>(feat_P, NP,
        W_P, b_P, WhP, a_p2p + 64, sd_p2p, a_a2p + 64, sd_a2p,
        W_p2p, b_p2p, z_p2p, a_p2p, ss_p2p,
        W_p2a, b_p2a, z_p2a, a_p2a, ss_p2a,
        W_p2s, b_p2s, z_p2s, a_p2s, ss_p2s);
    xform4m<<<gA, T, 0, stream>>>(feat_A, NA,
        W_A, b_A, WhA, a_p2a + 64, sd_p2a, a_a2a + 64, sd_a2a,
        W_a2p, b_a2p, z_a2p, a_a2p, ss_a2p,
        W_a2a, b_a2a, z_a2a, a_a2a, ss_a2a,
        W_a2s, b_a2s, z_a2s, a_a2s, ss_a2s);
    state_prep<<<1, 64, 0, stream>>>(feat_S, W_in, b_in, a_p2s, a_a2s, outS, sdst2);

    // ---- bucket sort: count -> tiny scan -> windowed scatter -> fine sort ----
    bucket_count<<<nblk, T, 0, stream>>>(dst_p2p, E_p2p, dst_a2p, E_a2p,
                                         dst_p2a, E_p2a, dst_a2a, E_a2a, bucktot, E_tot);
    bucket_scan<<<1, 1024, 0, stream>>>(bucktot, starts, cursor, E_tot);
    passA_scatter<<<nblk, T, 0, stream>>>(src_p2p, dst_p2p, E_p2p,
                                          src_a2p, dst_a2p, E_a2p,
                                          src_p2a, dst_p2a, E_p2a,
                                          src_a2a, dst_a2a, E_a2a,
                                          cursor, E_tot, ebuf);
    fine_sort<<<NBUCK, T, 0, stream>>>(ebuf, starts, E_tot, ssrc, offs);

    // ---- per-node GAT + self + relu ----
    gat_all<<<((NP + NA) * 64 + T - 1) / T, T, 0, stream>>>(ssrc, offs,
        WhP, outP, WhA, outA,
        ss_p2p, sd_p2p, z_p2p, ss_a2p, sd_a2p, z_a2p,
        ss_p2a, sd_p2a, z_p2a, ss_a2a, sd_a2a, z_a2a);

    // ---- state GAT (single fused kernel) ----
    state_all<<<SNB_P + SNB_A, T, 0, stream>>>(src_p2s, ss_p2s, z_p2s, E_p2s,
                                               src_a2s, ss_a2s, z_a2s, E_a2s,
                                               sdst2, numP, numA, den2, done, outS);
}

// Round 8
// 195.739 us; speedup vs baseline: 5.2403x; 1.1785x over previous
//
#include <hip/hip_runtime.h>
#include <math.h>

#define ALPHA 0.2f
#define NP 50000
#define NA 25000
#define NBINS 150000          // P: 2*NP interleaved bins, then A: 2*NA
#define ABASE 100000          // bin base for A nodes
#define NBUCK 586             // ceil(NBINS/256)
#define CH 4096               // edges per scatter block (507 blocks: keep CUs busy)
#define NBC 512               // bucket_count grid
#define CAP 6144              // max edges per bucket in LDS (mean ~3.5k, max ~4.3k)

typedef unsigned short u16;
typedef __attribute__((ext_vector_type(8))) short bf16x8;
typedef __attribute__((ext_vector_type(8))) unsigned short u16x8;
typedef __attribute__((ext_vector_type(4))) float f32x4;

__device__ __forceinline__ float bf2f(u16 u) { return __uint_as_float(((unsigned)u) << 16); }
__device__ __forceinline__ u16 f2bf(float f) {
    unsigned x = __float_as_uint(f);
    return (u16)((x + 0x7fffu + ((x >> 16) & 1u)) >> 16);   // RNE
}

// ---------------- MFMA 4-matrix transform + attention dots ----------------
__global__ __launch_bounds__(256) void xform4m(
    const float* __restrict__ X, int N,
    const float* __restrict__ W0, const float* __restrict__ b0, float* __restrict__ Wh,
    const float* __restrict__ dA, float* __restrict__ sdA,
    const float* __restrict__ dB, float* __restrict__ sdB,
    const float* __restrict__ W1, const float* __restrict__ b1, u16* __restrict__ z1,
    const float* __restrict__ v1, float* __restrict__ s1,
    const float* __restrict__ W2, const float* __restrict__ b2, u16* __restrict__ z2,
    const float* __restrict__ v2, float* __restrict__ s2,
    const float* __restrict__ W3, const float* __restrict__ b3, u16* __restrict__ z3,
    const float* __restrict__ v3, float* __restrict__ s3)
{
    int tid = threadIdx.x, wv = tid >> 6, lane = tid & 63;
    int g = lane >> 4, li = lane & 15;
    const float* Wm = wv == 0 ? W0 : wv == 1 ? W1 : wv == 2 ? W2 : W3;
    const float* bm = wv == 0 ? b0 : wv == 1 ? b1 : wv == 2 ? b2 : b3;
    const float* dv = wv == 0 ? dA : wv == 1 ? v1 : wv == 2 ? v2 : v3;
    float* sm       = wv == 0 ? sdA : wv == 1 ? s1 : wv == 2 ? s2 : s3;
    u16* zm         = wv == 1 ? z1 : wv == 2 ? z2 : wv == 3 ? z3 : nullptr;

    bf16x8 Bf[4][2];
#pragma unroll
    for (int cb = 0; cb < 4; ++cb)
#pragma unroll
        for (int kc = 0; kc < 2; ++kc) {
            bf16x8 t;
#pragma unroll
            for (int j = 0; j < 8; ++j)
                t[j] = (short)f2bf(Wm[(kc * 32 + g * 8 + j) * 64 + cb * 16 + li]);
            Bf[cb][kc] = t;
        }
    float bl[4], dvl[4], dbl[4];
#pragma unroll
    for (int cb = 0; cb < 4; ++cb) {
        bl[cb]  = bm[cb * 16 + li];
        dvl[cb] = dv[cb * 16 + li];
        dbl[cb] = (wv == 0) ? dB[cb * 16 + li] : 0.f;
    }

    int base0 = blockIdx.x * 64;
#pragma unroll
    for (int rt = 0; rt < 4; ++rt) {
        int rbase = base0 + rt * 16;
        if (rbase >= N) break;
        int rowC = min(rbase + li, N - 1);
        bf16x8 Af[2];
#pragma unroll
        for (int kc = 0; kc < 2; ++kc) {
            const float* xp = X + (long long)rowC * 64 + kc * 32 + g * 8;
            float4 x0 = *(const float4*)xp;
            float4 x1 = *(const float4*)(xp + 4);
            bf16x8 t;
            t[0] = (short)f2bf(x0.x); t[1] = (short)f2bf(x0.y);
            t[2] = (short)f2bf(x0.z); t[3] = (short)f2bf(x0.w);
            t[4] = (short)f2bf(x1.x); t[5] = (short)f2bf(x1.y);
            t[6] = (short)f2bf(x1.z); t[7] = (short)f2bf(x1.w);
            Af[kc] = t;
        }
        f32x4 acc[4] = {{0,0,0,0},{0,0,0,0},{0,0,0,0},{0,0,0,0}};
#pragma unroll
        for (int kc = 0; kc < 2; ++kc)
#pragma unroll
            for (int cb = 0; cb < 4; ++cb)
                acc[cb] = __builtin_amdgcn_mfma_f32_16x16x32_bf16(Af[kc], Bf[cb][kc], acc[cb], 0, 0, 0);
        float pd[4] = {0,0,0,0}, pb[4] = {0,0,0,0};
#pragma unroll
        for (int cb = 0; cb < 4; ++cb)
#pragma unroll
            for (int r = 0; r < 4; ++r) {
                float val = acc[cb][r] + bl[cb];
                acc[cb][r] = val;
                pd[r] = fmaf(val, dvl[cb], pd[r]);
                pb[r] = fmaf(val, dbl[cb], pb[r]);
            }
#pragma unroll
        for (int o = 1; o < 16; o <<= 1)
#pragma unroll
            for (int r = 0; r < 4; ++r) {
                pd[r] += __shfl_xor(pd[r], o, 64);
                pb[r] += __shfl_xor(pb[r], o, 64);
            }
        int rg = rbase + g * 4;
        if (li == 0) {
#pragma unroll
            for (int r = 0; r < 4; ++r) {
                int row = rg + r;
                if (row < N) {
                    sm[row] = pd[r];
                    if (wv == 0) sdB[row] = pb[r];
                }
            }
        }
        if (wv == 0) {
#pragma unroll
            for (int r = 0; r < 4; ++r) {
                int row = rg + r;
                if (row < N)
#pragma unroll
                    for (int cb = 0; cb < 4; ++cb)
                        Wh[(long long)row * 64 + cb * 16 + li] = acc[cb][r];
            }
        } else {
#pragma unroll
            for (int r = 0; r < 4; ++r) {
                int row = rg + r;
                if (row < N)
#pragma unroll
                    for (int cb = 0; cb < 4; ++cb)
                        zm[(long long)row * 64 + cb * 16 + li] = f2bf(acc[cb][r]);
            }
        }
    }
}

// ---------------- edge decode helpers ----------------
__device__ __forceinline__ int edge_bin(int k,
    const int* __restrict__ d0, int E0, const int* __restrict__ d1, int E1,
    const int* __restrict__ d2, int E2, const int* __restrict__ d3) {
    if (k < E0) return 2 * d0[k];
    k -= E0; if (k < E1) return 2 * d1[k] + 1;
    k -= E1; if (k < E2) return ABASE + 2 * d2[k];
    k -= E2; return ABASE + 2 * d3[k] + 1;
}
__device__ __forceinline__ void edge_decode(int k,
    const int* __restrict__ s0, const int* __restrict__ d0, int E0,
    const int* __restrict__ s1, const int* __restrict__ d1, int E1,
    const int* __restrict__ s2, const int* __restrict__ d2, int E2,
    const int* __restrict__ s3, const int* __restrict__ d3,
    int& src, int& bin) {
    if (k < E0) { src = s0[k]; bin = 2 * d0[k]; return; }
    k -= E0; if (k < E1) { src = s1[k]; bin = 2 * d1[k] + 1; return; }
    k -= E1; if (k < E2) { src = s2[k]; bin = ABASE + 2 * d2[k]; return; }
    k -= E2; src = s3[k]; bin = ABASE + 2 * d3[k] + 1;
}

// ---------------- bucket totals (LDS hist -> global atomics), 512-block grid ----------------
__global__ __launch_bounds__(256) void bucket_count(
    const int* __restrict__ d0, int E0, const int* __restrict__ d1, int E1,
    const int* __restrict__ d2, int E2, const int* __restrict__ d3, int E3,
    int* __restrict__ bucktot, int Etot) {
    __shared__ int h[NBUCK];
    int tid = threadIdx.x;
    for (int i = tid; i < NBUCK; i += 256) h[i] = 0;
    __syncthreads();
    int stride = gridDim.x * 256;
    for (int i = blockIdx.x * 256 + tid; i < Etot; i += stride) {
        int bin = edge_bin(i, d0, E0, d1, E1, d2, E2, d3);
        atomicAdd(&h[bin >> 8], 1);
    }
    __syncthreads();
    for (int i = tid; i < NBUCK; i += 256)
        if (h[i]) atomicAdd(&bucktot[i], h[i]);
}

// ---------------- tiny single-block scan of 586 bucket totals ----------------
__global__ __launch_bounds__(1024) void bucket_scan(const int* __restrict__ bucktot,
                                                    int* __restrict__ starts,
                                                    int* __restrict__ cursor, int Etot) {
    __shared__ int wtot[16];
    int t = threadIdx.x, lane = t & 63, wv = t >> 6;
    int v = (t < NBUCK) ? bucktot[t] : 0;
    int x = v;
#pragma unroll
    for (int o = 1; o < 64; o <<= 1) {
        int y = __shfl_up(x, o, 64);
        if (lane >= o) x += y;
    }
    if (lane == 63) wtot[wv] = x;
    __syncthreads();
    int woff = 0;
    for (int j = 0; j < wv; ++j) woff += wtot[j];
    int excl = x + woff - v;
    if (t < NBUCK) { starts[t] = excl; cursor[t] = excl; }
    if (t == 0) starts[NBUCK] = Etot;
}

// ---------------- scatter: per-block window reservation + packed write ----------------
__global__ __launch_bounds__(256) void passA_scatter(
    const int* __restrict__ s0, const int* __restrict__ d0, int E0,
    const int* __restrict__ s1, const int* __restrict__ d1, int E1,
    const int* __restrict__ s2, const int* __restrict__ d2, int E2,
    const int* __restrict__ s3, const int* __restrict__ d3, int E3,
    int* __restrict__ cursor, int Etot, int* __restrict__ ebuf) {
    __shared__ int h[NBUCK];
    __shared__ int base[NBUCK];
    int tid = threadIdx.x;
    for (int i = tid; i < NBUCK; i += 256) h[i] = 0;
    __syncthreads();
    int b0 = blockIdx.x * CH;
    int b1 = min(b0 + CH, Etot);
    for (int i = b0 + tid; i < b1; i += 256) {
        int bin = edge_bin(i, d0, E0, d1, E1, d2, E2, d3);
        atomicAdd(&h[bin >> 8], 1);
    }
    __syncthreads();
    for (int i = tid; i < NBUCK; i += 256) {
        int c = h[i];
        base[i] = c ? atomicAdd(&cursor[i], c) : 0;
        h[i] = 0;                               // reuse as local cursor
    }
    __syncthreads();
    for (int i = b0 + tid; i < b1; i += 256) {
        int src, bin;
        edge_decode(i, s0, d0, E0, s1, d1, E1, s2, d2, E2, s3, d3, src, bin);
        int bk = bin >> 8;
        int pos = base[bk] + atomicAdd(&h[bk], 1);
        ebuf[pos] = src | ((bin & 255) << 16);
    }
}

// ---------------- fine sort: bucket -> fully dst-sorted ssrc + global offs ----------------
__global__ __launch_bounds__(256) void fine_sort(
    const int* __restrict__ ebuf, const int* __restrict__ starts, int Etot,
    int* __restrict__ ssrc, int* __restrict__ offs) {
    __shared__ int lsrc[CAP];
    __shared__ int lcnt[256];
    __shared__ int loff[256];
    __shared__ int lcur[256];
    __shared__ int wtot[4];
    int b = blockIdx.x;
    int tid = threadIdx.x, lane = tid & 63, wv = tid >> 6;
    int bstart = starts[b];
    int bend = starts[b + 1];
    int cnt = bend - bstart;
    lcnt[tid] = 0;
    __syncthreads();
    for (int e = bstart + tid; e < bend; e += 256)
        atomicAdd(&lcnt[((unsigned)ebuf[e]) >> 16], 1);
    __syncthreads();
    // wave-level exclusive scan over 256 bins
    int v = lcnt[tid];
    int x = v;
#pragma unroll
    for (int o = 1; o < 64; o <<= 1) {
        int y = __shfl_up(x, o, 64);
        if (lane >= o) x += y;
    }
    if (lane == 63) wtot[wv] = x;
    __syncthreads();
    int woff = 0;
    for (int j = 0; j < wv; ++j) woff += wtot[j];
    int excl = x + woff - v;
    loff[tid] = excl;
    lcur[tid] = excl;
    __syncthreads();
    if (cnt <= CAP) {
        for (int e = bstart + tid; e < bend; e += 256) {
            int val = ebuf[e];
            int pos = atomicAdd(&lcur[((unsigned)val) >> 16], 1);
            lsrc[pos] = val & 0xFFFF;
        }
        __syncthreads();
        for (int i = tid; i < cnt; i += 256) ssrc[bstart + i] = lsrc[i];   // coalesced
    } else {                                   // overflow fallback
        for (int e = bstart + tid; e < bend; e += 256) {
            int val = ebuf[e];
            int pos = atomicAdd(&lcur[((unsigned)val) >> 16], 1);
            ssrc[bstart + pos] = val & 0xFFFF;
        }
    }
    int gb = b * 256 + tid;
    if (gb < NBINS) offs[gb] = bstart + loff[tid];
    if (gb == 0) offs[NBINS] = Etot;
}

// ---------------- per-node GAT gather: 8 edges in flight, 16B z loads ----------------
__device__ __forceinline__ void seg_gat_g8(const int* __restrict__ ssrc, int s0, int s1,
                                           const float* __restrict__ ss, float sd,
                                           const u16* __restrict__ z, int lane,
                                           float* __restrict__ acc) {
    int cnt = s1 - s0;
    if (cnt <= 0) return;
    int egrp = lane >> 3, cg8 = (lane & 7) * 8;
    if (cnt <= 64) {                    // fast path (deg <= 64: essentially always)
        int s = 0; float w = 0.f;
        if (lane < cnt) {
            s = ssrc[s0 + lane];        // coalesced
            float e = ss[s] + sd;
            e = e > 0.f ? e : ALPHA * e;
            w = __expf(e);
        }
        float den = w;
#pragma unroll
        for (int o = 32; o > 0; o >>= 1) den += __shfl_xor(den, o, 64);
        w *= 1.f / den;
        int nit = (cnt + 7) >> 3;
        for (int it = 0; it < nit; ++it) {
            int ei = it * 8 + egrp;
            float wt = __shfl(w, ei, 64);   // 0 for ei >= cnt
            int   st = __shfl(s, ei, 64);
            u16x8 q = *(const u16x8*)(z + (long long)st * 64 + cg8);
#pragma unroll
            for (int j = 0; j < 8; ++j)
                acc[j] = fmaf(wt, bf2f(q[j]), acc[j]);
        }
    } else {                            // general path (rare)
        float den = 0.f;
        for (int i = s0 + lane; i < s1; i += 64) {
            float e = ss[ssrc[i]] + sd; e = e > 0.f ? e : ALPHA * e; den += __expf(e);
        }
#pragma unroll
        for (int o = 32; o > 0; o >>= 1) den += __shfl_xor(den, o, 64);
        float inv = 1.f / den;
        for (int c = s0; c < s1; c += 64) {
            int i = c + lane; int s = 0; float w = 0.f;
            if (i < s1) {
                s = ssrc[i];
                float e = ss[s] + sd; e = e > 0.f ? e : ALPHA * e;
                w = __expf(e) * inv;
            }
            int cc = min(64, s1 - c);
            int nit = (cc + 7) >> 3;
            for (int it = 0; it < nit; ++it) {
                int ei = it * 8 + egrp;
                float wt = __shfl(w, ei, 64);
                int   st = __shfl(s, ei, 64);
                u16x8 q = *(const u16x8*)(z + (long long)st * 64 + cg8);
#pragma unroll
                for (int j = 0; j < 8; ++j)
                    acc[j] = fmaf(wt, bf2f(q[j]), acc[j]);
            }
        }
    }
}

__global__ __launch_bounds__(256) void gat_all(
    const int* __restrict__ ssrc, const int* __restrict__ offs,
    const float* __restrict__ WhP, float* __restrict__ outP,
    const float* __restrict__ WhA, float* __restrict__ outA,
    const float* __restrict__ ss_p2p, const float* __restrict__ sd_p2p, const u16* __restrict__ z_p2p,
    const float* __restrict__ ss_a2p, const float* __restrict__ sd_a2p, const u16* __restrict__ z_a2p,
    const float* __restrict__ ss_p2a, const float* __restrict__ sd_p2a, const u16* __restrict__ z_p2a,
    const float* __restrict__ ss_a2a, const float* __restrict__ sd_a2a, const u16* __restrict__ z_a2a) {
    int lane = threadIdx.x & 63;
    int g = (blockIdx.x * blockDim.x + threadIdx.x) >> 6;   // wave id = node id
    if (g >= NP + NA) return;                               // wave-uniform
    bool isP = g < NP;
    int d = isP ? g : g - NP;
    int bin0 = isP ? 2 * d : ABASE + 2 * d;
    int e0 = offs[bin0], e1 = offs[bin0 + 1], e2 = offs[bin0 + 2];
    float acc[8] = {0.f, 0.f, 0.f, 0.f, 0.f, 0.f, 0.f, 0.f};
    if (isP) {
        seg_gat_g8(ssrc, e0, e1, ss_p2p, sd_p2p[d], z_p2p, lane, acc);
        seg_gat_g8(ssrc, e1, e2, ss_a2p, sd_a2p[d], z_a2p, lane, acc);
    } else {
        seg_gat_g8(ssrc, e0, e1, ss_p2a, sd_p2a[d], z_p2a, lane, acc);
        seg_gat_g8(ssrc, e1, e2, ss_a2a, sd_a2a[d], z_a2a, lane, acc);
    }
#pragma unroll
    for (int o = 8; o <= 32; o <<= 1)
#pragma unroll
        for (int j = 0; j < 8; ++j)
            acc[j] += __shfl_xor(acc[j], o, 64);
    if (lane < 8) {
        const float* Wh = isP ? WhP : WhA;
        float* outp = isP ? outP : outA;
        const float* sp = &Wh[(long long)d * 64 + lane * 8];
        float4 s0v = *(const float4*)sp;
        float4 s1v = *(const float4*)(sp + 4);
        float4 r0, r1;
        r0.x = fmaxf(s0v.x + acc[0], 0.f); r0.y = fmaxf(s0v.y + acc[1], 0.f);
        r0.z = fmaxf(s0v.z + acc[2], 0.f); r0.w = fmaxf(s0v.w + acc[3], 0.f);
        r1.x = fmaxf(s1v.x + acc[4], 0.f); r1.y = fmaxf(s1v.y + acc[5], 0.f);
        r1.z = fmaxf(s1v.z + acc[6], 0.f); r1.w = fmaxf(s1v.w + acc[7], 0.f);
        float* op = &outp[(long long)d * 64 + lane * 8];
        *(float4*)op = r0;
        *(float4*)(op + 4) = r1;
    }
}

// ---------------- state path ----------------
__global__ void state_prep(const float* __restrict__ fS, const float* __restrict__ W_in,
                           const float* __restrict__ b_in, const float* __restrict__ a_p2s,
                           const float* __restrict__ a_a2s, float* __restrict__ outS,
                           float* __restrict__ sdst2) {
    int c = threadIdx.x;
    float acc = b_in[c];
    for (int k = 0; k < 64; ++k) acc = fmaf(fS[k], W_in[k * 64 + c], acc);
    outS[c] = acc;                         // Wh_in staged in outS
    float v0 = acc * a_p2s[64 + c];
    float v1 = acc * a_a2s[64 + c];
#pragma unroll
    for (int off = 32; off > 0; off >>= 1) {
        v0 += __shfl_down(v0, off, 64);
        v1 += __shfl_down(v1, off, 64);
    }
    if (c == 0) { sdst2[0] = v0; sdst2[1] = v1; }
}

#define SNB_P 128
#define SNB_A 64
__global__ __launch_bounds__(256) void state_all(
    const int* __restrict__ srcP, const float* __restrict__ ssP, const u16* __restrict__ zP, int EP,
    const int* __restrict__ srcA, const float* __restrict__ ssA, const u16* __restrict__ zA, int EA,
    const float* __restrict__ sdst2, float* __restrict__ numP, float* __restrict__ numA,
    float* __restrict__ den2, int* __restrict__ done, float* __restrict__ outS) {
    __shared__ float red[4][64];
    __shared__ float dred[4];
    __shared__ int tick;
    bool isP = (int)blockIdx.x < SNB_P;
    const int* src = isP ? srcP : srcA;
    const float* ss = isP ? ssP : ssA;
    const u16* z = isP ? zP : zA;
    int E = isP ? EP : EA;
    float sdst = sdst2[isP ? 0 : 1];
    float* num = isP ? numP : numA;
    int bid = isP ? blockIdx.x : blockIdx.x - SNB_P;
    int nb = isP ? SNB_P : SNB_A;
    int tid = threadIdx.x, lane = tid & 63, wv = tid >> 6;
    int egrp = lane >> 3, cg8 = (lane & 7) * 8;
    int gw = bid * 4 + wv;
    int waves = nb * 4;
    float acc[8] = {0,0,0,0,0,0,0,0};
    float dpart = 0.f;
    for (int base = gw * 8; base < E; base += waves * 8) {
        int i = base + egrp;
        float w = 0.f; int ri = 0;
        if (i < E) {
            ri = src[i];
            float e = ss[ri] + sdst;
            e = e > 0.f ? e : ALPHA * e;
            w = __expf(e);
        }
        dpart += w;                              // each edge counted by 8 lanes -> /8 later
        u16x8 q = *(const u16x8*)(z + (long long)ri * 64 + cg8);
#pragma unroll
        for (int j = 0; j < 8; ++j)
            acc[j] = fmaf(w, bf2f(q[j]), acc[j]);
    }
#pragma unroll
    for (int o = 8; o <= 32; o <<= 1)
#pragma unroll
        for (int j = 0; j < 8; ++j)
            acc[j] += __shfl_xor(acc[j], o, 64);
#pragma unroll
    for (int o = 32; o > 0; o >>= 1) dpart += __shfl_xor(dpart, o, 64);
    if (lane < 8)
#pragma unroll
        for (int j = 0; j < 8; ++j) red[wv][lane * 8 + j] = acc[j];
    if (lane == 0) dred[wv] = dpart;
    __syncthreads();
    if (tid < 64) {
        float t = red[0][tid] + red[1][tid] + red[2][tid] + red[3][tid];
        atomicAdd(&num[tid], t);
    }
    if (tid == 64) {
        float dtot = (dred[0] + dred[1] + dred[2] + dred[3]) * 0.125f;
        atomicAdd(&den2[isP ? 0 : 1], dtot);
    }
    __threadfence();
    __syncthreads();
    if (tid == 0) tick = atomicAdd(done, 1);
    __syncthreads();
    if (tick == SNB_P + SNB_A - 1 && tid < 64) {    // last block finalizes
        float dP = __hip_atomic_load(&den2[0], __ATOMIC_ACQUIRE, __HIP_MEMORY_SCOPE_AGENT);
        float dA = __hip_atomic_load(&den2[1], __ATOMIC_ACQUIRE, __HIP_MEMORY_SCOPE_AGENT);
        float nP = __hip_atomic_load(&numP[tid], __ATOMIC_ACQUIRE, __HIP_MEMORY_SCOPE_AGENT);
        float nA = __hip_atomic_load(&numA[tid], __ATOMIC_ACQUIRE, __HIP_MEMORY_SCOPE_AGENT);
        float whin = outS[tid];
        outS[tid] = fmaxf(whin + nP / dP + nA / dA, 0.f);
    }
}

extern "C" void kernel_launch(void* const* d_in, const int* in_sizes, int n_in,
                              void* d_out, int out_size, void* d_ws, size_t ws_size,
                              hipStream_t stream) {
    const float* feat_P = (const float*)d_in[0];
    const float* feat_A = (const float*)d_in[1];
    const float* feat_S = (const float*)d_in[2];
    const float* W_P   = (const float*)d_in[3];  const float* b_P   = (const float*)d_in[4];
    const float* W_A   = (const float*)d_in[5];  const float* b_A   = (const float*)d_in[6];
    const float* W_p2p = (const float*)d_in[7];  const float* b_p2p = (const float*)d_in[8];
    const float* W_p2a = (const float*)d_in[9];  const float* b_p2a = (const float*)d_in[10];
    const float* W_a2p = (const float*)d_in[11]; const float* b_a2p = (const float*)d_in[12];
    const float* W_a2a = (const float*)d_in[13]; const float* b_a2a = (const float*)d_in[14];
    const float* W_p2s = (const float*)d_in[15]; const float* b_p2s = (const float*)d_in[16];
    const float* W_a2s = (const float*)d_in[17]; const float* b_a2s = (const float*)d_in[18];
    const float* W_in  = (const float*)d_in[19]; const float* b_in  = (const float*)d_in[20];
    const float* a_p2p = (const float*)d_in[21];
    const float* a_p2a = (const float*)d_in[22];
    const float* a_a2p = (const float*)d_in[23];
    const float* a_a2a = (const float*)d_in[24];
    const float* a_p2s = (const float*)d_in[25];
    const float* a_a2s = (const float*)d_in[26];
    const int* src_p2p = (const int*)d_in[27]; const int* dst_p2p = (const int*)d_in[28];
    const int* src_p2a = (const int*)d_in[29]; const int* dst_p2a = (const int*)d_in[30];
    const int* src_a2p = (const int*)d_in[31]; const int* dst_a2p = (const int*)d_in[32];
    const int* src_a2a = (const int*)d_in[33]; const int* dst_a2a = (const int*)d_in[34];
    const int* src_p2s = (const int*)d_in[35];
    const int* src_a2s = (const int*)d_in[37];
    int E_p2p = in_sizes[27], E_p2a = in_sizes[29], E_a2p = in_sizes[31], E_a2a = in_sizes[33];
    int E_p2s = in_sizes[35], E_a2s = in_sizes[37];
    int E_tot = E_p2p + E_a2p + E_p2a + E_a2a;

    float* out = (float*)d_out;
    float* outP = out;
    float* outA = out + (long long)NP * 64;
    float* outS = out + (long long)(NP + NA) * 64;

    // ---- workspace layout ----
    float* ws = (float*)d_ws;
    float* WhP = ws; ws += (long long)NP * 64;
    float* WhA = ws; ws += (long long)NA * 64;
    u16* z_p2p = (u16*)ws; ws += (long long)NP * 32;
    u16* z_p2a = (u16*)ws; ws += (long long)NP * 32;
    u16* z_p2s = (u16*)ws; ws += (long long)NP * 32;
    u16* z_a2p = (u16*)ws; ws += (long long)NA * 32;
    u16* z_a2a = (u16*)ws; ws += (long long)NA * 32;
    u16* z_a2s = (u16*)ws; ws += (long long)NA * 32;
    float* ss_p2p = ws; ws += NP;  float* sd_p2p = ws; ws += NP;
    float* ss_p2a = ws; ws += NP;  float* sd_p2a = ws; ws += NA;
    float* ss_a2p = ws; ws += NA;  float* sd_a2p = ws; ws += NP;
    float* ss_a2a = ws; ws += NA;  float* sd_a2a = ws; ws += NA;
    float* ss_p2s = ws; ws += NP;
    float* ss_a2s = ws; ws += NA;
    float* sdst2  = ws; ws += 2;
    // ---- zeroed-every-call region (one memset) ----
    float* zreg   = ws;
    int*   bucktot = (int*)ws;  ws += NBUCK;
    float* den2   = ws; ws += 2;
    float* numP   = ws; ws += 64;
    float* numA   = ws; ws += 64;
    int*   done   = (int*)ws; ws += 1;
    size_t zbytes = (size_t)((char*)ws - (char*)zreg);
    // ---- rest ----
    int* iw = (int*)ws;
    int* starts  = iw; iw += NBUCK + 1;
    int* cursor  = iw; iw += NBUCK;
    int* ebuf    = iw; iw += E_tot;
    int* ssrc    = iw; iw += E_tot;
    int* offs    = iw; iw += NBINS + 1;

    const int T = 256;
    int nblk = (E_tot + CH - 1) / CH;

    hipMemsetAsync(zreg, 0, zbytes, stream);

    // ---- MFMA transforms + dots ----
    int gP = (NP + 63) / 64, gA = (NA + 63) / 64;
    xform4m<<<gP, T, 0, stream>>>(feat_P, NP,
        W_P, b_P, WhP, a_p2p + 64, sd_p2p, a_a2p + 64, sd_a2p,
        W_p2p, b_p2p, z_p2p, a_p2p, ss_p2p,
        W_p2a, b_p2a, z_p2a, a_p2a, ss_p2a,
        W_p2s, b_p2s, z_p2s, a_p2s, ss_p2s);
    xform4m<<<gA, T, 0, stream>>>(feat_A, NA,
        W_A, b_A, WhA, a_p2a + 64, sd_p2a, a_a2a + 64, sd_a2a,
        W_a2p, b_a2p, z_a2p, a_a2p, ss_a2p,
        W_a2a, b_a2a, z_a2a, a_a2a, ss_a2a,
        W_a2s, b_a2s, z_a2s, a_a2s, ss_a2s);
    state_prep<<<1, 64, 0, stream>>>(feat_S, W_in, b_in, a_p2s, a_a2s, outS, sdst2);

    // ---- bucket sort: count -> tiny scan -> windowed scatter -> fine sort ----
    bucket_count<<<NBC, T, 0, stream>>>(dst_p2p, E_p2p, dst_a2p, E_a2p,
                                        dst_p2a, E_p2a, dst_a2a, E_a2a, bucktot, E_tot);
    bucket_scan<<<1, 1024, 0, stream>>>(bucktot, starts, cursor, E_tot);
    passA_scatter<<<nblk, T, 0, stream>>>(src_p2p, dst_p2p, E_p2p,
                                          src_a2p, dst_a2p, E_a2p,
                                          src_p2a, dst_p2a, E_p2a,
                                          src_a2a, dst_a2a, E_a2a,
                                          cursor, E_tot, ebuf);
    fine_sort<<<NBUCK, T, 0, stream>>>(ebuf, starts, E_tot, ssrc, offs);

    // ---- per-node GAT + self + relu ----
    gat_all<<<((NP + NA) * 64 + T - 1) / T, T, 0, stream>>>(ssrc, offs,
        WhP, outP, WhA, outA,
        ss_p2p, sd_p2p, z_p2p, ss_a2p, sd_a2p, z_a2p,
        ss_p2a, sd_p2a, z_p2a, ss_a2a, sd_a2a, z_a2a);

    // ---- state GAT (single fused kernel) ----
    state_all<<<SNB_P + SNB_A, T, 0, stream>>>(src_p2s, ss_p2s, z_p2s, E_p2s,
                                               src_a2s, ss_a2s, z_a2s, E_a2s,
                                               sdst2, numP, numA, den2, done, outS);
}

// Round 9
// 162.768 us; speedup vs baseline: 6.3018x; 1.2026x over previous
//
#include <hip/hip_runtime.h>
#include <math.h>

#define ALPHA 0.2f
#define NP 50000
#define NA 25000
#define NBINS 150000          // P: 2*NP interleaved bins, then A: 2*NA
#define ABASE 100000          // bin base for A nodes
#define NBUCK 586             // ceil(NBINS/256)
#define CH 4096               // edges per scatter block (= 16*256, static unroll)
#define NBC 512               // bucket_count role blocks
#define CAP 6144              // max edges per bucket in LDS (mean ~3.5k, max ~4.3k)
#define GP ((NP + 63) / 64)   // 782 xform-P blocks
#define GA ((NA + 63) / 64)   // 391 xform-A blocks
#define GATB ((NP + NA) / 4)  // 18750 gat blocks (divides exactly)
#define SNB_P 128
#define SNB_A 64

typedef unsigned short u16;
typedef __attribute__((ext_vector_type(8))) short bf16x8;
typedef __attribute__((ext_vector_type(8))) unsigned short u16x8;
typedef __attribute__((ext_vector_type(4))) float f32x4;

__device__ __forceinline__ float bf2f(u16 u) { return __uint_as_float(((unsigned)u) << 16); }
__device__ __forceinline__ u16 f2bf(float f) {
    unsigned x = __float_as_uint(f);
    return (u16)((x + 0x7fffu + ((x >> 16) & 1u)) >> 16);   // RNE
}

// =============== args ===============
struct FrontArgs {
    const float *feat_P, *feat_A, *feat_S;
    const float *W_P, *b_P, *W_A, *b_A, *W_p2p, *b_p2p, *W_p2a, *b_p2a,
                *W_a2p, *b_a2p, *W_a2a, *b_a2a, *W_p2s, *b_p2s, *W_a2s, *b_a2s,
                *W_in, *b_in;
    const float *a_p2p, *a_p2a, *a_a2p, *a_a2a, *a_p2s, *a_a2s;
    float *WhP, *WhA;
    u16 *z_p2p, *z_p2a, *z_p2s, *z_a2p, *z_a2a, *z_a2s;
    float *ss_p2p, *sd_p2p, *ss_p2a, *sd_p2a, *ss_a2p, *sd_a2p, *ss_a2a, *sd_a2a,
          *ss_p2s, *ss_a2s;
    float *sdst2, *outS, *den2, *numP, *numA;
    int *done;
    const int *dst_p2p, *dst_a2p, *dst_p2a, *dst_a2a;
    int E_p2p, E_a2p, E_p2a, E_a2a, E_tot;
    int *bucktot;
};

// =============== MFMA 4-matrix transform body (per node type) ===============
__device__ __forceinline__ void xform_body(int bid,
    const float* __restrict__ X, int N,
    const float* __restrict__ W0, const float* __restrict__ b0, float* __restrict__ Wh,
    const float* __restrict__ dA, float* __restrict__ sdA,
    const float* __restrict__ dB, float* __restrict__ sdB,
    const float* __restrict__ W1, const float* __restrict__ b1, u16* __restrict__ z1,
    const float* __restrict__ v1, float* __restrict__ s1,
    const float* __restrict__ W2, const float* __restrict__ b2, u16* __restrict__ z2,
    const float* __restrict__ v2, float* __restrict__ s2,
    const float* __restrict__ W3, const float* __restrict__ b3, u16* __restrict__ z3,
    const float* __restrict__ v3, float* __restrict__ s3)
{
    int tid = threadIdx.x, wv = tid >> 6, lane = tid & 63;
    int g = lane >> 4, li = lane & 15;
    const float* Wm = wv == 0 ? W0 : wv == 1 ? W1 : wv == 2 ? W2 : W3;
    const float* bm = wv == 0 ? b0 : wv == 1 ? b1 : wv == 2 ? b2 : b3;
    const float* dv = wv == 0 ? dA : wv == 1 ? v1 : wv == 2 ? v2 : v3;
    float* sm       = wv == 0 ? sdA : wv == 1 ? s1 : wv == 2 ? s2 : s3;
    u16* zm         = wv == 1 ? z1 : wv == 2 ? z2 : wv == 3 ? z3 : nullptr;

    bf16x8 Bf[4][2];
#pragma unroll
    for (int cb = 0; cb < 4; ++cb)
#pragma unroll
        for (int kc = 0; kc < 2; ++kc) {
            bf16x8 t;
#pragma unroll
            for (int j = 0; j < 8; ++j)
                t[j] = (short)f2bf(Wm[(kc * 32 + g * 8 + j) * 64 + cb * 16 + li]);
            Bf[cb][kc] = t;
        }
    float bl[4], dvl[4], dbl[4];
#pragma unroll
    for (int cb = 0; cb < 4; ++cb) {
        bl[cb]  = bm[cb * 16 + li];
        dvl[cb] = dv[cb * 16 + li];
        dbl[cb] = (wv == 0) ? dB[cb * 16 + li] : 0.f;
    }

    int base0 = bid * 64;
#pragma unroll
    for (int rt = 0; rt < 4; ++rt) {
        int rbase = base0 + rt * 16;
        if (rbase >= N) break;
        int rowC = min(rbase + li, N - 1);
        bf16x8 Af[2];
#pragma unroll
        for (int kc = 0; kc < 2; ++kc) {
            const float* xp = X + (long long)rowC * 64 + kc * 32 + g * 8;
            float4 x0 = *(const float4*)xp;
            float4 x1 = *(const float4*)(xp + 4);
            bf16x8 t;
            t[0] = (short)f2bf(x0.x); t[1] = (short)f2bf(x0.y);
            t[2] = (short)f2bf(x0.z); t[3] = (short)f2bf(x0.w);
            t[4] = (short)f2bf(x1.x); t[5] = (short)f2bf(x1.y);
            t[6] = (short)f2bf(x1.z); t[7] = (short)f2bf(x1.w);
            Af[kc] = t;
        }
        f32x4 acc[4] = {{0,0,0,0},{0,0,0,0},{0,0,0,0},{0,0,0,0}};
#pragma unroll
        for (int kc = 0; kc < 2; ++kc)
#pragma unroll
            for (int cb = 0; cb < 4; ++cb)
                acc[cb] = __builtin_amdgcn_mfma_f32_16x16x32_bf16(Af[kc], Bf[cb][kc], acc[cb], 0, 0, 0);
        float pd[4] = {0,0,0,0}, pb[4] = {0,0,0,0};
#pragma unroll
        for (int cb = 0; cb < 4; ++cb)
#pragma unroll
            for (int r = 0; r < 4; ++r) {
                float val = acc[cb][r] + bl[cb];
                acc[cb][r] = val;
                pd[r] = fmaf(val, dvl[cb], pd[r]);
                pb[r] = fmaf(val, dbl[cb], pb[r]);
            }
#pragma unroll
        for (int o = 1; o < 16; o <<= 1)
#pragma unroll
            for (int r = 0; r < 4; ++r) {
                pd[r] += __shfl_xor(pd[r], o, 64);
                pb[r] += __shfl_xor(pb[r], o, 64);
            }
        int rg = rbase + g * 4;
        if (li == 0) {
#pragma unroll
            for (int r = 0; r < 4; ++r) {
                int row = rg + r;
                if (row < N) {
                    sm[row] = pd[r];
                    if (wv == 0) sdB[row] = pb[r];
                }
            }
        }
        if (wv == 0) {
#pragma unroll
            for (int r = 0; r < 4; ++r) {
                int row = rg + r;
                if (row < N)
#pragma unroll
                    for (int cb = 0; cb < 4; ++cb)
                        Wh[(long long)row * 64 + cb * 16 + li] = acc[cb][r];
            }
        } else {
#pragma unroll
            for (int r = 0; r < 4; ++r) {
                int row = rg + r;
                if (row < N)
#pragma unroll
                    for (int cb = 0; cb < 4; ++cb)
                        zm[(long long)row * 64 + cb * 16 + li] = f2bf(acc[cb][r]);
            }
        }
    }
}

// =============== edge decode ===============
__device__ __forceinline__ int edge_bin(int k,
    const int* __restrict__ d0, int E0, const int* __restrict__ d1, int E1,
    const int* __restrict__ d2, int E2, const int* __restrict__ d3) {
    if (k < E0) return 2 * d0[k];
    k -= E0; if (k < E1) return 2 * d1[k] + 1;
    k -= E1; if (k < E2) return ABASE + 2 * d2[k];
    k -= E2; return ABASE + 2 * d3[k] + 1;
}
__device__ __forceinline__ void edge_decode(int k,
    const int* __restrict__ s0, const int* __restrict__ d0, int E0,
    const int* __restrict__ s1, const int* __restrict__ d1, int E1,
    const int* __restrict__ s2, const int* __restrict__ d2, int E2,
    const int* __restrict__ s3, const int* __restrict__ d3,
    int& src, int& bin) {
    if (k < E0) { src = s0[k]; bin = 2 * d0[k]; return; }
    k -= E0; if (k < E1) { src = s1[k]; bin = 2 * d1[k] + 1; return; }
    k -= E1; if (k < E2) { src = s2[k]; bin = ABASE + 2 * d2[k]; return; }
    k -= E2; src = s3[k]; bin = ABASE + 2 * d3[k] + 1;
}

// =============== fused front: bucket_count | xform P | xform A | state_prep ===============
__global__ __launch_bounds__(256) void fused_front(FrontArgs A) {
    int bid = blockIdx.x;
    int tid = threadIdx.x;
    if (bid < NBC) {
        // ---- bucket_count role ----
        __shared__ int h[NBUCK];
        for (int i = tid; i < NBUCK; i += 256) h[i] = 0;
        __syncthreads();
        int stride = NBC * 256;
        for (int i = bid * 256 + tid; i < A.E_tot; i += stride) {
            int bin = edge_bin(i, A.dst_p2p, A.E_p2p, A.dst_a2p, A.E_a2p,
                               A.dst_p2a, A.E_p2a, A.dst_a2a);
            atomicAdd(&h[bin >> 8], 1);
        }
        __syncthreads();
        for (int i = tid; i < NBUCK; i += 256)
            if (h[i]) atomicAdd(&A.bucktot[i], h[i]);
        return;
    }
    bid -= NBC;
    if (bid < GP) {
        xform_body(bid, A.feat_P, NP,
                   A.W_P, A.b_P, A.WhP, A.a_p2p + 64, A.sd_p2p, A.a_a2p + 64, A.sd_a2p,
                   A.W_p2p, A.b_p2p, A.z_p2p, A.a_p2p, A.ss_p2p,
                   A.W_p2a, A.b_p2a, A.z_p2a, A.a_p2a, A.ss_p2a,
                   A.W_p2s, A.b_p2s, A.z_p2s, A.a_p2s, A.ss_p2s);
        return;
    }
    bid -= GP;
    if (bid < GA) {
        xform_body(bid, A.feat_A, NA,
                   A.W_A, A.b_A, A.WhA, A.a_p2a + 64, A.sd_p2a, A.a_a2a + 64, A.sd_a2a,
                   A.W_a2p, A.b_a2p, A.z_a2p, A.a_a2p, A.ss_a2p,
                   A.W_a2a, A.b_a2a, A.z_a2a, A.a_a2a, A.ss_a2a,
                   A.W_a2s, A.b_a2s, A.z_a2s, A.a_a2s, A.ss_a2s);
        return;
    }
    // ---- state_prep role (last block) + zero den/num/done ----
    if (tid < 64) {
        int c = tid;
        float acc = A.b_in[c];
        for (int k = 0; k < 64; ++k) acc = fmaf(A.feat_S[k], A.W_in[k * 64 + c], acc);
        A.outS[c] = acc;                       // Wh_in staged in outS
        float v0 = acc * A.a_p2s[64 + c];
        float v1 = acc * A.a_a2s[64 + c];
#pragma unroll
        for (int off = 32; off > 0; off >>= 1) {
            v0 += __shfl_down(v0, off, 64);
            v1 += __shfl_down(v1, off, 64);
        }
        if (c == 0) { A.sdst2[0] = v0; A.sdst2[1] = v1; }
    } else if (tid < 128) A.numP[tid - 64] = 0.f;
    else if (tid < 192)   A.numA[tid - 128] = 0.f;
    else if (tid == 192)  A.den2[0] = 0.f;
    else if (tid == 193)  A.den2[1] = 0.f;
    else if (tid == 194)  *A.done = 0;
}

// =============== in-block exclusive scan of 586 bucket totals ===============
__device__ void scan_buckets(const int* __restrict__ bucktot, int* sstart, int Etot) {
    __shared__ int wtot_sb[4];
    int tid = threadIdx.x, lane = tid & 63, wv = tid >> 6;
    int carry = 0;
    for (int c = 0; c < 3; ++c) {
        int i = c * 256 + tid;
        int v = (i < NBUCK) ? bucktot[i] : 0;
        int x = v;
#pragma unroll
        for (int o = 1; o < 64; o <<= 1) {
            int y = __shfl_up(x, o, 64);
            if (lane >= o) x += y;
        }
        if (lane == 63) wtot_sb[wv] = x;
        __syncthreads();
        int woff = carry;
        for (int j = 0; j < wv; ++j) woff += wtot_sb[j];
        int ctot = wtot_sb[0] + wtot_sb[1] + wtot_sb[2] + wtot_sb[3];
        if (i < NBUCK) sstart[i] = x + woff - v;
        __syncthreads();
        carry += ctot;
    }
    if (tid == 0) sstart[NBUCK] = Etot;
    __syncthreads();
}

// =============== scatter: local scan + window reservation + packed write ===============
__global__ __launch_bounds__(256) void passA_scatter(
    const int* __restrict__ s0, const int* __restrict__ d0, int E0,
    const int* __restrict__ s1, const int* __restrict__ d1, int E1,
    const int* __restrict__ s2, const int* __restrict__ d2, int E2,
    const int* __restrict__ s3, const int* __restrict__ d3, int E3,
    const int* __restrict__ bucktot, int* __restrict__ cursor0,
    int Etot, int* __restrict__ ebuf) {
    __shared__ int sstart[NBUCK + 1];
    __shared__ int h[NBUCK];
    __shared__ int base[NBUCK];
    int tid = threadIdx.x;
    scan_buckets(bucktot, sstart, Etot);
    for (int i = tid; i < NBUCK; i += 256) h[i] = 0;
    __syncthreads();
    int b0 = blockIdx.x * CH;
    int b1 = min(b0 + CH, Etot);
    int cbin[16], csrc[16];
#pragma unroll
    for (int it = 0; it < 16; ++it) {
        int i = b0 + it * 256 + tid;
        int bin = -1, src = 0;
        if (i < b1)
            edge_decode(i, s0, d0, E0, s1, d1, E1, s2, d2, E2, s3, d3, src, bin);
        cbin[it] = bin; csrc[it] = src;
        if (bin >= 0) atomicAdd(&h[bin >> 8], 1);
    }
    __syncthreads();
    for (int i = tid; i < NBUCK; i += 256) {
        int c = h[i];
        base[i] = c ? (sstart[i] + atomicAdd(&cursor0[i], c)) : 0;
        h[i] = 0;                               // reuse as local cursor
    }
    __syncthreads();
#pragma unroll
    for (int it = 0; it < 16; ++it) {
        int bin = cbin[it];
        if (bin >= 0) {
            int bk = bin >> 8;
            int pos = base[bk] + atomicAdd(&h[bk], 1);
            ebuf[pos] = csrc[it] | ((bin & 255) << 16);
        }
    }
}

// =============== fine sort: bucket -> fully dst-sorted ssrc + global offs ===============
__global__ __launch_bounds__(256) void fine_sort(
    const int* __restrict__ ebuf, const int* __restrict__ bucktot, int Etot,
    int* __restrict__ ssrc, int* __restrict__ offs) {
    __shared__ int sstart[NBUCK + 1];
    __shared__ int lsrc[CAP];
    __shared__ int lcnt[256];
    __shared__ int loff[256];
    __shared__ int lcur[256];
    __shared__ int wtot[4];
    int b = blockIdx.x;
    int tid = threadIdx.x, lane = tid & 63, wv = tid >> 6;
    scan_buckets(bucktot, sstart, Etot);
    int bstart = sstart[b];
    int bend = sstart[b + 1];
    int cnt = bend - bstart;
    lcnt[tid] = 0;
    __syncthreads();
    for (int e = bstart + tid; e < bend; e += 256)
        atomicAdd(&lcnt[((unsigned)ebuf[e]) >> 16], 1);
    __syncthreads();
    int v = lcnt[tid];
    int x = v;
#pragma unroll
    for (int o = 1; o < 64; o <<= 1) {
        int y = __shfl_up(x, o, 64);
        if (lane >= o) x += y;
    }
    if (lane == 63) wtot[wv] = x;
    __syncthreads();
    int woff = 0;
    for (int j = 0; j < wv; ++j) woff += wtot[j];
    int excl = x + woff - v;
    loff[tid] = excl;
    lcur[tid] = excl;
    __syncthreads();
    if (cnt <= CAP) {
        for (int e = bstart + tid; e < bend; e += 256) {
            int val = ebuf[e];
            int pos = atomicAdd(&lcur[((unsigned)val) >> 16], 1);
            lsrc[pos] = val & 0xFFFF;
        }
        __syncthreads();
        for (int i = tid; i < cnt; i += 256) ssrc[bstart + i] = lsrc[i];   // coalesced
    } else {                                   // overflow fallback
        for (int e = bstart + tid; e < bend; e += 256) {
            int val = ebuf[e];
            int pos = atomicAdd(&lcur[((unsigned)val) >> 16], 1);
            ssrc[bstart + pos] = val & 0xFFFF;
        }
    }
    int gb = b * 256 + tid;
    if (gb < NBINS) offs[gb] = bstart + loff[tid];
    if (gb == 0) offs[NBINS] = Etot;
}

// =============== general-path per-segment gather (rare, deg_total > 64) ===============
__device__ __forceinline__ void seg_gat_g8(const int* __restrict__ ssrc, int s0, int s1,
                                           const float* __restrict__ ss, float sd,
                                           const u16* __restrict__ z, int lane,
                                           float* __restrict__ acc) {
    int cnt = s1 - s0;
    if (cnt <= 0) return;
    int egrp = lane >> 3, cg8 = (lane & 7) * 8;
    float den = 0.f;
    for (int i = s0 + lane; i < s1; i += 64) {
        float e = ss[ssrc[i]] + sd; e = e > 0.f ? e : ALPHA * e; den += __expf(e);
    }
#pragma unroll
    for (int o = 32; o > 0; o >>= 1) den += __shfl_xor(den, o, 64);
    float inv = 1.f / den;
    for (int c = s0; c < s1; c += 64) {
        int i = c + lane; int s = 0; float w = 0.f;
        if (i < s1) {
            s = ssrc[i];
            float e = ss[s] + sd; e = e > 0.f ? e : ALPHA * e;
            w = __expf(e) * inv;
        }
        int cc = min(64, s1 - c);
        int nit = (cc + 7) >> 3;
        for (int it = 0; it < nit; ++it) {
            int ei = it * 8 + egrp;
            float wt = __shfl(w, ei, 64);
            int   st = __shfl(s, ei, 64);
            u16x8 q = *(const u16x8*)(z + (long long)st * 64 + cg8);
#pragma unroll
            for (int j = 0; j < 8; ++j)
                acc[j] = fmaf(wt, bf2f(q[j]), acc[j]);
        }
    }
}

// =============== fused back: gat (merged segments) | state_all ===============
__global__ __launch_bounds__(256) void fused_back(
    const int* __restrict__ ssrc, const int* __restrict__ offs,
    const float* __restrict__ WhP, float* __restrict__ outP,
    const float* __restrict__ WhA, float* __restrict__ outA,
    const float* __restrict__ ss_p2p, const float* __restrict__ sd_p2p, const u16* __restrict__ z_p2p,
    const float* __restrict__ ss_a2p, const float* __restrict__ sd_a2p, const u16* __restrict__ z_a2p,
    const float* __restrict__ ss_p2a, const float* __restrict__ sd_p2a, const u16* __restrict__ z_p2a,
    const float* __restrict__ ss_a2a, const float* __restrict__ sd_a2a, const u16* __restrict__ z_a2a,
    const int* __restrict__ srcP, const float* __restrict__ ssP, const u16* __restrict__ zP, int EP,
    const int* __restrict__ srcA, const float* __restrict__ ssA, const u16* __restrict__ zA, int EA,
    const float* __restrict__ sdst2, float* __restrict__ numP, float* __restrict__ numA,
    float* __restrict__ den2, int* __restrict__ done, float* __restrict__ outS) {
    int tid = threadIdx.x, lane = tid & 63, wv = tid >> 6;
    if ((int)blockIdx.x < GATB) {
        // ---- gat role: wave per node, merged two-segment fast path ----
        int g = blockIdx.x * 4 + wv;
        bool isP = g < NP;
        int d = isP ? g : g - NP;
        int bin0 = isP ? 2 * d : ABASE + 2 * d;
        int e0 = offs[bin0], e1 = offs[bin0 + 1], e2 = offs[bin0 + 2];
        int cnt = e2 - e0, c1 = e1 - e0;
        const float* ss0 = isP ? ss_p2p : ss_p2a;
        const float* ss1 = isP ? ss_a2p : ss_a2a;
        const u16* z0 = isP ? z_p2p : z_p2a;
        const u16* z1 = isP ? z_a2p : z_a2a;
        float sd0v = (isP ? sd_p2p : sd_p2a)[d];
        float sd1v = (isP ? sd_a2p : sd_a2a)[d];
        int egrp = lane >> 3, cg8 = (lane & 7) * 8;
        float acc[8] = {0.f, 0.f, 0.f, 0.f, 0.f, 0.f, 0.f, 0.f};
        if (cnt <= 64) {                       // fast path (deg_tot <= 64: ~always)
            int s = 0; float w = 0.f;
            bool s1f = lane >= c1;
            if (lane < cnt) {
                s = ssrc[e0 + lane];           // coalesced
                float sc = (s1f ? ss1[s] : ss0[s]) + (s1f ? sd1v : sd0v);
                sc = sc > 0.f ? sc : ALPHA * sc;
                w = __expf(sc);
            }
            float d0 = s1f ? 0.f : w, d1 = s1f ? w : 0.f;
#pragma unroll
            for (int o = 32; o > 0; o >>= 1) {
                d0 += __shfl_xor(d0, o, 64);
                d1 += __shfl_xor(d1, o, 64);
            }
            float inv0 = 1.f / d0, inv1 = 1.f / d1;
            w = (lane < cnt) ? w * (s1f ? inv1 : inv0) : 0.f;   // stays exactly 0 for pad lanes
            int nit = (cnt + 7) >> 3;
            for (int it = 0; it < nit; ++it) {
                int ei = it * 8 + egrp;
                float wt = __shfl(w, ei, 64);
                int   st = __shfl(s, ei, 64);
                const u16* zp = (ei >= c1) ? z1 : z0;
                u16x8 q = *(const u16x8*)(zp + (long long)st * 64 + cg8);
#pragma unroll
                for (int j = 0; j < 8; ++j)
                    acc[j] = fmaf(wt, bf2f(q[j]), acc[j]);
            }
        } else {                               // general path (rare)
            seg_gat_g8(ssrc, e0, e1, ss0, sd0v, z0, lane, acc);
            seg_gat_g8(ssrc, e1, e2, ss1, sd1v, z1, lane, acc);
        }
#pragma unroll
        for (int o = 8; o <= 32; o <<= 1)
#pragma unroll
            for (int j = 0; j < 8; ++j)
                acc[j] += __shfl_xor(acc[j], o, 64);
        if (lane < 8) {
            const float* Wh = isP ? WhP : WhA;
            float* outp = isP ? outP : outA;
            const float* sp = &Wh[(long long)d * 64 + lane * 8];
            float4 s0v = *(const float4*)sp;
            float4 s1v = *(const float4*)(sp + 4);
            float4 r0, r1;
            r0.x = fmaxf(s0v.x + acc[0], 0.f); r0.y = fmaxf(s0v.y + acc[1], 0.f);
            r0.z = fmaxf(s0v.z + acc[2], 0.f); r0.w = fmaxf(s0v.w + acc[3], 0.f);
            r1.x = fmaxf(s1v.x + acc[4], 0.f); r1.y = fmaxf(s1v.y + acc[5], 0.f);
            r1.z = fmaxf(s1v.z + acc[6], 0.f); r1.w = fmaxf(s1v.w + acc[7], 0.f);
            float* op = &outp[(long long)d * 64 + lane * 8];
            *(float4*)op = r0;
            *(float4*)(op + 4) = r1;
        }
        return;
    }
    // ---- state role ----
    __shared__ float red[4][64];
    __shared__ float dred[4];
    __shared__ int tick;
    int sb = blockIdx.x - GATB;
    bool isP = sb < SNB_P;
    const int* src = isP ? srcP : srcA;
    const float* ss = isP ? ssP : ssA;
    const u16* z = isP ? zP : zA;
    int E = isP ? EP : EA;
    float sdst = sdst2[isP ? 0 : 1];
    float* num = isP ? numP : numA;
    int bidl = isP ? sb : sb - SNB_P;
    int nb = isP ? SNB_P : SNB_A;
    int egrp = lane >> 3, cg8 = (lane & 7) * 8;
    int gw = bidl * 4 + wv;
    int waves = nb * 4;
    float acc[8] = {0,0,0,0,0,0,0,0};
    float dpart = 0.f;
    for (int base = gw * 8; base < E; base += waves * 8) {
        int i = base + egrp;
        float w = 0.f; int ri = 0;
        if (i < E) {
            ri = src[i];
            float e = ss[ri] + sdst;
            e = e > 0.f ? e : ALPHA * e;
            w = __expf(e);
        }
        dpart += w;                            // each edge counted by 8 lanes -> /8 later
        u16x8 q = *(const u16x8*)(z + (long long)ri * 64 + cg8);
#pragma unroll
        for (int j = 0; j < 8; ++j)
            acc[j] = fmaf(w, bf2f(q[j]), acc[j]);
    }
#pragma unroll
    for (int o = 8; o <= 32; o <<= 1)
#pragma unroll
        for (int j = 0; j < 8; ++j)
            acc[j] += __shfl_xor(acc[j], o, 64);
#pragma unroll
    for (int o = 32; o > 0; o >>= 1) dpart += __shfl_xor(dpart, o, 64);
    if (lane < 8)
#pragma unroll
        for (int j = 0; j < 8; ++j) red[wv][lane * 8 + j] = acc[j];
    if (lane == 0) dred[wv] = dpart;
    __syncthreads();
    if (tid < 64) {
        float t = red[0][tid] + red[1][tid] + red[2][tid] + red[3][tid];
        atomicAdd(&num[tid], t);
    }
    if (tid == 64) {
        float dtot = (dred[0] + dred[1] + dred[2] + dred[3]) * 0.125f;
        atomicAdd(&den2[isP ? 0 : 1], dtot);
    }
    __threadfence();
    __syncthreads();
    if (tid == 0) tick = atomicAdd(done, 1);
    __syncthreads();
    if (tick == SNB_P + SNB_A - 1 && tid < 64) {   // last state block finalizes
        float dP = __hip_atomic_load(&den2[0], __ATOMIC_ACQUIRE, __HIP_MEMORY_SCOPE_AGENT);
        float dA = __hip_atomic_load(&den2[1], __ATOMIC_ACQUIRE, __HIP_MEMORY_SCOPE_AGENT);
        float nP = __hip_atomic_load(&numP[tid], __ATOMIC_ACQUIRE, __HIP_MEMORY_SCOPE_AGENT);
        float nA = __hip_atomic_load(&numA[tid], __ATOMIC_ACQUIRE, __HIP_MEMORY_SCOPE_AGENT);
        float whin = outS[tid];
        outS[tid] = fmaxf(whin + nP / dP + nA / dA, 0.f);
    }
}

extern "C" void kernel_launch(void* const* d_in, const int* in_sizes, int n_in,
                              void* d_out, int out_size, void* d_ws, size_t ws_size,
                              hipStream_t stream) {
    const float* feat_P = (const float*)d_in[0];
    const float* feat_A = (const float*)d_in[1];
    const float* feat_S = (const float*)d_in[2];
    const float* W_P   = (const float*)d_in[3];  const float* b_P   = (const float*)d_in[4];
    const float* W_A   = (const float*)d_in[5];  const float* b_A   = (const float*)d_in[6];
    const float* W_p2p = (const float*)d_in[7];  const float* b_p2p = (const float*)d_in[8];
    const float* W_p2a = (const float*)d_in[9];  const float* b_p2a = (const float*)d_in[10];
    const float* W_a2p = (const float*)d_in[11]; const float* b_a2p = (const float*)d_in[12];
    const float* W_a2a = (const float*)d_in[13]; const float* b_a2a = (const float*)d_in[14];
    const float* W_p2s = (const float*)d_in[15]; const float* b_p2s = (const float*)d_in[16];
    const float* W_a2s = (const float*)d_in[17]; const float* b_a2s = (const float*)d_in[18];
    const float* W_in  = (const float*)d_in[19]; const float* b_in  = (const float*)d_in[20];
    const float* a_p2p = (const float*)d_in[21];
    const float* a_p2a = (const float*)d_in[22];
    const float* a_a2p = (const float*)d_in[23];
    const float* a_a2a = (const float*)d_in[24];
    const float* a_p2s = (const float*)d_in[25];
    const float* a_a2s = (const float*)d_in[26];
    const int* src_p2p = (const int*)d_in[27]; const int* dst_p2p = (const int*)d_in[28];
    const int* src_p2a = (const int*)d_in[29]; const int* dst_p2a = (const int*)d_in[30];
    const int* src_a2p = (const int*)d_in[31]; const int* dst_a2p = (const int*)d_in[32];
    const int* src_a2a = (const int*)d_in[33]; const int* dst_a2a = (const int*)d_in[34];
    const int* src_p2s = (const int*)d_in[35];
    const int* src_a2s = (const int*)d_in[37];
    int E_p2p = in_sizes[27], E_p2a = in_sizes[29], E_a2p = in_sizes[31], E_a2a = in_sizes[33];
    int E_p2s = in_sizes[35], E_a2s = in_sizes[37];
    int E_tot = E_p2p + E_a2p + E_p2a + E_a2a;

    float* out = (float*)d_out;
    float* outP = out;
    float* outA = out + (long long)NP * 64;
    float* outS = out + (long long)(NP + NA) * 64;

    // ---- workspace layout ----
    float* ws = (float*)d_ws;
    float* WhP = ws; ws += (long long)NP * 64;
    float* WhA = ws; ws += (long long)NA * 64;
    u16* z_p2p = (u16*)ws; ws += (long long)NP * 32;
    u16* z_p2a = (u16*)ws; ws += (long long)NP * 32;
    u16* z_p2s = (u16*)ws; ws += (long long)NP * 32;
    u16* z_a2p = (u16*)ws; ws += (long long)NA * 32;
    u16* z_a2a = (u16*)ws; ws += (long long)NA * 32;
    u16* z_a2s = (u16*)ws; ws += (long long)NA * 32;
    float* ss_p2p = ws; ws += NP;  float* sd_p2p = ws; ws += NP;
    float* ss_p2a = ws; ws += NP;  float* sd_p2a = ws; ws += NA;
    float* ss_a2p = ws; ws += NA;  float* sd_a2p = ws; ws += NP;
    float* ss_a2a = ws; ws += NA;  float* sd_a2a = ws; ws += NA;
    float* ss_p2s = ws; ws += NP;
    float* ss_a2s = ws; ws += NA;
    float* sdst2  = ws; ws += 2;
    float* den2   = ws; ws += 2;
    float* numP   = ws; ws += 64;
    float* numA   = ws; ws += 64;
    int*   done   = (int*)ws; ws += 1;
    // ---- zeroed-every-call region (one small memset) ----
    float* zreg    = ws;
    int*   bucktot = (int*)ws; ws += NBUCK;
    int*   cursor0 = (int*)ws; ws += NBUCK;
    size_t zbytes = (size_t)((char*)ws - (char*)zreg);
    // ---- rest ----
    int* iw = (int*)ws;
    int* ebuf = iw; iw += E_tot;
    int* ssrc = iw; iw += E_tot;
    int* offs = iw; iw += NBINS + 1;

    const int T = 256;
    int nblk = (E_tot + CH - 1) / CH;

    hipMemsetAsync(zreg, 0, zbytes, stream);

    // ---- fused front: bucket_count | xform P | xform A | state_prep ----
    FrontArgs FA;
    FA.feat_P = feat_P; FA.feat_A = feat_A; FA.feat_S = feat_S;
    FA.W_P = W_P; FA.b_P = b_P; FA.W_A = W_A; FA.b_A = b_A;
    FA.W_p2p = W_p2p; FA.b_p2p = b_p2p; FA.W_p2a = W_p2a; FA.b_p2a = b_p2a;
    FA.W_a2p = W_a2p; FA.b_a2p = b_a2p; FA.W_a2a = W_a2a; FA.b_a2a = b_a2a;
    FA.W_p2s = W_p2s; FA.b_p2s = b_p2s; FA.W_a2s = W_a2s; FA.b_a2s = b_a2s;
    FA.W_in = W_in; FA.b_in = b_in;
    FA.a_p2p = a_p2p; FA.a_p2a = a_p2a; FA.a_a2p = a_a2p; FA.a_a2a = a_a2a;
    FA.a_p2s = a_p2s; FA.a_a2s = a_a2s;
    FA.WhP = WhP; FA.WhA = WhA;
    FA.z_p2p = z_p2p; FA.z_p2a = z_p2a; FA.z_p2s = z_p2s;
    FA.z_a2p = z_a2p; FA.z_a2a = z_a2a; FA.z_a2s = z_a2s;
    FA.ss_p2p = ss_p2p; FA.sd_p2p = sd_p2p; FA.ss_p2a = ss_p2a; FA.sd_p2a = sd_p2a;
    FA.ss_a2p = ss_a2p; FA.sd_a2p = sd_a2p; FA.ss_a2a = ss_a2a; FA.sd_a2a = sd_a2a;
    FA.ss_p2s = ss_p2s; FA.ss_a2s = ss_a2s;
    FA.sdst2 = sdst2; FA.outS = outS; FA.den2 = den2; FA.numP = numP; FA.numA = numA;
    FA.done = done;
    FA.dst_p2p = dst_p2p; FA.dst_a2p = dst_a2p; FA.dst_p2a = dst_p2a; FA.dst_a2a = dst_a2a;
    FA.E_p2p = E_p2p; FA.E_a2p = E_a2p; FA.E_p2a = E_p2a; FA.E_a2a = E_a2a; FA.E_tot = E_tot;
    FA.bucktot = bucktot;
    fused_front<<<NBC + GP + GA + 1, T, 0, stream>>>(FA);

    // ---- sort: windowed scatter (local scan) -> fine sort (local scan) ----
    passA_scatter<<<nblk, T, 0, stream>>>(src_p2p, dst_p2p, E_p2p,
                                          src_a2p, dst_a2p, E_a2p,
                                          src_p2a, dst_p2a, E_p2a,
                                          src_a2a, dst_a2a, E_a2a,
                                          bucktot, cursor0, E_tot, ebuf);
    fine_sort<<<NBUCK, T, 0, stream>>>(ebuf, bucktot, E_tot, ssrc, offs);

    // ---- fused back: gat (merged segments) | state_all ----
    fused_back<<<GATB + SNB_P + SNB_A, T, 0, stream>>>(ssrc, offs,
        WhP, outP, WhA, outA,
        ss_p2p, sd_p2p, z_p2p, ss_a2p, sd_a2p, z_a2p,
        ss_p2a, sd_p2a, z_p2a, ss_a2a, sd_a2a, z_a2a,
        src_p2s, ss_p2s, z_p2s, E_p2s,
        src_a2s, ss_a2s, z_a2s, E_a2s,
        sdst2, numP, numA, den2, done, outS);
}

// Round 10
// 144.556 us; speedup vs baseline: 7.0958x; 1.1260x over previous
//
#include <hip/hip_runtime.h>
#include <math.h>

#define ALPHA 0.2f
#define NP 50000
#define NA 25000
#define NBINS 150000          // P: 2*NP interleaved bins, then A: 2*NA
#define ABASE 100000          // bin base for A nodes (even -> node bins stay bucket-local)
#define NBUCK 586             // ceil(NBINS/256)
#define CH 4096               // edges per scatter block (= 16*256, static unroll)
#define CAP 8192              // fixed bucket region capacity (max observed ~3.9k)
#define GP ((NP + 63) / 64)   // 782 xform-P blocks
#define GA ((NA + 63) / 64)   // 391 xform-A blocks
#define GATB ((NP + NA) / 4)  // 18750 gat blocks (divides exactly)
#define SNB_P 128
#define SNB_A 64
#define SNB (SNB_P + SNB_A)

typedef unsigned short u16;
typedef __attribute__((ext_vector_type(8))) short bf16x8;
typedef __attribute__((ext_vector_type(8))) unsigned short u16x8;
typedef __attribute__((ext_vector_type(4))) float f32x4;

__device__ __forceinline__ float bf2f(u16 u) { return __uint_as_float(((unsigned)u) << 16); }
__device__ __forceinline__ u16 f2bf(float f) {
    unsigned x = __float_as_uint(f);
    return (u16)((x + 0x7fffu + ((x >> 16) & 1u)) >> 16);   // RNE
}

// =============== args ===============
struct FrontArgs {
    const float *feat_P, *feat_A, *feat_S;
    const float *W_P, *b_P, *W_A, *b_A, *W_p2p, *b_p2p, *W_p2a, *b_p2a,
                *W_a2p, *b_a2p, *W_a2a, *b_a2a, *W_p2s, *b_p2s, *W_a2s, *b_a2s,
                *W_in, *b_in;
    const float *a_p2p, *a_p2a, *a_a2p, *a_a2a, *a_p2s, *a_a2s;
    float *WhP, *WhA;
    u16 *z_p2p, *z_p2a, *z_p2s, *z_a2p, *z_a2a, *z_a2s;
    float *ss_p2p, *sd_p2p, *ss_p2a, *sd_p2a, *ss_a2p, *sd_a2p, *ss_a2a, *sd_a2a,
          *ss_p2s, *ss_a2s;
    float *sdst2, *outS, *den2, *numP, *numA;
    int *done;
};

// =============== MFMA 4-matrix transform body (per node type) ===============
__device__ __forceinline__ void xform_body(int bid,
    const float* __restrict__ X, int N,
    const float* __restrict__ W0, const float* __restrict__ b0, float* __restrict__ Wh,
    const float* __restrict__ dA, float* __restrict__ sdA,
    const float* __restrict__ dB, float* __restrict__ sdB,
    const float* __restrict__ W1, const float* __restrict__ b1, u16* __restrict__ z1,
    const float* __restrict__ v1, float* __restrict__ s1,
    const float* __restrict__ W2, const float* __restrict__ b2, u16* __restrict__ z2,
    const float* __restrict__ v2, float* __restrict__ s2,
    const float* __restrict__ W3, const float* __restrict__ b3, u16* __restrict__ z3,
    const float* __restrict__ v3, float* __restrict__ s3)
{
    int tid = threadIdx.x, wv = tid >> 6, lane = tid & 63;
    int g = lane >> 4, li = lane & 15;
    const float* Wm = wv == 0 ? W0 : wv == 1 ? W1 : wv == 2 ? W2 : W3;
    const float* bm = wv == 0 ? b0 : wv == 1 ? b1 : wv == 2 ? b2 : b3;
    const float* dv = wv == 0 ? dA : wv == 1 ? v1 : wv == 2 ? v2 : v3;
    float* sm       = wv == 0 ? sdA : wv == 1 ? s1 : wv == 2 ? s2 : s3;
    u16* zm         = wv == 1 ? z1 : wv == 2 ? z2 : wv == 3 ? z3 : nullptr;

    bf16x8 Bf[4][2];
#pragma unroll
    for (int cb = 0; cb < 4; ++cb)
#pragma unroll
        for (int kc = 0; kc < 2; ++kc) {
            bf16x8 t;
#pragma unroll
            for (int j = 0; j < 8; ++j)
                t[j] = (short)f2bf(Wm[(kc * 32 + g * 8 + j) * 64 + cb * 16 + li]);
            Bf[cb][kc] = t;
        }
    float bl[4], dvl[4], dbl[4];
#pragma unroll
    for (int cb = 0; cb < 4; ++cb) {
        bl[cb]  = bm[cb * 16 + li];
        dvl[cb] = dv[cb * 16 + li];
        dbl[cb] = (wv == 0) ? dB[cb * 16 + li] : 0.f;
    }

    int base0 = bid * 64;
#pragma unroll
    for (int rt = 0; rt < 4; ++rt) {
        int rbase = base0 + rt * 16;
        if (rbase >= N) break;
        int rowC = min(rbase + li, N - 1);
        bf16x8 Af[2];
#pragma unroll
        for (int kc = 0; kc < 2; ++kc) {
            const float* xp = X + (long long)rowC * 64 + kc * 32 + g * 8;
            float4 x0 = *(const float4*)xp;
            float4 x1 = *(const float4*)(xp + 4);
            bf16x8 t;
            t[0] = (short)f2bf(x0.x); t[1] = (short)f2bf(x0.y);
            t[2] = (short)f2bf(x0.z); t[3] = (short)f2bf(x0.w);
            t[4] = (short)f2bf(x1.x); t[5] = (short)f2bf(x1.y);
            t[6] = (short)f2bf(x1.z); t[7] = (short)f2bf(x1.w);
            Af[kc] = t;
        }
        f32x4 acc[4] = {{0,0,0,0},{0,0,0,0},{0,0,0,0},{0,0,0,0}};
#pragma unroll
        for (int kc = 0; kc < 2; ++kc)
#pragma unroll
            for (int cb = 0; cb < 4; ++cb)
                acc[cb] = __builtin_amdgcn_mfma_f32_16x16x32_bf16(Af[kc], Bf[cb][kc], acc[cb], 0, 0, 0);
        float pd[4] = {0,0,0,0}, pb[4] = {0,0,0,0};
#pragma unroll
        for (int cb = 0; cb < 4; ++cb)
#pragma unroll
            for (int r = 0; r < 4; ++r) {
                float val = acc[cb][r] + bl[cb];
                acc[cb][r] = val;
                pd[r] = fmaf(val, dvl[cb], pd[r]);
                pb[r] = fmaf(val, dbl[cb], pb[r]);
            }
#pragma unroll
        for (int o = 1; o < 16; o <<= 1)
#pragma unroll
            for (int r = 0; r < 4; ++r) {
                pd[r] += __shfl_xor(pd[r], o, 64);
                pb[r] += __shfl_xor(pb[r], o, 64);
            }
        int rg = rbase + g * 4;
        if (li == 0) {
#pragma unroll
            for (int r = 0; r < 4; ++r) {
                int row = rg + r;
                if (row < N) {
                    sm[row] = pd[r];
                    if (wv == 0) sdB[row] = pb[r];
                }
            }
        }
        if (wv == 0) {
#pragma unroll
            for (int r = 0; r < 4; ++r) {
                int row = rg + r;
                if (row < N)
#pragma unroll
                    for (int cb = 0; cb < 4; ++cb)
                        Wh[(long long)row * 64 + cb * 16 + li] = acc[cb][r];
            }
        } else {
#pragma unroll
            for (int r = 0; r < 4; ++r) {
                int row = rg + r;
                if (row < N)
#pragma unroll
                    for (int cb = 0; cb < 4; ++cb)
                        zm[(long long)row * 64 + cb * 16 + li] = f2bf(acc[cb][r]);
            }
        }
    }
}

// =============== edge decode ===============
__device__ __forceinline__ void edge_decode(int k,
    const int* __restrict__ s0, const int* __restrict__ d0, int E0,
    const int* __restrict__ s1, const int* __restrict__ d1, int E1,
    const int* __restrict__ s2, const int* __restrict__ d2, int E2,
    const int* __restrict__ s3, const int* __restrict__ d3,
    int& src, int& bin) {
    if (k < E0) { src = s0[k]; bin = 2 * d0[k]; return; }
    k -= E0; if (k < E1) { src = s1[k]; bin = 2 * d1[k] + 1; return; }
    k -= E1; if (k < E2) { src = s2[k]; bin = ABASE + 2 * d2[k]; return; }
    k -= E2; src = s3[k]; bin = ABASE + 2 * d3[k] + 1;
}

// =============== fused front: xform P | xform A | state_prep ===============
__global__ __launch_bounds__(256) void fused_front(FrontArgs A) {
    int bid = blockIdx.x;
    int tid = threadIdx.x;
    if (bid < GP) {
        xform_body(bid, A.feat_P, NP,
                   A.W_P, A.b_P, A.WhP, A.a_p2p + 64, A.sd_p2p, A.a_a2p + 64, A.sd_a2p,
                   A.W_p2p, A.b_p2p, A.z_p2p, A.a_p2p, A.ss_p2p,
                   A.W_p2a, A.b_p2a, A.z_p2a, A.a_p2a, A.ss_p2a,
                   A.W_p2s, A.b_p2s, A.z_p2s, A.a_p2s, A.ss_p2s);
        return;
    }
    bid -= GP;
    if (bid < GA) {
        xform_body(bid, A.feat_A, NA,
                   A.W_A, A.b_A, A.WhA, A.a_p2a + 64, A.sd_p2a, A.a_a2a + 64, A.sd_a2a,
                   A.W_a2p, A.b_a2p, A.z_a2p, A.a_a2p, A.ss_a2p,
                   A.W_a2a, A.b_a2a, A.z_a2a, A.a_a2a, A.ss_a2a,
                   A.W_a2s, A.b_a2s, A.z_a2s, A.a_a2s, A.ss_a2s);
        return;
    }
    // ---- state_prep role (last block) + zero den/num/done ----
    if (tid < 64) {
        int c = tid;
        float acc = A.b_in[c];
        for (int k = 0; k < 64; ++k) acc = fmaf(A.feat_S[k], A.W_in[k * 64 + c], acc);
        A.outS[c] = acc;                       // Wh_in staged in outS
        float v0 = acc * A.a_p2s[64 + c];
        float v1 = acc * A.a_a2s[64 + c];
#pragma unroll
        for (int off = 32; off > 0; off >>= 1) {
            v0 += __shfl_down(v0, off, 64);
            v1 += __shfl_down(v1, off, 64);
        }
        if (c == 0) { A.sdst2[0] = v0; A.sdst2[1] = v1; }
    } else if (tid < 128) A.numP[tid - 64] = 0.f;
    else if (tid < 192)   A.numA[tid - 128] = 0.f;
    else if (tid == 192)  A.den2[0] = 0.f;
    else if (tid == 193)  A.den2[1] = 0.f;
    else if (tid == 194)  *A.done = 0;
}

// =============== scatter: window reservation into fixed bucket regions ===============
__global__ __launch_bounds__(256) void passA_scatter(
    const int* __restrict__ s0, const int* __restrict__ d0, int E0,
    const int* __restrict__ s1, const int* __restrict__ d1, int E1,
    const int* __restrict__ s2, const int* __restrict__ d2, int E2,
    const int* __restrict__ s3, const int* __restrict__ d3, int E3,
    int* __restrict__ cursor0, int Etot, int* __restrict__ ebuf) {
    __shared__ int h[NBUCK];
    __shared__ int base[NBUCK];
    int tid = threadIdx.x;
    for (int i = tid; i < NBUCK; i += 256) h[i] = 0;
    __syncthreads();
    int b0 = blockIdx.x * CH;
    int b1 = min(b0 + CH, Etot);
    int cbin[16], csrc[16];
#pragma unroll
    for (int it = 0; it < 16; ++it) {
        int i = b0 + it * 256 + tid;
        int bin = -1, src = 0;
        if (i < b1)
            edge_decode(i, s0, d0, E0, s1, d1, E1, s2, d2, E2, s3, d3, src, bin);
        cbin[it] = bin; csrc[it] = src;
        if (bin >= 0) atomicAdd(&h[bin >> 8], 1);
    }
    __syncthreads();
    for (int i = tid; i < NBUCK; i += 256) {
        int c = h[i];
        base[i] = c ? (i * CAP + atomicAdd(&cursor0[i], c)) : 0;
        h[i] = 0;                               // reuse as local cursor
    }
    __syncthreads();
#pragma unroll
    for (int it = 0; it < 16; ++it) {
        int bin = cbin[it];
        if (bin >= 0) {
            int bk = bin >> 8;
            int pos = base[bk] + atomicAdd(&h[bk], 1);
            if (pos < (bk + 1) * CAP)           // capacity guard (never hit: max ~3.9k < 8192)
                ebuf[pos] = csrc[it] | ((bin & 255) << 16);
        }
    }
}

// =============== fine sort: bucket region -> bin-sorted ssrc + offs (257/bucket) ===============
__global__ __launch_bounds__(256) void fine_sort(
    const int* __restrict__ ebuf, const int* __restrict__ cursor0,
    int* __restrict__ ssrc, int* __restrict__ offs) {
    __shared__ int lsrc[CAP];
    __shared__ int lcnt[256];
    __shared__ int loff[256];
    __shared__ int lcur[256];
    __shared__ int wtot[4];
    int b = blockIdx.x;
    int tid = threadIdx.x, lane = tid & 63, wv = tid >> 6;
    int bstart = b * CAP;
    int cnt = min(cursor0[b], CAP);
    int bend = bstart + cnt;
    lcnt[tid] = 0;
    __syncthreads();
    for (int e = bstart + tid; e < bend; e += 256)
        atomicAdd(&lcnt[((unsigned)ebuf[e]) >> 16], 1);
    __syncthreads();
    int v = lcnt[tid];
    int x = v;
#pragma unroll
    for (int o = 1; o < 64; o <<= 1) {
        int y = __shfl_up(x, o, 64);
        if (lane >= o) x += y;
    }
    if (lane == 63) wtot[wv] = x;
    __syncthreads();
    int woff = 0;
    for (int j = 0; j < wv; ++j) woff += wtot[j];
    int excl = x + woff - v;
    loff[tid] = excl;
    lcur[tid] = excl;
    __syncthreads();
    for (int e = bstart + tid; e < bend; e += 256) {
        int val = ebuf[e];
        int pos = atomicAdd(&lcur[((unsigned)val) >> 16], 1);
        lsrc[pos] = val & 0xFFFF;
    }
    __syncthreads();
    for (int i = tid; i < cnt; i += 256) ssrc[bstart + i] = lsrc[i];   // coalesced
    offs[b * 257 + tid] = bstart + loff[tid];
    if (tid == 0) offs[b * 257 + 256] = bend;
}

// =============== general-path per-segment gather (rare, deg_total > 64) ===============
__device__ __forceinline__ void seg_gat_g8(const int* __restrict__ ssrc, int s0, int s1,
                                           const float* __restrict__ ss, float sd,
                                           const u16* __restrict__ z, int lane,
                                           float* __restrict__ acc) {
    int cnt = s1 - s0;
    if (cnt <= 0) return;
    int egrp = lane >> 3, cg8 = (lane & 7) * 8;
    float den = 0.f;
    for (int i = s0 + lane; i < s1; i += 64) {
        float e = ss[ssrc[i]] + sd; e = e > 0.f ? e : ALPHA * e; den += __expf(e);
    }
#pragma unroll
    for (int o = 32; o > 0; o >>= 1) den += __shfl_xor(den, o, 64);
    float inv = 1.f / den;
    for (int c = s0; c < s1; c += 64) {
        int i = c + lane; int s = 0; float w = 0.f;
        if (i < s1) {
            s = ssrc[i];
            float e = ss[s] + sd; e = e > 0.f ? e : ALPHA * e;
            w = __expf(e) * inv;
        }
        int cc = min(64, s1 - c);
        int nit = (cc + 7) >> 3;
        for (int it = 0; it < nit; ++it) {
            int ei = it * 8 + egrp;
            float wt = __shfl(w, ei, 64);
            int   st = __shfl(s, ei, 64);
            u16x8 q = *(const u16x8*)(z + (long long)st * 64 + cg8);
#pragma unroll
            for (int j = 0; j < 8; ++j)
                acc[j] = fmaf(wt, bf2f(q[j]), acc[j]);
        }
    }
}

// =============== fused back: state_all FIRST | gat (merged segments) ===============
__global__ __launch_bounds__(256) void fused_back(
    const int* __restrict__ ssrc, const int* __restrict__ offs,
    const float* __restrict__ WhP, float* __restrict__ outP,
    const float* __restrict__ WhA, float* __restrict__ outA,
    const float* __restrict__ ss_p2p, const float* __restrict__ sd_p2p, const u16* __restrict__ z_p2p,
    const float* __restrict__ ss_a2p, const float* __restrict__ sd_a2p, const u16* __restrict__ z_a2p,
    const float* __restrict__ ss_p2a, const float* __restrict__ sd_p2a, const u16* __restrict__ z_p2a,
    const float* __restrict__ ss_a2a, const float* __restrict__ sd_a2a, const u16* __restrict__ z_a2a,
    const int* __restrict__ srcP, const float* __restrict__ ssP, const u16* __restrict__ zP, int EP,
    const int* __restrict__ srcA, const float* __restrict__ ssA, const u16* __restrict__ zA, int EA,
    const float* __restrict__ sdst2, float* __restrict__ numP, float* __restrict__ numA,
    float* __restrict__ den2, int* __restrict__ done, float* __restrict__ outS) {
    int tid = threadIdx.x, lane = tid & 63, wv = tid >> 6;
    if ((int)blockIdx.x >= SNB) {
        // ---- gat role: wave per node, merged two-segment fast path ----
        int g = ((int)blockIdx.x - SNB) * 4 + wv;
        bool isP = g < NP;
        int d = isP ? g : g - NP;
        int bin0 = isP ? 2 * d : ABASE + 2 * d;
        int obase = (bin0 >> 8) * 257 + (bin0 & 255);
        int e0 = offs[obase], e1 = offs[obase + 1], e2 = offs[obase + 2];
        int cnt = e2 - e0, c1 = e1 - e0;
        const float* ss0 = isP ? ss_p2p : ss_p2a;
        const float* ss1 = isP ? ss_a2p : ss_a2a;
        const u16* z0 = isP ? z_p2p : z_p2a;
        const u16* z1 = isP ? z_a2p : z_a2a;
        float sd0v = (isP ? sd_p2p : sd_p2a)[d];
        float sd1v = (isP ? sd_a2p : sd_a2a)[d];
        int egrp = lane >> 3, cg8 = (lane & 7) * 8;
        float acc[8] = {0.f, 0.f, 0.f, 0.f, 0.f, 0.f, 0.f, 0.f};
        if (cnt <= 64) {                       // fast path (deg_tot <= 64: ~always)
            int s = 0; float w = 0.f;
            bool s1f = lane >= c1;
            if (lane < cnt) {
                s = ssrc[e0 + lane];           // coalesced
                float sc = (s1f ? ss1[s] : ss0[s]) + (s1f ? sd1v : sd0v);
                sc = sc > 0.f ? sc : ALPHA * sc;
                w = __expf(sc);
            }
            float d0 = s1f ? 0.f : w, d1 = s1f ? w : 0.f;
#pragma unroll
            for (int o = 32; o > 0; o >>= 1) {
                d0 += __shfl_xor(d0, o, 64);
                d1 += __shfl_xor(d1, o, 64);
            }
            float inv0 = 1.f / d0, inv1 = 1.f / d1;
            w = (lane < cnt) ? w * (s1f ? inv1 : inv0) : 0.f;   // exactly 0 for pad lanes
            int nit = (cnt + 7) >> 3;          // wave-uniform
            float wtv[8]; int stv[8]; u16x8 q[8];
#pragma unroll
            for (int it = 0; it < 8; ++it)
                if (it < nit) {
                    int ei = it * 8 + egrp;
                    wtv[it] = __shfl(w, ei, 64);
                    stv[it] = __shfl(s, ei, 64);
                }
#pragma unroll
            for (int it = 0; it < 8; ++it)     // issue all gathers back-to-back (MLP)
                if (it < nit) {
                    const u16* zp = (it * 8 + egrp >= c1) ? z1 : z0;
                    q[it] = *(const u16x8*)(zp + (long long)stv[it] * 64 + cg8);
                }
#pragma unroll
            for (int it = 0; it < 8; ++it)
                if (it < nit) {
#pragma unroll
                    for (int j = 0; j < 8; ++j)
                        acc[j] = fmaf(wtv[it], bf2f(q[it][j]), acc[j]);
                }
        } else {                               // general path (rare)
            seg_gat_g8(ssrc, e0, e1, ss0, sd0v, z0, lane, acc);
            seg_gat_g8(ssrc, e1, e2, ss1, sd1v, z1, lane, acc);
        }
#pragma unroll
        for (int o = 8; o <= 32; o <<= 1)
#pragma unroll
            for (int j = 0; j < 8; ++j)
                acc[j] += __shfl_xor(acc[j], o, 64);
        if (lane < 8) {
            const float* Wh = isP ? WhP : WhA;
            float* outp = isP ? outP : outA;
            const float* sp = &Wh[(long long)d * 64 + lane * 8];
            float4 s0v = *(const float4*)sp;
            float4 s1v = *(const float4*)(sp + 4);
            float4 r0, r1;
            r0.x = fmaxf(s0v.x + acc[0], 0.f); r0.y = fmaxf(s0v.y + acc[1], 0.f);
            r0.z = fmaxf(s0v.z + acc[2], 0.f); r0.w = fmaxf(s0v.w + acc[3], 0.f);
            r1.x = fmaxf(s1v.x + acc[4], 0.f); r1.y = fmaxf(s1v.y + acc[5], 0.f);
            r1.z = fmaxf(s1v.z + acc[6], 0.f); r1.w = fmaxf(s1v.w + acc[7], 0.f);
            float* op = &outp[(long long)d * 64 + lane * 8];
            *(float4*)op = r0;
            *(float4*)(op + 4) = r1;
        }
        return;
    }
    // ---- state role (blocks 0..SNB-1: launched FIRST, overlaps gat fill) ----
    __shared__ float red[4][64];
    __shared__ float dred[4];
    __shared__ int tick;
    int sb = blockIdx.x;
    bool isP = sb < SNB_P;
    const int* src = isP ? srcP : srcA;
    const float* ss = isP ? ssP : ssA;
    const u16* z = isP ? zP : zA;
    int E = isP ? EP : EA;
    float sdst = sdst2[isP ? 0 : 1];
    float* num = isP ? numP : numA;
    int bidl = isP ? sb : sb - SNB_P;
    int nb = isP ? SNB_P : SNB_A;
    int egrp = lane >> 3, cg8 = (lane & 7) * 8;
    int gw = bidl * 4 + wv;
    int waves = nb * 4;
    float acc[8] = {0,0,0,0,0,0,0,0};
    float dpart = 0.f;
    for (int base = gw * 8; base < E; base += waves * 8) {
        int i = base + egrp;
        float w = 0.f; int ri = 0;
        if (i < E) {
            ri = src[i];
            float e = ss[ri] + sdst;
            e = e > 0.f ? e : ALPHA * e;
            w = __expf(e);
        }
        dpart += w;                            // each edge counted by 8 lanes -> /8 later
        u16x8 q = *(const u16x8*)(z + (long long)ri * 64 + cg8);
#pragma unroll
        for (int j = 0; j < 8; ++j)
            acc[j] = fmaf(w, bf2f(q[j]), acc[j]);
    }
#pragma unroll
    for (int o = 8; o <= 32; o <<= 1)
#pragma unroll
        for (int j = 0; j < 8; ++j)
            acc[j] += __shfl_xor(acc[j], o, 64);
#pragma unroll
    for (int o = 32; o > 0; o >>= 1) dpart += __shfl_xor(dpart, o, 64);
    if (lane < 8)
#pragma unroll
        for (int j = 0; j < 8; ++j) red[wv][lane * 8 + j] = acc[j];
    if (lane == 0) dred[wv] = dpart;
    __syncthreads();
    if (tid < 64) {
        float t = red[0][tid] + red[1][tid] + red[2][tid] + red[3][tid];
        atomicAdd(&num[tid], t);
    }
    if (tid == 64) {
        float dtot = (dred[0] + dred[1] + dred[2] + dred[3]) * 0.125f;
        atomicAdd(&den2[isP ? 0 : 1], dtot);
    }
    __threadfence();
    __syncthreads();
    if (tid == 0) tick = atomicAdd(done, 1);
    __syncthreads();
    if (tick == SNB - 1 && tid < 64) {         // last state block finalizes
        float dP = __hip_atomic_load(&den2[0], __ATOMIC_ACQUIRE, __HIP_MEMORY_SCOPE_AGENT);
        float dA = __hip_atomic_load(&den2[1], __ATOMIC_ACQUIRE, __HIP_MEMORY_SCOPE_AGENT);
        float nP = __hip_atomic_load(&numP[tid], __ATOMIC_ACQUIRE, __HIP_MEMORY_SCOPE_AGENT);
        float nA = __hip_atomic_load(&numA[tid], __ATOMIC_ACQUIRE, __HIP_MEMORY_SCOPE_AGENT);
        float whin = outS[tid];
        outS[tid] = fmaxf(whin + nP / dP + nA / dA, 0.f);
    }
}

extern "C" void kernel_launch(void* const* d_in, const int* in_sizes, int n_in,
                              void* d_out, int out_size, void* d_ws, size_t ws_size,
                              hipStream_t stream) {
    const float* feat_P = (const float*)d_in[0];
    const float* feat_A = (const float*)d_in[1];
    const float* feat_S = (const float*)d_in[2];
    const float* W_P   = (const float*)d_in[3];  const float* b_P   = (const float*)d_in[4];
    const float* W_A   = (const float*)d_in[5];  const float* b_A   = (const float*)d_in[6];
    const float* W_p2p = (const float*)d_in[7];  const float* b_p2p = (const float*)d_in[8];
    const float* W_p2a = (const float*)d_in[9];  const float* b_p2a = (const float*)d_in[10];
    const float* W_a2p = (const float*)d_in[11]; const float* b_a2p = (const float*)d_in[12];
    const float* W_a2a = (const float*)d_in[13]; const float* b_a2a = (const float*)d_in[14];
    const float* W_p2s = (const float*)d_in[15]; const float* b_p2s = (const float*)d_in[16];
    const float* W_a2s = (const float*)d_in[17]; const float* b_a2s = (const float*)d_in[18];
    const float* W_in  = (const float*)d_in[19]; const float* b_in  = (const float*)d_in[20];
    const float* a_p2p = (const float*)d_in[21];
    const float* a_p2a = (const float*)d_in[22];
    const float* a_a2p = (const float*)d_in[23];
    const float* a_a2a = (const float*)d_in[24];
    const float* a_p2s = (const float*)d_in[25];
    const float* a_a2s = (const float*)d_in[26];
    const int* src_p2p = (const int*)d_in[27]; const int* dst_p2p = (const int*)d_in[28];
    const int* src_p2a = (const int*)d_in[29]; const int* dst_p2a = (const int*)d_in[30];
    const int* src_a2p = (const int*)d_in[31]; const int* dst_a2p = (const int*)d_in[32];
    const int* src_a2a = (const int*)d_in[33]; const int* dst_a2a = (const int*)d_in[34];
    const int* src_p2s = (const int*)d_in[35];
    const int* src_a2s = (const int*)d_in[37];
    int E_p2p = in_sizes[27], E_p2a = in_sizes[29], E_a2p = in_sizes[31], E_a2a = in_sizes[33];
    int E_p2s = in_sizes[35], E_a2s = in_sizes[37];
    int E_tot = E_p2p + E_a2p + E_p2a + E_a2a;

    float* out = (float*)d_out;
    float* outP = out;
    float* outA = out + (long long)NP * 64;
    float* outS = out + (long long)(NP + NA) * 64;

    // ---- workspace layout ----
    float* ws = (float*)d_ws;
    float* WhP = ws; ws += (long long)NP * 64;
    float* WhA = ws; ws += (long long)NA * 64;
    u16* z_p2p = (u16*)ws; ws += (long long)NP * 32;
    u16* z_p2a = (u16*)ws; ws += (long long)NP * 32;
    u16* z_p2s = (u16*)ws; ws += (long long)NP * 32;
    u16* z_a2p = (u16*)ws; ws += (long long)NA * 32;
    u16* z_a2a = (u16*)ws; ws += (long long)NA * 32;
    u16* z_a2s = (u16*)ws; ws += (long long)NA * 32;
    float* ss_p2p = ws; ws += NP;  float* sd_p2p = ws; ws += NP;
    float* ss_p2a = ws; ws += NP;  float* sd_p2a = ws; ws += NA;
    float* ss_a2p = ws; ws += NA;  float* sd_a2p = ws; ws += NP;
    float* ss_a2a = ws; ws += NA;  float* sd_a2a = ws; ws += NA;
    float* ss_p2s = ws; ws += NP;
    float* ss_a2s = ws; ws += NA;
    float* sdst2  = ws; ws += 2;
    float* den2   = ws; ws += 2;
    float* numP   = ws; ws += 64;
    float* numA   = ws; ws += 64;
    int*   done   = (int*)ws; ws += 1;
    // ---- zeroed-every-call region (tiny memset) ----
    int* cursor0 = (int*)ws; ws += NBUCK;
    // ---- rest ----
    int* iw = (int*)ws;
    int* ebuf = iw; iw += NBUCK * CAP;
    int* ssrc = iw; iw += NBUCK * CAP;
    int* offs = iw; iw += NBUCK * 257 + 1;

    const int T = 256;
    int nblk = (E_tot + CH - 1) / CH;

    hipMemsetAsync(cursor0, 0, (size_t)NBUCK * 4, stream);

    // ---- fused front: xform P | xform A | state_prep ----
    FrontArgs FA;
    FA.feat_P = feat_P; FA.feat_A = feat_A; FA.feat_S = feat_S;
    FA.W_P = W_P; FA.b_P = b_P; FA.W_A = W_A; FA.b_A = b_A;
    FA.W_p2p = W_p2p; FA.b_p2p = b_p2p; FA.W_p2a = W_p2a; FA.b_p2a = b_p2a;
    FA.W_a2p = W_a2p; FA.b_a2p = b_a2p; FA.W_a2a = W_a2a; FA.b_a2a = b_a2a;
    FA.W_p2s = W_p2s; FA.b_p2s = b_p2s; FA.W_a2s = W_a2s; FA.b_a2s = b_a2s;
    FA.W_in = W_in; FA.b_in = b_in;
    FA.a_p2p = a_p2p; FA.a_p2a = a_p2a; FA.a_a2p = a_a2p; FA.a_a2a = a_a2a;
    FA.a_p2s = a_p2s; FA.a_a2s = a_a2s;
    FA.WhP = WhP; FA.WhA = WhA;
    FA.z_p2p = z_p2p; FA.z_p2a = z_p2a; FA.z_p2s = z_p2s;
    FA.z_a2p = z_a2p; FA.z_a2a = z_a2a; FA.z_a2s = z_a2s;
    FA.ss_p2p = ss_p2p; FA.sd_p2p = sd_p2p; FA.ss_p2a = ss_p2a; FA.sd_p2a = sd_p2a;
    FA.ss_a2p = ss_a2p; FA.sd_a2p = sd_a2p; FA.ss_a2a = ss_a2a; FA.sd_a2a = sd_a2a;
    FA.ss_p2s = ss_p2s; FA.ss_a2s = ss_a2s;
    FA.sdst2 = sdst2; FA.outS = outS; FA.den2 = den2; FA.numP = numP; FA.numA = numA;
    FA.done = done;
    fused_front<<<GP + GA + 1, T, 0, stream>>>(FA);

    // ---- sort: windowed scatter (fixed regions) -> fine sort ----
    passA_scatter<<<nblk, T, 0, stream>>>(src_p2p, dst_p2p, E_p2p,
                                          src_a2p, dst_a2p, E_a2p,
                                          src_p2a, dst_p2a, E_p2a,
                                          src_a2a, dst_a2a, E_a2a,
                                          cursor0, E_tot, ebuf);
    fine_sort<<<NBUCK, T, 0, stream>>>(ebuf, cursor0, ssrc, offs);

    // ---- fused back: state_all (first) | gat (merged segments) ----
    fused_back<<<SNB + GATB, T, 0, stream>>>(ssrc, offs,
        WhP, outP, WhA, outA,
        ss_p2p, sd_p2p, z_p2p, ss_a2p, sd_a2p, z_a2p,
        ss_p2a, sd_p2a, z_p2a, ss_a2a, sd_a2a, z_a2a,
        src_p2s, ss_p2s, z_p2s, E_p2s,
        src_a2s, ss_a2s, z_a2s, E_a2s,
        sdst2, numP, numA, den2, done, outS);
}